// Round 11
// baseline (485.169 us; speedup 1.0000x reference)
//
#include <hip/hip_runtime.h>
#include <hip/hip_bf16.h>

#define S 4
#define N 32768
#define D 256
#define KSEG 512
#define NH 4
#define HD 64
#define FF 1024

typedef __attribute__((ext_vector_type(8))) short short8;
typedef __attribute__((ext_vector_type(4))) float f32x4;
typedef __attribute__((ext_vector_type(4))) unsigned int u32x4;
typedef __attribute__((ext_vector_type(2))) unsigned int u32x2;

__device__ __forceinline__ unsigned short f2bf(float f) {
  union { __hip_bfloat16 h; unsigned short u; } cv;
  cv.h = __float2bfloat16(f);
  return cv.u;
}

__device__ __forceinline__ float gelu_f(float x) {
  return 0.5f * x * (1.0f + erff(x * 0.70710678118654752440f));
}

__device__ __forceinline__ float wave_reduce_sum(float v) {
  #pragma unroll
  for (int o = 32; o > 0; o >>= 1) v += __shfl_xor(v, o, 64);
  return v;
}

// ---------------- Phase A: counting sort by patch id ----------------
__global__ __launch_bounds__(256) void hist_kernel(
    const int* __restrict__ pids, int* __restrict__ histc)
{
  __shared__ int h[KSEG];
  int b = blockIdx.x, t = threadIdx.x;
  int s = b >> 4, c = b & 15;
  for (int i = t; i < KSEG; i += 256) h[i] = 0;
  __syncthreads();
  const int* p = pids + s * N + c * 2048;
  for (int i = t; i < 2048; i += 256) atomicAdd(&h[p[i]], 1);
  __syncthreads();
  for (int i = t; i < KSEG; i += 256) histc[(s * 16 + c) * KSEG + i] = h[i];
}

__global__ __launch_bounds__(256) void prefix_kernel(
    int* __restrict__ histc, int* __restrict__ segstart,
    int* __restrict__ cnti, float* __restrict__ counts)
{
  __shared__ int h[16 * KSEG];   // 32 KB
  __shared__ int sc[KSEG];
  __shared__ int sa[KSEG], sb[KSEG];
  int s = blockIdx.x, t = threadIdx.x;
  for (int i = t; i < 16 * KSEG; i += 256) h[i] = histc[s * 16 * KSEG + i];
  __syncthreads();
  #pragma unroll
  for (int u = 0; u < 2; u++) {
    int bin = t + u * 256;
    int cc = 0;
    #pragma unroll
    for (int c = 0; c < 16; c++) cc += h[c * KSEG + bin];
    sc[bin] = cc;
    sa[bin] = cc;
  }
  __syncthreads();
  int* src = sa; int* dst = sb;
  for (int off = 1; off < KSEG; off <<= 1) {
    #pragma unroll
    for (int u = 0; u < 2; u++) {
      int bin = t + u * 256;
      int v = src[bin];
      if (bin >= off) v += src[bin - off];
      dst[bin] = v;
    }
    __syncthreads();
    int* tmp = src; src = dst; dst = tmp;
  }
  #pragma unroll
  for (int u = 0; u < 2; u++) {
    int bin = t + u * 256;
    int cc = sc[bin];
    int excl = src[bin] - cc;
    segstart[s * KSEG + bin] = excl;
    cnti[s * KSEG + bin] = cc;
    counts[s * KSEG + bin] = (float)cc;
    int run = excl;
    #pragma unroll
    for (int c = 0; c < 16; c++) {
      int v = h[c * KSEG + bin];
      h[c * KSEG + bin] = run;
      run += v;
    }
  }
  __syncthreads();
  for (int i = t; i < 16 * KSEG; i += 256) histc[s * 16 * KSEG + i] = h[i];
}

__global__ __launch_bounds__(256) void scatter_kernel(
    const int* __restrict__ pids, const int* __restrict__ histc,
    int* __restrict__ order)
{
  __shared__ int offs[KSEG];
  int b = blockIdx.x, t = threadIdx.x;
  int s = b >> 4, c = b & 15;
  for (int i = t; i < KSEG; i += 256) offs[i] = histc[(s * 16 + c) * KSEG + i];
  __syncthreads();
  const int* p = pids + s * N + c * 2048;
  for (int i = t; i < 2048; i += 256) {
    int pid = p[i];
    int pos = atomicAdd(&offs[pid], 1);
    order[s * N + pos] = s * N + c * 2048 + i;
  }
}

// gather-reduce + fused LN1: TWO waves per segment. grid 1024.
__global__ __launch_bounds__(256) void pool_gather(
    const float* __restrict__ H, const int* __restrict__ order,
    const int* __restrict__ segstart, const int* __restrict__ cnti,
    const float* __restrict__ g, const float* __restrict__ bta,
    float* __restrict__ xw, float* __restrict__ yw)
{
  __shared__ float pbuf[4][256];
  int tid = threadIdx.x;
  int w = tid >> 6, lane = tid & 63;
  int seg = blockIdx.x * 2 + (w >> 1);
  int half = w & 1;
  int s = seg >> 9;
  int st = segstart[seg], cn = cnti[seg];
  int en = st + cn;
  const int* ord = order + (size_t)s * N;
  int c4 = lane << 2;
  f32x4 a0 = {0,0,0,0}, a1 = {0,0,0,0}, a2 = {0,0,0,0}, a3 = {0,0,0,0};
  f32x4 a4 = {0,0,0,0}, a5 = {0,0,0,0}, a6 = {0,0,0,0}, a7 = {0,0,0,0};
  int i = st + half;
  for (; i + 14 < en; i += 16) {
    int r0 = ord[i + 0], r1 = ord[i + 2], r2 = ord[i + 4], r3 = ord[i + 6];
    int r4 = ord[i + 8], r5 = ord[i + 10], r6 = ord[i + 12], r7 = ord[i + 14];
    a0 += *(const f32x4*)(H + (size_t)r0 * 256 + c4);
    a1 += *(const f32x4*)(H + (size_t)r1 * 256 + c4);
    a2 += *(const f32x4*)(H + (size_t)r2 * 256 + c4);
    a3 += *(const f32x4*)(H + (size_t)r3 * 256 + c4);
    a4 += *(const f32x4*)(H + (size_t)r4 * 256 + c4);
    a5 += *(const f32x4*)(H + (size_t)r5 * 256 + c4);
    a6 += *(const f32x4*)(H + (size_t)r6 * 256 + c4);
    a7 += *(const f32x4*)(H + (size_t)r7 * 256 + c4);
  }
  for (; i < en; i += 2) {
    int r = ord[i];
    a0 += *(const f32x4*)(H + (size_t)r * 256 + c4);
  }
  f32x4 ssum = ((a0 + a1) + (a2 + a3)) + ((a4 + a5) + (a6 + a7));
  *(f32x4*)&pbuf[w][c4] = ssum;
  __syncthreads();
  if (half == 0) {
    f32x4 tot = *(f32x4*)&pbuf[w][c4];
    tot += *(f32x4*)&pbuf[w + 1][c4];
    float inv = 1.f / fmaxf((float)cn, 1.f);
    tot = tot * inv;
    *(f32x4*)(xw + (size_t)seg * 256 + c4) = tot;
    // fused LN1
    float s1 = tot[0] + tot[1] + tot[2] + tot[3];
    float s2 = tot[0]*tot[0] + tot[1]*tot[1] + tot[2]*tot[2] + tot[3]*tot[3];
    s1 = wave_reduce_sum(s1);
    s2 = wave_reduce_sum(s2);
    float mu = s1 * (1.f / 256.f);
    float var = s2 * (1.f / 256.f) - mu * mu;
    float rs = rsqrtf(var + 1e-5f);
    float4 g4 = *(const float4*)(g + c4);
    float4 b4 = *(const float4*)(bta + c4);
    float4 yv = {(tot[0]-mu)*rs*g4.x + b4.x, (tot[1]-mu)*rs*g4.y + b4.y,
                 (tot[2]-mu)*rs*g4.z + b4.z, (tot[3]-mu)*rs*g4.w + b4.w};
    *(float4*)(yw + (size_t)seg * 256 + c4) = yv;
  }
}

// ---------------- weight pre-pack: all 8 matrices into fragment order ----
__global__ __launch_bounds__(256) void wprep2_kernel(
    const float* __restrict__ Wq, const float* __restrict__ Wk,
    const float* __restrict__ Wv, const float* __restrict__ Wo,
    const float* __restrict__ fW1, const float* __restrict__ fW2,
    const float* __restrict__ mW1, const float* __restrict__ mW2,
    unsigned short* __restrict__ Wpack)
{
  int fi = blockIdx.x * 256 + threadIdx.x;   // 0..122879
  const float* src; int ld, colbase, kcbits; size_t outb; int rfi;
  if (fi < 32768) {
    int m = fi >> 13; rfi = fi & 8191;
    src = (m == 0) ? Wq : ((m == 1) ? Wk : ((m == 2) ? Wv : Wo));
    ld = 256; colbase = 0; kcbits = 3; outb = (size_t)m * 65536;
  } else if (fi < 65536) {
    rfi = fi - 32768; int cc = rfi >> 13; rfi &= 8191;
    src = fW1; ld = 1024; colbase = cc * 256; kcbits = 3;
    outb = 262144 + (size_t)cc * 65536;
  } else if (fi < 98304) {
    rfi = fi - 65536; src = fW2; ld = 256; colbase = 0; kcbits = 5; outb = 524288;
  } else if (fi < 114688) {
    rfi = fi - 98304; src = mW1; ld = 256; colbase = 0; kcbits = 4; outb = 786432;
  } else {
    rfi = fi - 114688; src = mW2; ld = 256; colbase = 0; kcbits = 3; outb = 917504;
  }
  int tile = rfi >> 6, lane = rfi & 63;
  int c = tile >> kcbits, kc = tile & ((1 << kcbits) - 1);
  int k0 = kc * 32 + (lane >> 4) * 8;
  int col = colbase + c * 16 + (lane & 15);
  unsigned int p[4];
  #pragma unroll
  for (int jj = 0; jj < 4; jj++) {
    unsigned int lo = f2bf(src[(size_t)(k0 + 2 * jj) * ld + col]);
    unsigned int hi = f2bf(src[(size_t)(k0 + 2 * jj + 1) * ld + col]);
    p[jj] = lo | (hi << 16);
  }
  u32x4 v = {p[0], p[1], p[2], p[3]};
  *(u32x4*)&Wpack[outb + (size_t)rfi * 8] = v;
}

// ---------------- MFMA patch-GEMM template pieces (16 rows x 256 cols) ----
#define AP3 264  // A row stride (bf16): 256 + 8 pad
#define CP3 260  // C row stride (f32): 256 + 4 pad

// QKV merged: grid 128, loops m=0..2 with one A staging.
// Separate Ah/Cl buffers (no alias) so A persists across the m-loop.
__global__ __launch_bounds__(256, 4) void qkv_all(
    const float* __restrict__ y, const float* __restrict__ counts,
    const unsigned short* __restrict__ Wpack,
    const float* __restrict__ bq, const float* __restrict__ bk,
    const float* __restrict__ bv,
    float* __restrict__ qo, float* __restrict__ ko, float* __restrict__ vo)
{
  __shared__ __align__(16) unsigned short Ah[16 * AP3];  // 8448 B
  __shared__ __align__(16) float Cl[16 * CP3];           // 16640 B
  int tid = threadIdx.x, lane = tid & 63, w = tid >> 6;
  int ln15 = lane & 15, hi = lane >> 4;
  int base = blockIdx.x * 16;

  for (int i = tid; i < 16 * 64; i += 256) {
    int r = i >> 6, c4 = i & 63;
    float4 f = *(const float4*)(y + ((size_t)(base + r)) * 256 + c4 * 4);
    unsigned int lo = (unsigned int)f2bf(f.x) | ((unsigned int)f2bf(f.y) << 16);
    unsigned int h2 = (unsigned int)f2bf(f.z) | ((unsigned int)f2bf(f.w) << 16);
    u32x2 val = {lo, h2};
    *((u32x2*)&Ah[r * AP3 + c4 * 4]) = val;
  }
  float mk[4];
  #pragma unroll
  for (int r = 0; r < 4; r++)
    mk[r] = (counts[base + hi * 4 + r] > 0.f) ? 1.f : 0.f;
  __syncthreads();

  for (int m = 0; m < 3; m++) {
    const unsigned short* Wf = Wpack + (size_t)m * 65536;
    const float* bias = (m == 0) ? bq : ((m == 1) ? bk : bv);
    float* outp = (m == 0) ? qo : ((m == 1) ? ko : vo);

    f32x4 acc[4];
    #pragma unroll
    for (int c = 0; c < 4; c++) acc[c] = (f32x4){0.f, 0.f, 0.f, 0.f};
    const unsigned short* Wl = Wf + (size_t)lane * 8;
    short8 bcur[4];
    #pragma unroll
    for (int ct = 0; ct < 4; ct++)
      bcur[ct] = *(const short8*)(Wl + ((w * 4 + ct) * 8 + 0) * 512);
    #pragma unroll
    for (int kc = 0; kc < 8; kc++) {
      short8 a = *(const short8*)(&Ah[ln15 * AP3 + kc * 32 + hi * 8]);
      short8 bnext[4];
      if (kc < 7) {
        #pragma unroll
        for (int ct = 0; ct < 4; ct++)
          bnext[ct] = *(const short8*)(Wl + ((w * 4 + ct) * 8 + kc + 1) * 512);
      }
      #pragma unroll
      for (int ct = 0; ct < 4; ct++)
        acc[ct] = __builtin_amdgcn_mfma_f32_16x16x32_bf16(a, bcur[ct], acc[ct], 0, 0, 0);
      if (kc < 7) {
        #pragma unroll
        for (int ct = 0; ct < 4; ct++) bcur[ct] = bnext[ct];
      }
    }
    __syncthreads();  // prior m's Cl store-reads done
    #pragma unroll
    for (int ct = 0; ct < 4; ct++) {
      int col = w * 64 + ct * 16 + ln15;
      float bb = bias[col];
      #pragma unroll
      for (int r = 0; r < 4; r++) {
        float tv = acc[ct][r] + bb;
        if (m <= 1) tv = (tv > 0.f) ? (tv + 1.f) : expf(tv);
        if (m >= 1) tv *= mk[r];
        Cl[(hi * 4 + r) * CP3 + col] = tv;
      }
    }
    __syncthreads();
    for (int i = tid; i < 16 * 64; i += 256) {
      int r = i >> 6, c4 = i & 63;
      *(float4*)(outp + ((size_t)(base + r)) * 256 + c4 * 4) =
          *(const float4*)&Cl[r * CP3 + c4 * 4];
    }
  }
}

// oproj + fused LN2: x2 = x + a@Wo + bo; y2 = LN(x2). grid 128.
__global__ __launch_bounds__(256, 4) void oproj_mfma(
    const float* __restrict__ aw, const float* __restrict__ xw,
    const unsigned short* __restrict__ Wpack, const float* __restrict__ bo,
    const float* __restrict__ g, const float* __restrict__ bta,
    float* __restrict__ x2, float* __restrict__ y2)
{
  __shared__ __align__(16) unsigned char smem[16 * CP3 * 4];
  unsigned short* Ah = (unsigned short*)smem;
  float* Cl = (float*)smem;
  const unsigned short* Wf = Wpack + 196608;
  int tid = threadIdx.x, lane = tid & 63, w = tid >> 6;
  int ln15 = lane & 15, hi = lane >> 4;
  int base = blockIdx.x * 16;

  for (int i = tid; i < 16 * 64; i += 256) {
    int r = i >> 6, c4 = i & 63;
    float4 f = *(const float4*)(aw + ((size_t)(base + r)) * 256 + c4 * 4);
    unsigned int lo = (unsigned int)f2bf(f.x) | ((unsigned int)f2bf(f.y) << 16);
    unsigned int h2 = (unsigned int)f2bf(f.z) | ((unsigned int)f2bf(f.w) << 16);
    u32x2 val = {lo, h2};
    *((u32x2*)&Ah[r * AP3 + c4 * 4]) = val;
  }
  __syncthreads();

  f32x4 acc[4];
  #pragma unroll
  for (int c = 0; c < 4; c++) acc[c] = (f32x4){0.f, 0.f, 0.f, 0.f};
  const unsigned short* Wl = Wf + (size_t)lane * 8;
  short8 bcur[4];
  #pragma unroll
  for (int ct = 0; ct < 4; ct++)
    bcur[ct] = *(const short8*)(Wl + ((w * 4 + ct) * 8 + 0) * 512);
  #pragma unroll
  for (int kc = 0; kc < 8; kc++) {
    short8 a = *(const short8*)(&Ah[ln15 * AP3 + kc * 32 + hi * 8]);
    short8 bnext[4];
    if (kc < 7) {
      #pragma unroll
      for (int ct = 0; ct < 4; ct++)
        bnext[ct] = *(const short8*)(Wl + ((w * 4 + ct) * 8 + kc + 1) * 512);
    }
    #pragma unroll
    for (int ct = 0; ct < 4; ct++)
      acc[ct] = __builtin_amdgcn_mfma_f32_16x16x32_bf16(a, bcur[ct], acc[ct], 0, 0, 0);
    if (kc < 7) {
      #pragma unroll
      for (int ct = 0; ct < 4; ct++) bcur[ct] = bnext[ct];
    }
  }
  __syncthreads();

  #pragma unroll
  for (int ct = 0; ct < 4; ct++) {
    int col = w * 64 + ct * 16 + ln15;
    float bb = bo[col];
    #pragma unroll
    for (int r = 0; r < 4; r++)
      Cl[(hi * 4 + r) * CP3 + col] = acc[ct][r] + bb;
  }
  __syncthreads();
  // fused residual + LN2: wave w handles rows {4k + w}
  int c4 = lane << 2;
  float4 g4 = *(const float4*)(g + c4);
  float4 b4 = *(const float4*)(bta + c4);
  #pragma unroll
  for (int k = 0; k < 4; k++) {
    int r = k * 4 + w;
    size_t gbase = ((size_t)(base + r)) * 256 + c4;
    float4 xv = *(const float4*)(xw + gbase);
    float4 cv = *(const float4*)&Cl[r * CP3 + c4];
    float4 x2v = {xv.x + cv.x, xv.y + cv.y, xv.z + cv.z, xv.w + cv.w};
    *(float4*)(x2 + gbase) = x2v;
    float s1 = x2v.x + x2v.y + x2v.z + x2v.w;
    float s2 = x2v.x*x2v.x + x2v.y*x2v.y + x2v.z*x2v.z + x2v.w*x2v.w;
    s1 = wave_reduce_sum(s1);
    s2 = wave_reduce_sum(s2);
    float mu = s1 * (1.f / 256.f);
    float var = s2 * (1.f / 256.f) - mu * mu;
    float rs = rsqrtf(var + 1e-5f);
    float4 yv = {(x2v.x-mu)*rs*g4.x + b4.x, (x2v.y-mu)*rs*g4.y + b4.y,
                 (x2v.z-mu)*rs*g4.z + b4.z, (x2v.w-mu)*rs*g4.w + b4.w};
    *(float4*)(y2 + gbase) = yv;
  }
}

// ffn1 merged: grid 128, loops cc=0..3 with one A staging.
__global__ __launch_bounds__(256, 4) void ffn1_all(
    const float* __restrict__ y2, const unsigned short* __restrict__ Wpack,
    const float* __restrict__ b1, unsigned short* __restrict__ hidb)
{
  __shared__ __align__(16) unsigned short Ah[16 * AP3];  // 8448 B
  __shared__ __align__(16) unsigned short Hb[16 * 256];  // 8192 B
  int tid = threadIdx.x, lane = tid & 63, w = tid >> 6;
  int ln15 = lane & 15, hi = lane >> 4;
  int base = blockIdx.x * 16;

  for (int i = tid; i < 16 * 64; i += 256) {
    int r = i >> 6, c4 = i & 63;
    float4 f = *(const float4*)(y2 + ((size_t)(base + r)) * 256 + c4 * 4);
    unsigned int lo = (unsigned int)f2bf(f.x) | ((unsigned int)f2bf(f.y) << 16);
    unsigned int h2 = (unsigned int)f2bf(f.z) | ((unsigned int)f2bf(f.w) << 16);
    u32x2 val = {lo, h2};
    *((u32x2*)&Ah[r * AP3 + c4 * 4]) = val;
  }
  __syncthreads();

  for (int cc = 0; cc < 4; cc++) {
    const unsigned short* Wf = Wpack + 262144 + (size_t)cc * 65536;
    f32x4 acc[4];
    #pragma unroll
    for (int c = 0; c < 4; c++) acc[c] = (f32x4){0.f, 0.f, 0.f, 0.f};
    const unsigned short* Wl = Wf + (size_t)lane * 8;
    short8 bcur[4];
    #pragma unroll
    for (int ct = 0; ct < 4; ct++)
      bcur[ct] = *(const short8*)(Wl + ((w * 4 + ct) * 8 + 0) * 512);
    #pragma unroll
    for (int kc = 0; kc < 8; kc++) {
      short8 a = *(const short8*)(&Ah[ln15 * AP3 + kc * 32 + hi * 8]);
      short8 bnext[4];
      if (kc < 7) {
        #pragma unroll
        for (int ct = 0; ct < 4; ct++)
          bnext[ct] = *(const short8*)(Wl + ((w * 4 + ct) * 8 + kc + 1) * 512);
      }
      #pragma unroll
      for (int ct = 0; ct < 4; ct++)
        acc[ct] = __builtin_amdgcn_mfma_f32_16x16x32_bf16(a, bcur[ct], acc[ct], 0, 0, 0);
      if (kc < 7) {
        #pragma unroll
        for (int ct = 0; ct < 4; ct++) bcur[ct] = bnext[ct];
      }
    }
    __syncthreads();  // prior cc's Hb store-reads done
    #pragma unroll
    for (int ct = 0; ct < 4; ct++) {
      int col = w * 64 + ct * 16 + ln15;
      float bb = b1[cc * 256 + col];
      #pragma unroll
      for (int r = 0; r < 4; r++)
        Hb[(hi * 4 + r) * 256 + col] = f2bf(gelu_f(acc[ct][r] + bb));
    }
    __syncthreads();
    for (int i = tid; i < 16 * 32; i += 256) {
      int r = i >> 5, c8 = i & 31;
      *(u32x4*)(hidb + ((size_t)(base + r)) * FF + cc * 256 + c8 * 8) =
          *(const u32x4*)&Hb[r * 256 + c8 * 8];
    }
  }
}

// ffn2: psu = x2 + hidb @ fW2 + b2 (fp32 out + bf16 psub). grid 128. K=1024.
__global__ __launch_bounds__(256, 4) void ffn2_mfma(
    const unsigned short* __restrict__ hidb, const float* __restrict__ x2,
    const unsigned short* __restrict__ Wpack, const float* __restrict__ b2,
    float* __restrict__ psu_out, unsigned short* __restrict__ psub)
{
  __shared__ __align__(16) unsigned char smem[16 * CP3 * 4];
  unsigned short* Ah = (unsigned short*)smem;
  float* Cl = (float*)smem;
  const unsigned short* Wf = Wpack + 524288;
  int tid = threadIdx.x, lane = tid & 63, w = tid >> 6;
  int ln15 = lane & 15, hi = lane >> 4;
  int base = blockIdx.x * 16;

  f32x4 acc[4];
  #pragma unroll
  for (int c = 0; c < 4; c++) acc[c] = (f32x4){0.f, 0.f, 0.f, 0.f};
  const unsigned short* Wl = Wf + (size_t)lane * 8;

  for (int ch = 0; ch < 4; ch++) {
    __syncthreads();
    for (int i = tid; i < 16 * 32; i += 256) {
      int r = i >> 5, c8 = i & 31;
      *((u32x4*)&Ah[r * AP3 + c8 * 8]) =
          *(const u32x4*)(hidb + ((size_t)(base + r)) * FF + ch * 256 + c8 * 8);
    }
    __syncthreads();
    short8 bcur[4];
    #pragma unroll
    for (int ct = 0; ct < 4; ct++)
      bcur[ct] = *(const short8*)(Wl + ((w * 4 + ct) * 32 + ch * 8 + 0) * 512);
    #pragma unroll
    for (int kc = 0; kc < 8; kc++) {
      short8 a = *(const short8*)(&Ah[ln15 * AP3 + kc * 32 + hi * 8]);
      short8 bnext[4];
      if (kc < 7) {
        #pragma unroll
        for (int ct = 0; ct < 4; ct++)
          bnext[ct] = *(const short8*)(Wl + ((w * 4 + ct) * 32 + ch * 8 + kc + 1) * 512);
      }
      #pragma unroll
      for (int ct = 0; ct < 4; ct++)
        acc[ct] = __builtin_amdgcn_mfma_f32_16x16x32_bf16(a, bcur[ct], acc[ct], 0, 0, 0);
      if (kc < 7) {
        #pragma unroll
        for (int ct = 0; ct < 4; ct++) bcur[ct] = bnext[ct];
      }
    }
  }
  __syncthreads();

  #pragma unroll
  for (int ct = 0; ct < 4; ct++) {
    int col = w * 64 + ct * 16 + ln15;
    float bb = b2[col];
    #pragma unroll
    for (int r = 0; r < 4; r++)
      Cl[(hi * 4 + r) * CP3 + col] = acc[ct][r] + bb;
  }
  __syncthreads();
  for (int i = tid; i < 16 * 64; i += 256) {
    int r = i >> 6, c4 = i & 63;
    size_t gidx = ((size_t)(base + r)) * 256 + c4 * 4;
    float4 xv = *(const float4*)(x2 + gidx);
    float4 cv = *(const float4*)&Cl[r * CP3 + c4 * 4];
    float4 o = {xv.x + cv.x, xv.y + cv.y, xv.z + cv.z, xv.w + cv.w};
    *(float4*)(psu_out + gidx) = o;
    unsigned int lo = (unsigned int)f2bf(o.x) | ((unsigned int)f2bf(o.y) << 16);
    unsigned int h2 = (unsigned int)f2bf(o.z) | ((unsigned int)f2bf(o.w) << 16);
    u32x2 pb = {lo, h2};
    *(u32x2*)(psub + gidx) = pb;
  }
}

// kv[s,h,d,e] = sum_k k*v ; ksum. grid 128
__global__ __launch_bounds__(256) void kv_kernel(
    const float* __restrict__ kw, const float* __restrict__ vw,
    float* __restrict__ kvb, float* __restrict__ ksb)
{
  int b = blockIdx.x, t = threadIdx.x;
  int s = b / (NH * 8), h = (b / 8) % NH, ck = b & 7;
  __shared__ float kl[64 * 64];
  __shared__ float vl[64 * 64];
  for (int i = t; i < 4096; i += 256) {
    int kk = i >> 6, d = i & 63;
    size_t rowb = ((size_t)(s * KSEG + ck * 64 + kk) * NH + h) * HD + d;
    kl[i] = kw[rowb];
    vl[i] = vw[rowb];
  }
  __syncthreads();
  int d = t & 63, eb = (t >> 6) * 16;
  f32x4 a4[4];
  #pragma unroll
  for (int j = 0; j < 4; j++) a4[j] = (f32x4){0.f, 0.f, 0.f, 0.f};
  float acck = 0.f;
  #pragma unroll 4
  for (int kk = 0; kk < 64; kk++) {
    float kd = kl[kk * 64 + d];
    acck += kd;
    #pragma unroll
    for (int j = 0; j < 4; j++) {
      f32x4 vv = *(const f32x4*)&vl[kk * 64 + eb + j * 4];
      a4[j] += kd * vv;
    }
  }
  #pragma unroll
  for (int j = 0; j < 4; j++)
    #pragma unroll
    for (int e = 0; e < 4; e++)
      atomicAdd(&kvb[(((size_t)(s * NH + h)) * HD + d) * HD + eb + j * 4 + e], a4[j][e]);
  if (t < 64) atomicAdd(&ksb[(s * NH + h) * HD + t], acck);
}

// a = num/den per row. grid 256 blocks
__global__ __launch_bounds__(256) void attn_kernel(
    const float* __restrict__ qw, const float* __restrict__ kvb,
    const float* __restrict__ ksb, float* __restrict__ aw)
{
  __shared__ float kvl[64 * 64];
  __shared__ float ksl[64];
  __shared__ float ql[32 * 64];
  int t = threadIdx.x, b = blockIdx.x;
  int sh = b >> 4, rb = b & 15;
  int s = sh >> 2, h = sh & 3;
  for (int i = t; i < 4096; i += 256) kvl[i] = kvb[sh * 4096 + i];
  if (t < 64) ksl[t] = ksb[sh * 64 + t];
  for (int i = t; i < 2048; i += 256) {
    int r = i >> 6, d = i & 63;
    ql[i] = qw[((size_t)(s * KSEG + rb * 32 + r)) * 256 + h * 64 + d];
  }
  __syncthreads();
  int e = t & 63, rg = t >> 6;
  float num[8], den[8];
  #pragma unroll
  for (int r = 0; r < 8; r++) { num[r] = 0.f; den[r] = 0.f; }
  #pragma unroll 4
  for (int d4 = 0; d4 < 64; d4 += 4) {
    float4 ks4 = *(const float4*)&ksl[d4];
    float kv0 = kvl[(d4 + 0) * 64 + e];
    float kv1 = kvl[(d4 + 1) * 64 + e];
    float kv2 = kvl[(d4 + 2) * 64 + e];
    float kv3 = kvl[(d4 + 3) * 64 + e];
    #pragma unroll
    for (int r = 0; r < 8; r++) {
      float4 q4 = *(const float4*)&ql[(rg * 8 + r) * 64 + d4];
      num[r] += q4.x * kv0 + q4.y * kv1 + q4.z * kv2 + q4.w * kv3;
      den[r] += q4.x * ks4.x + q4.y * ks4.y + q4.z * ks4.z + q4.w * ks4.w;
    }
  }
  #pragma unroll
  for (int r = 0; r < 8; r++) {
    int row = rb * 32 + rg * 8 + r;
    aw[((size_t)(s * KSEG + row)) * 256 + h * 64 + e] = num[r] / (den[r] + 1e-6f);
  }
}

// ---------------- Phase C: fused node MLP (bf16 MFMA), v5 ----------------
// R6-proven structure; only change vs R10: launch_bounds (256,5) -> (256,6).
// Unified regfile: 48 VGPR + 32 AGPR = 80 <= 512/6 = 85 budget (no spill).
#define AP2 264
#define CP2 260
__global__ __launch_bounds__(256, 6) void node_mlp_kernel(
    const float* __restrict__ H, const int* __restrict__ pids,
    const unsigned short* __restrict__ psub,
    const unsigned short* __restrict__ W1f, const unsigned short* __restrict__ W2f,
    const float* __restrict__ b1, const float* __restrict__ b2,
    float* __restrict__ out)
{
  __shared__ __align__(16) unsigned char smem[32 * AP2 * 2];  // 16896 B
  __shared__ int pidl[32];
  unsigned short* Ah = (unsigned short*)smem;
  float* Cl = (float*)smem;
  int tid = threadIdx.x;
  int lane = tid & 63, w = tid >> 6;
  int ln15 = lane & 15, hi = lane >> 4;
  int base = blockIdx.x * 32;

  f32x4 acc[2][4];
  #pragma unroll
  for (int a = 0; a < 2; a++)
    #pragma unroll
    for (int c = 0; c < 4; c++) acc[a][c] = (f32x4){0.f, 0.f, 0.f, 0.f};

  // ---- stage 1: H cols 0..255 (fp32 -> bf16) ----
  if (tid < 32) pidl[tid] = pids[base + tid];
  #pragma unroll
  for (int k = 0; k < 8; k++) {
    int i = tid + k * 256;
    int r = i >> 6, c4 = i & 63;
    float4 f = *(const float4*)(H + ((size_t)(base + r)) * 256 + c4 * 4);
    unsigned int lo = (unsigned int)f2bf(f.x) | ((unsigned int)f2bf(f.y) << 16);
    unsigned int hi2 = (unsigned int)f2bf(f.z) | ((unsigned int)f2bf(f.w) << 16);
    u32x2 val = {lo, hi2};
    *((u32x2*)&Ah[r * AP2 + c4 * 4]) = val;
  }
  __syncthreads();  // B1

  const unsigned short* Wl1 = W1f + (size_t)lane * 8;
  // ---- GEMM1a kc 0..7 (K 0..255) ----
  {
    short8 bcur[4];
    #pragma unroll
    for (int ct = 0; ct < 4; ct++)
      bcur[ct] = *(const short8*)(Wl1 + ((w * 4 + ct) * 16 + 0) * 512);
    #pragma unroll
    for (int kc = 0; kc < 8; kc++) {
      short8 a[2], bnext[4];
      #pragma unroll
      for (int rt = 0; rt < 2; rt++)
        a[rt] = *(const short8*)(&Ah[(rt * 16 + ln15) * AP2 + kc * 32 + hi * 8]);
      if (kc < 7) {
        #pragma unroll
        for (int ct = 0; ct < 4; ct++)
          bnext[ct] = *(const short8*)(Wl1 + ((w * 4 + ct) * 16 + kc + 1) * 512);
      }
      __builtin_amdgcn_s_setprio(1);
      #pragma unroll
      for (int rt = 0; rt < 2; rt++)
        #pragma unroll
        for (int ct = 0; ct < 4; ct++)
          acc[rt][ct] = __builtin_amdgcn_mfma_f32_16x16x32_bf16(a[rt], bcur[ct], acc[rt][ct], 0, 0, 0);
      __builtin_amdgcn_s_setprio(0);
      if (kc < 7) {
        #pragma unroll
        for (int ct = 0; ct < 4; ct++) bcur[ct] = bnext[ct];
      }
    }
  }

  // ---- early-issue psu gather (loads in flight across B2) ----
  int ss = base >> 15;
  int r0 = tid >> 5, ch = tid & 31;
  int p0 = pidl[r0], p1 = pidl[8 + r0], p2 = pidl[16 + r0], p3 = pidl[24 + r0];
  const unsigned short* pbase = psub + (size_t)(ss * KSEG) * 256 + (size_t)ch * 8;
  u32x4 g0 = *(const u32x4*)(pbase + (size_t)p0 * 256);
  u32x4 g1 = *(const u32x4*)(pbase + (size_t)p1 * 256);
  u32x4 g2 = *(const u32x4*)(pbase + (size_t)p2 * 256);
  u32x4 g3 = *(const u32x4*)(pbase + (size_t)p3 * 256);
  __syncthreads();  // B2 (GEMM1a A-reads done)
  *(u32x4*)&Ah[r0 * AP2 + ch * 8] = g0;
  *(u32x4*)&Ah[(8 + r0) * AP2 + ch * 8] = g1;
  *(u32x4*)&Ah[(16 + r0) * AP2 + ch * 8] = g2;
  *(u32x4*)&Ah[(24 + r0) * AP2 + ch * 8] = g3;
  __syncthreads();  // B3

  // ---- GEMM1b kc 8..15 (K 256..511) ----
  {
    short8 bcur[4];
    #pragma unroll
    for (int ct = 0; ct < 4; ct++)
      bcur[ct] = *(const short8*)(Wl1 + ((w * 4 + ct) * 16 + 8) * 512);
    #pragma unroll
    for (int kc = 8; kc < 16; kc++) {
      short8 a[2], bnext[4];
      #pragma unroll
      for (int rt = 0; rt < 2; rt++)
        a[rt] = *(const short8*)(&Ah[(rt * 16 + ln15) * AP2 + (kc - 8) * 32 + hi * 8]);
      if (kc < 15) {
        #pragma unroll
        for (int ct = 0; ct < 4; ct++)
          bnext[ct] = *(const short8*)(Wl1 + ((w * 4 + ct) * 16 + kc + 1) * 512);
      }
      __builtin_amdgcn_s_setprio(1);
      #pragma unroll
      for (int rt = 0; rt < 2; rt++)
        #pragma unroll
        for (int ct = 0; ct < 4; ct++)
          acc[rt][ct] = __builtin_amdgcn_mfma_f32_16x16x32_bf16(a[rt], bcur[ct], acc[rt][ct], 0, 0, 0);
      __builtin_amdgcn_s_setprio(0);
      if (kc < 15) {
        #pragma unroll
        for (int ct = 0; ct < 4; ct++) bcur[ct] = bnext[ct];
      }
    }
  }
  __syncthreads();  // B4

  // ---- epi1: bias + gelu -> Hid (aliased over Ah) ----
  #pragma unroll
  for (int rt = 0; rt < 2; rt++) {
    #pragma unroll
    for (int ct = 0; ct < 4; ct++) {
      int col = w * 64 + ct * 16 + ln15;
      float bb = b1[col];
      #pragma unroll
      for (int r = 0; r < 4; r++) {
        int row = rt * 16 + hi * 4 + r;
        Ah[row * AP2 + col] = f2bf(gelu_f(acc[rt][ct][r] + bb));
      }
      acc[rt][ct] = (f32x4){0.f, 0.f, 0.f, 0.f};
    }
  }
  __syncthreads();  // B5

  // ---- GEMM2: [32x256] @ [256x256] ----
  {
    const unsigned short* Wl2 = W2f + (size_t)lane * 8;
    short8 bcur[4];
    #pragma unroll
    for (int ct = 0; ct < 4; ct++)
      bcur[ct] = *(const short8*)(Wl2 + ((w * 4 + ct) * 8 + 0) * 512);
    #pragma unroll
    for (int kc = 0; kc < 8; kc++) {
      short8 a[2], bnext[4];
      #pragma unroll
      for (int rt = 0; rt < 2; rt++)
        a[rt] = *(const short8*)(&Ah[(rt * 16 + ln15) * AP2 + kc * 32 + hi * 8]);
      if (kc < 7) {
        #pragma unroll
        for (int ct = 0; ct < 4; ct++)
          bnext[ct] = *(const short8*)(Wl2 + ((w * 4 + ct) * 8 + kc + 1) * 512);
      }
      __builtin_amdgcn_s_setprio(1);
      #pragma unroll
      for (int rt = 0; rt < 2; rt++)
        #pragma unroll
        for (int ct = 0; ct < 4; ct++)
          acc[rt][ct] = __builtin_amdgcn_mfma_f32_16x16x32_bf16(a[rt], bcur[ct], acc[rt][ct], 0, 0, 0);
      __builtin_amdgcn_s_setprio(0);
      if (kc < 7) {
        #pragma unroll
        for (int ct = 0; ct < 4; ct++) bcur[ct] = bnext[ct];
      }
    }
  }

  // ---- final epilogue: two 16-row LDS passes, H re-read from global ----
  #pragma unroll
  for (int rh = 0; rh < 2; rh++) {
    __syncthreads();  // GEMM2 Ah reads done (rh=0) / prior pass done (rh=1)
    #pragma unroll
    for (int ct = 0; ct < 4; ct++) {
      int col = w * 64 + ct * 16 + ln15;
      float bb = b2[col];
      #pragma unroll
      for (int r = 0; r < 4; r++)
        Cl[(hi * 4 + r) * CP2 + col] = acc[rh][ct][r] + bb;
    }
    __syncthreads();
    #pragma unroll
    for (int k2 = 0; k2 < 4; k2++) {
      int i = tid + k2 * 256;
      int r = i >> 6, c4 = i & 63;
      size_t gidx = ((size_t)(base + rh * 16 + r)) * 256 + c4 * 4;
      float4 hv = *(const float4*)(H + gidx);
      float4 cv = *(const float4*)&Cl[r * CP2 + c4 * 4];
      float4 o4 = {hv.x + cv.x, hv.y + cv.y, hv.z + cv.z, hv.w + cv.w};
      *(float4*)(out + gidx) = o4;
    }
  }
}

extern "C" void kernel_launch(void* const* d_in, const int* in_sizes, int n_in,
                              void* d_out, int out_size, void* d_ws, size_t ws_size,
                              hipStream_t stream) {
  (void)in_sizes; (void)n_in; (void)out_size; (void)ws_size;
  const float* H    = (const float*)d_in[0];
  const int*   pids = (const int*)d_in[1];
  const float* ln1g = (const float*)d_in[2];
  const float* ln1b = (const float*)d_in[3];
  const float* Wq   = (const float*)d_in[4];
  const float* bq   = (const float*)d_in[5];
  const float* Wk   = (const float*)d_in[6];
  const float* bk   = (const float*)d_in[7];
  const float* Wv   = (const float*)d_in[8];
  const float* bv   = (const float*)d_in[9];
  const float* Wo   = (const float*)d_in[10];
  const float* bo   = (const float*)d_in[11];
  const float* ln2g = (const float*)d_in[12];
  const float* ln2b = (const float*)d_in[13];
  const float* fW1  = (const float*)d_in[14];
  const float* fb1  = (const float*)d_in[15];
  const float* fW2  = (const float*)d_in[16];
  const float* fb2  = (const float*)d_in[17];
  const float* mW1  = (const float*)d_in[18];
  const float* mb1  = (const float*)d_in[19];
  const float* mW2  = (const float*)d_in[20];
  const float* mb2  = (const float*)d_in[21];
  float* out = (float*)d_out;
  float* ws = (float*)d_ws;

  int*   histc   = (int*)ws;                          // (32768)
  int*   segstart= (int*)(ws + 32768);                // (2048)
  int*   cnti    = (int*)(ws + 34816);                // (2048)
  int*   order   = (int*)(ws + 36864);                // (131072)
  float* counts  = ws + 167936;                       // (2048)
  float* xw      = ws + 169984;                       // (524288)
  float* yw      = ws + 694272;                       // (524288)
  float* qw      = ws + 1218560;                      // (524288)
  float* kw      = ws + 1742848;                      // (524288)
  float* vw      = ws + 2267136;                      // (524288)
  float* kvb     = ws + 2791424;                      // (65536)
  float* ksb     = ws + 2856960;                      // (1024)
  float* aw      = ws + 2857984;                      // (524288)
  float* x2w     = ws + 3382272;                      // (524288)
  float* y2w     = ws + 3906560;                      // (524288)
  unsigned short* hidb  = (unsigned short*)(ws + 4430848);  // 2M shorts
  unsigned short* psub  = (unsigned short*)(ws + 5479424);  // 512K shorts
  unsigned short* Wpack = (unsigned short*)(ws + 5741568);  // 983040 shorts

  hipMemsetAsync(kvb, 0, (65536 + 1024) * sizeof(float), stream);

  wprep2_kernel<<<480, 256, 0, stream>>>(Wq, Wk, Wv, Wo, fW1, fW2, mW1, mW2, Wpack);
  hist_kernel<<<64, 256, 0, stream>>>(pids, histc);
  prefix_kernel<<<4, 256, 0, stream>>>(histc, segstart, cnti, counts);
  scatter_kernel<<<64, 256, 0, stream>>>(pids, histc, order);
  pool_gather<<<1024, 256, 0, stream>>>(H, order, segstart, cnti, ln1g, ln1b, xw, yw);
  qkv_all<<<128, 256, 0, stream>>>(yw, counts, Wpack, bq, bk, bv, qw, kw, vw);
  kv_kernel<<<128, 256, 0, stream>>>(kw, vw, kvb, ksb);
  attn_kernel<<<256, 256, 0, stream>>>(qw, kvb, ksb, aw);
  oproj_mfma<<<128, 256, 0, stream>>>(aw, xw, Wpack, bo, ln2g, ln2b, x2w, y2w);
  ffn1_all<<<128, 256, 0, stream>>>(y2w, Wpack, fb1, hidb);
  ffn2_mfma<<<128, 256, 0, stream>>>(hidb, x2w, Wpack, fb2,
                                     out + (size_t)S * N * D, psub);
  node_mlp_kernel<<<4096, 256, 0, stream>>>(H, pids, psub,
                                            Wpack + 786432, Wpack + 917504,
                                            mb1, mb2, out);
}

// Round 12
// 250.392 us; speedup vs baseline: 1.9376x; 1.9376x over previous
//
#include <hip/hip_runtime.h>
#include <hip/hip_bf16.h>

#define S 4
#define N 32768
#define D 256
#define KSEG 512
#define NH 4
#define HD 64
#define FF 1024

typedef __attribute__((ext_vector_type(8))) short short8;
typedef __attribute__((ext_vector_type(4))) float f32x4;
typedef __attribute__((ext_vector_type(4))) unsigned int u32x4;
typedef __attribute__((ext_vector_type(2))) unsigned int u32x2;

__device__ __forceinline__ unsigned short f2bf(float f) {
  union { __hip_bfloat16 h; unsigned short u; } cv;
  cv.h = __float2bfloat16(f);
  return cv.u;
}

__device__ __forceinline__ float gelu_f(float x) {
  return 0.5f * x * (1.0f + erff(x * 0.70710678118654752440f));
}

__device__ __forceinline__ float wave_reduce_sum(float v) {
  #pragma unroll
  for (int o = 32; o > 0; o >>= 1) v += __shfl_xor(v, o, 64);
  return v;
}

// ---------------- Phase A: counting sort by patch id ----------------
__global__ __launch_bounds__(256) void hist_kernel(
    const int* __restrict__ pids, int* __restrict__ histc)
{
  __shared__ int h[KSEG];
  int b = blockIdx.x, t = threadIdx.x;
  int s = b >> 4, c = b & 15;
  for (int i = t; i < KSEG; i += 256) h[i] = 0;
  __syncthreads();
  const int* p = pids + s * N + c * 2048;
  for (int i = t; i < 2048; i += 256) atomicAdd(&h[p[i]], 1);
  __syncthreads();
  for (int i = t; i < KSEG; i += 256) histc[(s * 16 + c) * KSEG + i] = h[i];
}

__global__ __launch_bounds__(256) void prefix_kernel(
    int* __restrict__ histc, int* __restrict__ segstart,
    int* __restrict__ cnti, float* __restrict__ counts)
{
  __shared__ int h[16 * KSEG];   // 32 KB
  __shared__ int sc[KSEG];
  __shared__ int sa[KSEG], sb[KSEG];
  int s = blockIdx.x, t = threadIdx.x;
  for (int i = t; i < 16 * KSEG; i += 256) h[i] = histc[s * 16 * KSEG + i];
  __syncthreads();
  #pragma unroll
  for (int u = 0; u < 2; u++) {
    int bin = t + u * 256;
    int cc = 0;
    #pragma unroll
    for (int c = 0; c < 16; c++) cc += h[c * KSEG + bin];
    sc[bin] = cc;
    sa[bin] = cc;
  }
  __syncthreads();
  int* src = sa; int* dst = sb;
  for (int off = 1; off < KSEG; off <<= 1) {
    #pragma unroll
    for (int u = 0; u < 2; u++) {
      int bin = t + u * 256;
      int v = src[bin];
      if (bin >= off) v += src[bin - off];
      dst[bin] = v;
    }
    __syncthreads();
    int* tmp = src; src = dst; dst = tmp;
  }
  #pragma unroll
  for (int u = 0; u < 2; u++) {
    int bin = t + u * 256;
    int cc = sc[bin];
    int excl = src[bin] - cc;
    segstart[s * KSEG + bin] = excl;
    cnti[s * KSEG + bin] = cc;
    counts[s * KSEG + bin] = (float)cc;
    int run = excl;
    #pragma unroll
    for (int c = 0; c < 16; c++) {
      int v = h[c * KSEG + bin];
      h[c * KSEG + bin] = run;
      run += v;
    }
  }
  __syncthreads();
  for (int i = t; i < 16 * KSEG; i += 256) histc[s * 16 * KSEG + i] = h[i];
}

__global__ __launch_bounds__(256) void scatter_kernel(
    const int* __restrict__ pids, const int* __restrict__ histc,
    int* __restrict__ order)
{
  __shared__ int offs[KSEG];
  int b = blockIdx.x, t = threadIdx.x;
  int s = b >> 4, c = b & 15;
  for (int i = t; i < KSEG; i += 256) offs[i] = histc[(s * 16 + c) * KSEG + i];
  __syncthreads();
  const int* p = pids + s * N + c * 2048;
  for (int i = t; i < 2048; i += 256) {
    int pid = p[i];
    int pos = atomicAdd(&offs[pid], 1);
    order[s * N + pos] = s * N + c * 2048 + i;
  }
}

// gather-reduce + fused LN1: TWO waves per segment. grid 1024.
__global__ __launch_bounds__(256) void pool_gather(
    const float* __restrict__ H, const int* __restrict__ order,
    const int* __restrict__ segstart, const int* __restrict__ cnti,
    const float* __restrict__ g, const float* __restrict__ bta,
    float* __restrict__ xw, float* __restrict__ yw)
{
  __shared__ float pbuf[4][256];
  int tid = threadIdx.x;
  int w = tid >> 6, lane = tid & 63;
  int seg = blockIdx.x * 2 + (w >> 1);
  int half = w & 1;
  int s = seg >> 9;
  int st = segstart[seg], cn = cnti[seg];
  int en = st + cn;
  const int* ord = order + (size_t)s * N;
  int c4 = lane << 2;
  f32x4 a0 = {0,0,0,0}, a1 = {0,0,0,0}, a2 = {0,0,0,0}, a3 = {0,0,0,0};
  f32x4 a4 = {0,0,0,0}, a5 = {0,0,0,0}, a6 = {0,0,0,0}, a7 = {0,0,0,0};
  int i = st + half;
  for (; i + 14 < en; i += 16) {
    int r0 = ord[i + 0], r1 = ord[i + 2], r2 = ord[i + 4], r3 = ord[i + 6];
    int r4 = ord[i + 8], r5 = ord[i + 10], r6 = ord[i + 12], r7 = ord[i + 14];
    a0 += *(const f32x4*)(H + (size_t)r0 * 256 + c4);
    a1 += *(const f32x4*)(H + (size_t)r1 * 256 + c4);
    a2 += *(const f32x4*)(H + (size_t)r2 * 256 + c4);
    a3 += *(const f32x4*)(H + (size_t)r3 * 256 + c4);
    a4 += *(const f32x4*)(H + (size_t)r4 * 256 + c4);
    a5 += *(const f32x4*)(H + (size_t)r5 * 256 + c4);
    a6 += *(const f32x4*)(H + (size_t)r6 * 256 + c4);
    a7 += *(const f32x4*)(H + (size_t)r7 * 256 + c4);
  }
  for (; i < en; i += 2) {
    int r = ord[i];
    a0 += *(const f32x4*)(H + (size_t)r * 256 + c4);
  }
  f32x4 ssum = ((a0 + a1) + (a2 + a3)) + ((a4 + a5) + (a6 + a7));
  *(f32x4*)&pbuf[w][c4] = ssum;
  __syncthreads();
  if (half == 0) {
    f32x4 tot = *(f32x4*)&pbuf[w][c4];
    tot += *(f32x4*)&pbuf[w + 1][c4];
    float inv = 1.f / fmaxf((float)cn, 1.f);
    tot = tot * inv;
    *(f32x4*)(xw + (size_t)seg * 256 + c4) = tot;
    // fused LN1
    float s1 = tot[0] + tot[1] + tot[2] + tot[3];
    float s2 = tot[0]*tot[0] + tot[1]*tot[1] + tot[2]*tot[2] + tot[3]*tot[3];
    s1 = wave_reduce_sum(s1);
    s2 = wave_reduce_sum(s2);
    float mu = s1 * (1.f / 256.f);
    float var = s2 * (1.f / 256.f) - mu * mu;
    float rs = rsqrtf(var + 1e-5f);
    float4 g4 = *(const float4*)(g + c4);
    float4 b4 = *(const float4*)(bta + c4);
    float4 yv = {(tot[0]-mu)*rs*g4.x + b4.x, (tot[1]-mu)*rs*g4.y + b4.y,
                 (tot[2]-mu)*rs*g4.z + b4.z, (tot[3]-mu)*rs*g4.w + b4.w};
    *(float4*)(yw + (size_t)seg * 256 + c4) = yv;
  }
}

// ---------------- weight pre-pack: all 8 matrices into fragment order ----
__global__ __launch_bounds__(256) void wprep2_kernel(
    const float* __restrict__ Wq, const float* __restrict__ Wk,
    const float* __restrict__ Wv, const float* __restrict__ Wo,
    const float* __restrict__ fW1, const float* __restrict__ fW2,
    const float* __restrict__ mW1, const float* __restrict__ mW2,
    unsigned short* __restrict__ Wpack)
{
  int fi = blockIdx.x * 256 + threadIdx.x;   // 0..122879
  const float* src; int ld, colbase, kcbits; size_t outb; int rfi;
  if (fi < 32768) {
    int m = fi >> 13; rfi = fi & 8191;
    src = (m == 0) ? Wq : ((m == 1) ? Wk : ((m == 2) ? Wv : Wo));
    ld = 256; colbase = 0; kcbits = 3; outb = (size_t)m * 65536;
  } else if (fi < 65536) {
    rfi = fi - 32768; int cc = rfi >> 13; rfi &= 8191;
    src = fW1; ld = 1024; colbase = cc * 256; kcbits = 3;
    outb = 262144 + (size_t)cc * 65536;
  } else if (fi < 98304) {
    rfi = fi - 65536; src = fW2; ld = 256; colbase = 0; kcbits = 5; outb = 524288;
  } else if (fi < 114688) {
    rfi = fi - 98304; src = mW1; ld = 256; colbase = 0; kcbits = 4; outb = 786432;
  } else {
    rfi = fi - 114688; src = mW2; ld = 256; colbase = 0; kcbits = 3; outb = 917504;
  }
  int tile = rfi >> 6, lane = rfi & 63;
  int c = tile >> kcbits, kc = tile & ((1 << kcbits) - 1);
  int k0 = kc * 32 + (lane >> 4) * 8;
  int col = colbase + c * 16 + (lane & 15);
  unsigned int p[4];
  #pragma unroll
  for (int jj = 0; jj < 4; jj++) {
    unsigned int lo = f2bf(src[(size_t)(k0 + 2 * jj) * ld + col]);
    unsigned int hi = f2bf(src[(size_t)(k0 + 2 * jj + 1) * ld + col]);
    p[jj] = lo | (hi << 16);
  }
  u32x4 v = {p[0], p[1], p[2], p[3]};
  *(u32x4*)&Wpack[outb + (size_t)rfi * 8] = v;
}

// ---------------- MFMA patch-GEMM template pieces (16 rows x 256 cols) ----
#define AP3 264  // A row stride (bf16): 256 + 8 pad
#define CP3 260  // C row stride (f32): 256 + 4 pad

// QKV: grid (128, 3). epilogue: phi (m<=1), mask (m>=1).
__global__ __launch_bounds__(256, 4) void qkv_mfma(
    const float* __restrict__ y, const float* __restrict__ counts,
    const unsigned short* __restrict__ Wpack,
    const float* __restrict__ bq, const float* __restrict__ bk,
    const float* __restrict__ bv,
    float* __restrict__ qo, float* __restrict__ ko, float* __restrict__ vo)
{
  __shared__ __align__(16) unsigned char smem[16 * CP3 * 4];  // 16640 B
  unsigned short* Ah = (unsigned short*)smem;
  float* Cl = (float*)smem;
  int m = blockIdx.y;
  const unsigned short* Wf = Wpack + (size_t)m * 65536;
  const float* bias = (m == 0) ? bq : ((m == 1) ? bk : bv);
  float* outp = (m == 0) ? qo : ((m == 1) ? ko : vo);
  int tid = threadIdx.x, lane = tid & 63, w = tid >> 6;
  int ln15 = lane & 15, hi = lane >> 4;
  int base = blockIdx.x * 16;

  for (int i = tid; i < 16 * 64; i += 256) {
    int r = i >> 6, c4 = i & 63;
    float4 f = *(const float4*)(y + ((size_t)(base + r)) * 256 + c4 * 4);
    unsigned int lo = (unsigned int)f2bf(f.x) | ((unsigned int)f2bf(f.y) << 16);
    unsigned int h2 = (unsigned int)f2bf(f.z) | ((unsigned int)f2bf(f.w) << 16);
    u32x2 val = {lo, h2};
    *((u32x2*)&Ah[r * AP3 + c4 * 4]) = val;
  }
  __syncthreads();

  f32x4 acc[4];
  #pragma unroll
  for (int c = 0; c < 4; c++) acc[c] = (f32x4){0.f, 0.f, 0.f, 0.f};
  const unsigned short* Wl = Wf + (size_t)lane * 8;
  short8 bcur[4];
  #pragma unroll
  for (int ct = 0; ct < 4; ct++)
    bcur[ct] = *(const short8*)(Wl + ((w * 4 + ct) * 8 + 0) * 512);
  #pragma unroll
  for (int kc = 0; kc < 8; kc++) {
    short8 a = *(const short8*)(&Ah[ln15 * AP3 + kc * 32 + hi * 8]);
    short8 bnext[4];
    if (kc < 7) {
      #pragma unroll
      for (int ct = 0; ct < 4; ct++)
        bnext[ct] = *(const short8*)(Wl + ((w * 4 + ct) * 8 + kc + 1) * 512);
    }
    #pragma unroll
    for (int ct = 0; ct < 4; ct++)
      acc[ct] = __builtin_amdgcn_mfma_f32_16x16x32_bf16(a, bcur[ct], acc[ct], 0, 0, 0);
    if (kc < 7) {
      #pragma unroll
      for (int ct = 0; ct < 4; ct++) bcur[ct] = bnext[ct];
    }
  }
  __syncthreads();  // A reads done; reuse smem as Cl

  float mk[4];
  #pragma unroll
  for (int r = 0; r < 4; r++)
    mk[r] = (counts[base + hi * 4 + r] > 0.f) ? 1.f : 0.f;
  #pragma unroll
  for (int ct = 0; ct < 4; ct++) {
    int col = w * 64 + ct * 16 + ln15;
    float bb = bias[col];
    #pragma unroll
    for (int r = 0; r < 4; r++) {
      float tv = acc[ct][r] + bb;
      if (m <= 1) tv = (tv > 0.f) ? (tv + 1.f) : expf(tv);
      if (m >= 1) tv *= mk[r];
      Cl[(hi * 4 + r) * CP3 + col] = tv;
    }
  }
  __syncthreads();
  for (int i = tid; i < 16 * 64; i += 256) {
    int r = i >> 6, c4 = i & 63;
    *(float4*)(outp + ((size_t)(base + r)) * 256 + c4 * 4) =
        *(const float4*)&Cl[r * CP3 + c4 * 4];
  }
}

// oproj + fused LN2: x2 = x + a@Wo + bo; y2 = LN(x2). grid 128.
__global__ __launch_bounds__(256, 4) void oproj_mfma(
    const float* __restrict__ aw, const float* __restrict__ xw,
    const unsigned short* __restrict__ Wpack, const float* __restrict__ bo,
    const float* __restrict__ g, const float* __restrict__ bta,
    float* __restrict__ x2, float* __restrict__ y2)
{
  __shared__ __align__(16) unsigned char smem[16 * CP3 * 4];
  unsigned short* Ah = (unsigned short*)smem;
  float* Cl = (float*)smem;
  const unsigned short* Wf = Wpack + 196608;
  int tid = threadIdx.x, lane = tid & 63, w = tid >> 6;
  int ln15 = lane & 15, hi = lane >> 4;
  int base = blockIdx.x * 16;

  for (int i = tid; i < 16 * 64; i += 256) {
    int r = i >> 6, c4 = i & 63;
    float4 f = *(const float4*)(aw + ((size_t)(base + r)) * 256 + c4 * 4);
    unsigned int lo = (unsigned int)f2bf(f.x) | ((unsigned int)f2bf(f.y) << 16);
    unsigned int h2 = (unsigned int)f2bf(f.z) | ((unsigned int)f2bf(f.w) << 16);
    u32x2 val = {lo, h2};
    *((u32x2*)&Ah[r * AP3 + c4 * 4]) = val;
  }
  __syncthreads();

  f32x4 acc[4];
  #pragma unroll
  for (int c = 0; c < 4; c++) acc[c] = (f32x4){0.f, 0.f, 0.f, 0.f};
  const unsigned short* Wl = Wf + (size_t)lane * 8;
  short8 bcur[4];
  #pragma unroll
  for (int ct = 0; ct < 4; ct++)
    bcur[ct] = *(const short8*)(Wl + ((w * 4 + ct) * 8 + 0) * 512);
  #pragma unroll
  for (int kc = 0; kc < 8; kc++) {
    short8 a = *(const short8*)(&Ah[ln15 * AP3 + kc * 32 + hi * 8]);
    short8 bnext[4];
    if (kc < 7) {
      #pragma unroll
      for (int ct = 0; ct < 4; ct++)
        bnext[ct] = *(const short8*)(Wl + ((w * 4 + ct) * 8 + kc + 1) * 512);
    }
    #pragma unroll
    for (int ct = 0; ct < 4; ct++)
      acc[ct] = __builtin_amdgcn_mfma_f32_16x16x32_bf16(a, bcur[ct], acc[ct], 0, 0, 0);
    if (kc < 7) {
      #pragma unroll
      for (int ct = 0; ct < 4; ct++) bcur[ct] = bnext[ct];
    }
  }
  __syncthreads();

  #pragma unroll
  for (int ct = 0; ct < 4; ct++) {
    int col = w * 64 + ct * 16 + ln15;
    float bb = bo[col];
    #pragma unroll
    for (int r = 0; r < 4; r++)
      Cl[(hi * 4 + r) * CP3 + col] = acc[ct][r] + bb;
  }
  __syncthreads();
  // fused residual + LN2: wave w handles rows {4k + w}
  int c4 = lane << 2;
  float4 g4 = *(const float4*)(g + c4);
  float4 b4 = *(const float4*)(bta + c4);
  #pragma unroll
  for (int k = 0; k < 4; k++) {
    int r = k * 4 + w;
    size_t gbase = ((size_t)(base + r)) * 256 + c4;
    float4 xv = *(const float4*)(xw + gbase);
    float4 cv = *(const float4*)&Cl[r * CP3 + c4];
    float4 x2v = {xv.x + cv.x, xv.y + cv.y, xv.z + cv.z, xv.w + cv.w};
    *(float4*)(x2 + gbase) = x2v;
    float s1 = x2v.x + x2v.y + x2v.z + x2v.w;
    float s2 = x2v.x*x2v.x + x2v.y*x2v.y + x2v.z*x2v.z + x2v.w*x2v.w;
    s1 = wave_reduce_sum(s1);
    s2 = wave_reduce_sum(s2);
    float mu = s1 * (1.f / 256.f);
    float var = s2 * (1.f / 256.f) - mu * mu;
    float rs = rsqrtf(var + 1e-5f);
    float4 yv = {(x2v.x-mu)*rs*g4.x + b4.x, (x2v.y-mu)*rs*g4.y + b4.y,
                 (x2v.z-mu)*rs*g4.z + b4.z, (x2v.w-mu)*rs*g4.w + b4.w};
    *(float4*)(y2 + gbase) = yv;
  }
}

// ffn1: hidb = bf16(gelu(y2 @ fW1 + b1)). grid (128, 4 col-chunks).
__global__ __launch_bounds__(256, 4) void ffn1_mfma(
    const float* __restrict__ y2, const unsigned short* __restrict__ Wpack,
    const float* __restrict__ b1, unsigned short* __restrict__ hidb)
{
  __shared__ __align__(16) unsigned char smem[16 * CP3 * 4];
  unsigned short* Ah = (unsigned short*)smem;
  int cc = blockIdx.y;
  const unsigned short* Wf = Wpack + 262144 + (size_t)cc * 65536;
  int tid = threadIdx.x, lane = tid & 63, w = tid >> 6;
  int ln15 = lane & 15, hi = lane >> 4;
  int base = blockIdx.x * 16;

  for (int i = tid; i < 16 * 64; i += 256) {
    int r = i >> 6, c4 = i & 63;
    float4 f = *(const float4*)(y2 + ((size_t)(base + r)) * 256 + c4 * 4);
    unsigned int lo = (unsigned int)f2bf(f.x) | ((unsigned int)f2bf(f.y) << 16);
    unsigned int h2 = (unsigned int)f2bf(f.z) | ((unsigned int)f2bf(f.w) << 16);
    u32x2 val = {lo, h2};
    *((u32x2*)&Ah[r * AP3 + c4 * 4]) = val;
  }
  __syncthreads();

  f32x4 acc[4];
  #pragma unroll
  for (int c = 0; c < 4; c++) acc[c] = (f32x4){0.f, 0.f, 0.f, 0.f};
  const unsigned short* Wl = Wf + (size_t)lane * 8;
  short8 bcur[4];
  #pragma unroll
  for (int ct = 0; ct < 4; ct++)
    bcur[ct] = *(const short8*)(Wl + ((w * 4 + ct) * 8 + 0) * 512);
  #pragma unroll
  for (int kc = 0; kc < 8; kc++) {
    short8 a = *(const short8*)(&Ah[ln15 * AP3 + kc * 32 + hi * 8]);
    short8 bnext[4];
    if (kc < 7) {
      #pragma unroll
      for (int ct = 0; ct < 4; ct++)
        bnext[ct] = *(const short8*)(Wl + ((w * 4 + ct) * 8 + kc + 1) * 512);
    }
    #pragma unroll
    for (int ct = 0; ct < 4; ct++)
      acc[ct] = __builtin_amdgcn_mfma_f32_16x16x32_bf16(a, bcur[ct], acc[ct], 0, 0, 0);
    if (kc < 7) {
      #pragma unroll
      for (int ct = 0; ct < 4; ct++) bcur[ct] = bnext[ct];
    }
  }
  __syncthreads();

  #pragma unroll
  for (int ct = 0; ct < 4; ct++) {
    int col = w * 64 + ct * 16 + ln15;
    float bb = b1[cc * 256 + col];
    #pragma unroll
    for (int r = 0; r < 4; r++)
      Ah[(hi * 4 + r) * 256 + col] = f2bf(gelu_f(acc[ct][r] + bb));
  }
  __syncthreads();
  for (int i = tid; i < 16 * 32; i += 256) {
    int r = i >> 5, c8 = i & 31;
    *(u32x4*)(hidb + ((size_t)(base + r)) * FF + cc * 256 + c8 * 8) =
        *(const u32x4*)&Ah[r * 256 + c8 * 8];
  }
}

// ffn2: psu = x2 + hidb @ fW2 + b2 (fp32 out + bf16 psub). grid 128. K=1024.
__global__ __launch_bounds__(256, 4) void ffn2_mfma(
    const unsigned short* __restrict__ hidb, const float* __restrict__ x2,
    const unsigned short* __restrict__ Wpack, const float* __restrict__ b2,
    float* __restrict__ psu_out, unsigned short* __restrict__ psub)
{
  __shared__ __align__(16) unsigned char smem[16 * CP3 * 4];
  unsigned short* Ah = (unsigned short*)smem;
  float* Cl = (float*)smem;
  const unsigned short* Wf = Wpack + 524288;
  int tid = threadIdx.x, lane = tid & 63, w = tid >> 6;
  int ln15 = lane & 15, hi = lane >> 4;
  int base = blockIdx.x * 16;

  f32x4 acc[4];
  #pragma unroll
  for (int c = 0; c < 4; c++) acc[c] = (f32x4){0.f, 0.f, 0.f, 0.f};
  const unsigned short* Wl = Wf + (size_t)lane * 8;

  for (int ch = 0; ch < 4; ch++) {
    __syncthreads();
    for (int i = tid; i < 16 * 32; i += 256) {
      int r = i >> 5, c8 = i & 31;
      *((u32x4*)&Ah[r * AP3 + c8 * 8]) =
          *(const u32x4*)(hidb + ((size_t)(base + r)) * FF + ch * 256 + c8 * 8);
    }
    __syncthreads();
    short8 bcur[4];
    #pragma unroll
    for (int ct = 0; ct < 4; ct++)
      bcur[ct] = *(const short8*)(Wl + ((w * 4 + ct) * 32 + ch * 8 + 0) * 512);
    #pragma unroll
    for (int kc = 0; kc < 8; kc++) {
      short8 a = *(const short8*)(&Ah[ln15 * AP3 + kc * 32 + hi * 8]);
      short8 bnext[4];
      if (kc < 7) {
        #pragma unroll
        for (int ct = 0; ct < 4; ct++)
          bnext[ct] = *(const short8*)(Wl + ((w * 4 + ct) * 32 + ch * 8 + kc + 1) * 512);
      }
      #pragma unroll
      for (int ct = 0; ct < 4; ct++)
        acc[ct] = __builtin_amdgcn_mfma_f32_16x16x32_bf16(a, bcur[ct], acc[ct], 0, 0, 0);
      if (kc < 7) {
        #pragma unroll
        for (int ct = 0; ct < 4; ct++) bcur[ct] = bnext[ct];
      }
    }
  }
  __syncthreads();

  #pragma unroll
  for (int ct = 0; ct < 4; ct++) {
    int col = w * 64 + ct * 16 + ln15;
    float bb = b2[col];
    #pragma unroll
    for (int r = 0; r < 4; r++)
      Cl[(hi * 4 + r) * CP3 + col] = acc[ct][r] + bb;
  }
  __syncthreads();
  for (int i = tid; i < 16 * 64; i += 256) {
    int r = i >> 6, c4 = i & 63;
    size_t gidx = ((size_t)(base + r)) * 256 + c4 * 4;
    float4 xv = *(const float4*)(x2 + gidx);
    float4 cv = *(const float4*)&Cl[r * CP3 + c4 * 4];
    float4 o = {xv.x + cv.x, xv.y + cv.y, xv.z + cv.z, xv.w + cv.w};
    *(float4*)(psu_out + gidx) = o;
    unsigned int lo = (unsigned int)f2bf(o.x) | ((unsigned int)f2bf(o.y) << 16);
    unsigned int h2 = (unsigned int)f2bf(o.z) | ((unsigned int)f2bf(o.w) << 16);
    u32x2 pb = {lo, h2};
    *(u32x2*)(psub + gidx) = pb;
  }
}

// kv[s,h,d,e] = sum_k k*v ; ksum. grid 128
__global__ __launch_bounds__(256) void kv_kernel(
    const float* __restrict__ kw, const float* __restrict__ vw,
    float* __restrict__ kvb, float* __restrict__ ksb)
{
  int b = blockIdx.x, t = threadIdx.x;
  int s = b / (NH * 8), h = (b / 8) % NH, ck = b & 7;
  __shared__ float kl[64 * 64];
  __shared__ float vl[64 * 64];
  for (int i = t; i < 4096; i += 256) {
    int kk = i >> 6, d = i & 63;
    size_t rowb = ((size_t)(s * KSEG + ck * 64 + kk) * NH + h) * HD + d;
    kl[i] = kw[rowb];
    vl[i] = vw[rowb];
  }
  __syncthreads();
  int d = t & 63, eb = (t >> 6) * 16;
  f32x4 a4[4];
  #pragma unroll
  for (int j = 0; j < 4; j++) a4[j] = (f32x4){0.f, 0.f, 0.f, 0.f};
  float acck = 0.f;
  #pragma unroll 4
  for (int kk = 0; kk < 64; kk++) {
    float kd = kl[kk * 64 + d];
    acck += kd;
    #pragma unroll
    for (int j = 0; j < 4; j++) {
      f32x4 vv = *(const f32x4*)&vl[kk * 64 + eb + j * 4];
      a4[j] += kd * vv;
    }
  }
  #pragma unroll
  for (int j = 0; j < 4; j++)
    #pragma unroll
    for (int e = 0; e < 4; e++)
      atomicAdd(&kvb[(((size_t)(s * NH + h)) * HD + d) * HD + eb + j * 4 + e], a4[j][e]);
  if (t < 64) atomicAdd(&ksb[(s * NH + h) * HD + t], acck);
}

// a = num/den per row. grid 256 blocks
__global__ __launch_bounds__(256) void attn_kernel(
    const float* __restrict__ qw, const float* __restrict__ kvb,
    const float* __restrict__ ksb, float* __restrict__ aw)
{
  __shared__ float kvl[64 * 64];
  __shared__ float ksl[64];
  __shared__ float ql[32 * 64];
  int t = threadIdx.x, b = blockIdx.x;
  int sh = b >> 4, rb = b & 15;
  int s = sh >> 2, h = sh & 3;
  for (int i = t; i < 4096; i += 256) kvl[i] = kvb[sh * 4096 + i];
  if (t < 64) ksl[t] = ksb[sh * 64 + t];
  for (int i = t; i < 2048; i += 256) {
    int r = i >> 6, d = i & 63;
    ql[i] = qw[((size_t)(s * KSEG + rb * 32 + r)) * 256 + h * 64 + d];
  }
  __syncthreads();
  int e = t & 63, rg = t >> 6;
  float num[8], den[8];
  #pragma unroll
  for (int r = 0; r < 8; r++) { num[r] = 0.f; den[r] = 0.f; }
  #pragma unroll 4
  for (int d4 = 0; d4 < 64; d4 += 4) {
    float4 ks4 = *(const float4*)&ksl[d4];
    float kv0 = kvl[(d4 + 0) * 64 + e];
    float kv1 = kvl[(d4 + 1) * 64 + e];
    float kv2 = kvl[(d4 + 2) * 64 + e];
    float kv3 = kvl[(d4 + 3) * 64 + e];
    #pragma unroll
    for (int r = 0; r < 8; r++) {
      float4 q4 = *(const float4*)&ql[(rg * 8 + r) * 64 + d4];
      num[r] += q4.x * kv0 + q4.y * kv1 + q4.z * kv2 + q4.w * kv3;
      den[r] += q4.x * ks4.x + q4.y * ks4.y + q4.z * ks4.z + q4.w * ks4.w;
    }
  }
  #pragma unroll
  for (int r = 0; r < 8; r++) {
    int row = rb * 32 + rg * 8 + r;
    aw[((size_t)(s * KSEG + row)) * 256 + h * 64 + e] = num[r] / (den[r] + 1e-6f);
  }
}

// ---------------- Phase C: fused node MLP (bf16 MFMA), v6 ----------------
// R10-proven structure at (256,5). One change: T14 early-issue of the
// epilogue H re-reads (4 float4, statically indexed, live across 2 barriers
// -- same bounded pattern as the proven psu gather).
#define AP2 264
#define CP2 260
__global__ __launch_bounds__(256, 5) void node_mlp_kernel(
    const float* __restrict__ H, const int* __restrict__ pids,
    const unsigned short* __restrict__ psub,
    const unsigned short* __restrict__ W1f, const unsigned short* __restrict__ W2f,
    const float* __restrict__ b1, const float* __restrict__ b2,
    float* __restrict__ out)
{
  __shared__ __align__(16) unsigned char smem[32 * AP2 * 2];  // 16896 B
  __shared__ int pidl[32];
  unsigned short* Ah = (unsigned short*)smem;
  float* Cl = (float*)smem;
  int tid = threadIdx.x;
  int lane = tid & 63, w = tid >> 6;
  int ln15 = lane & 15, hi = lane >> 4;
  int base = blockIdx.x * 32;

  f32x4 acc[2][4];
  #pragma unroll
  for (int a = 0; a < 2; a++)
    #pragma unroll
    for (int c = 0; c < 4; c++) acc[a][c] = (f32x4){0.f, 0.f, 0.f, 0.f};

  // ---- stage 1: H cols 0..255 (fp32 -> bf16) ----
  if (tid < 32) pidl[tid] = pids[base + tid];
  #pragma unroll
  for (int k = 0; k < 8; k++) {
    int i = tid + k * 256;
    int r = i >> 6, c4 = i & 63;
    float4 f = *(const float4*)(H + ((size_t)(base + r)) * 256 + c4 * 4);
    unsigned int lo = (unsigned int)f2bf(f.x) | ((unsigned int)f2bf(f.y) << 16);
    unsigned int hi2 = (unsigned int)f2bf(f.z) | ((unsigned int)f2bf(f.w) << 16);
    u32x2 val = {lo, hi2};
    *((u32x2*)&Ah[r * AP2 + c4 * 4]) = val;
  }
  __syncthreads();  // B1

  const unsigned short* Wl1 = W1f + (size_t)lane * 8;
  // ---- GEMM1a kc 0..7 (K 0..255) ----
  {
    short8 bcur[4];
    #pragma unroll
    for (int ct = 0; ct < 4; ct++)
      bcur[ct] = *(const short8*)(Wl1 + ((w * 4 + ct) * 16 + 0) * 512);
    #pragma unroll
    for (int kc = 0; kc < 8; kc++) {
      short8 a[2], bnext[4];
      #pragma unroll
      for (int rt = 0; rt < 2; rt++)
        a[rt] = *(const short8*)(&Ah[(rt * 16 + ln15) * AP2 + kc * 32 + hi * 8]);
      if (kc < 7) {
        #pragma unroll
        for (int ct = 0; ct < 4; ct++)
          bnext[ct] = *(const short8*)(Wl1 + ((w * 4 + ct) * 16 + kc + 1) * 512);
      }
      __builtin_amdgcn_s_setprio(1);
      #pragma unroll
      for (int rt = 0; rt < 2; rt++)
        #pragma unroll
        for (int ct = 0; ct < 4; ct++)
          acc[rt][ct] = __builtin_amdgcn_mfma_f32_16x16x32_bf16(a[rt], bcur[ct], acc[rt][ct], 0, 0, 0);
      __builtin_amdgcn_s_setprio(0);
      if (kc < 7) {
        #pragma unroll
        for (int ct = 0; ct < 4; ct++) bcur[ct] = bnext[ct];
      }
    }
  }

  // ---- early-issue psu gather (loads in flight across B2) ----
  int ss = base >> 15;
  int r0 = tid >> 5, ch = tid & 31;
  int p0 = pidl[r0], p1 = pidl[8 + r0], p2 = pidl[16 + r0], p3 = pidl[24 + r0];
  const unsigned short* pbase = psub + (size_t)(ss * KSEG) * 256 + (size_t)ch * 8;
  u32x4 g0 = *(const u32x4*)(pbase + (size_t)p0 * 256);
  u32x4 g1 = *(const u32x4*)(pbase + (size_t)p1 * 256);
  u32x4 g2 = *(const u32x4*)(pbase + (size_t)p2 * 256);
  u32x4 g3 = *(const u32x4*)(pbase + (size_t)p3 * 256);
  __syncthreads();  // B2 (GEMM1a A-reads done)
  *(u32x4*)&Ah[r0 * AP2 + ch * 8] = g0;
  *(u32x4*)&Ah[(8 + r0) * AP2 + ch * 8] = g1;
  *(u32x4*)&Ah[(16 + r0) * AP2 + ch * 8] = g2;
  *(u32x4*)&Ah[(24 + r0) * AP2 + ch * 8] = g3;
  __syncthreads();  // B3

  // ---- GEMM1b kc 8..15 (K 256..511) ----
  {
    short8 bcur[4];
    #pragma unroll
    for (int ct = 0; ct < 4; ct++)
      bcur[ct] = *(const short8*)(Wl1 + ((w * 4 + ct) * 16 + 8) * 512);
    #pragma unroll
    for (int kc = 8; kc < 16; kc++) {
      short8 a[2], bnext[4];
      #pragma unroll
      for (int rt = 0; rt < 2; rt++)
        a[rt] = *(const short8*)(&Ah[(rt * 16 + ln15) * AP2 + (kc - 8) * 32 + hi * 8]);
      if (kc < 15) {
        #pragma unroll
        for (int ct = 0; ct < 4; ct++)
          bnext[ct] = *(const short8*)(Wl1 + ((w * 4 + ct) * 16 + kc + 1) * 512);
      }
      __builtin_amdgcn_s_setprio(1);
      #pragma unroll
      for (int rt = 0; rt < 2; rt++)
        #pragma unroll
        for (int ct = 0; ct < 4; ct++)
          acc[rt][ct] = __builtin_amdgcn_mfma_f32_16x16x32_bf16(a[rt], bcur[ct], acc[rt][ct], 0, 0, 0);
      __builtin_amdgcn_s_setprio(0);
      if (kc < 15) {
        #pragma unroll
        for (int ct = 0; ct < 4; ct++) bcur[ct] = bnext[ct];
      }
    }
  }
  __syncthreads();  // B4

  // ---- epi1: bias + gelu -> Hid (aliased over Ah) ----
  #pragma unroll
  for (int rt = 0; rt < 2; rt++) {
    #pragma unroll
    for (int ct = 0; ct < 4; ct++) {
      int col = w * 64 + ct * 16 + ln15;
      float bb = b1[col];
      #pragma unroll
      for (int r = 0; r < 4; r++) {
        int row = rt * 16 + hi * 4 + r;
        Ah[row * AP2 + col] = f2bf(gelu_f(acc[rt][ct][r] + bb));
      }
      acc[rt][ct] = (f32x4){0.f, 0.f, 0.f, 0.f};
    }
  }
  __syncthreads();  // B5

  // ---- GEMM2: [32x256] @ [256x256] ----
  {
    const unsigned short* Wl2 = W2f + (size_t)lane * 8;
    short8 bcur[4];
    #pragma unroll
    for (int ct = 0; ct < 4; ct++)
      bcur[ct] = *(const short8*)(Wl2 + ((w * 4 + ct) * 8 + 0) * 512);
    #pragma unroll
    for (int kc = 0; kc < 8; kc++) {
      short8 a[2], bnext[4];
      #pragma unroll
      for (int rt = 0; rt < 2; rt++)
        a[rt] = *(const short8*)(&Ah[(rt * 16 + ln15) * AP2 + kc * 32 + hi * 8]);
      if (kc < 7) {
        #pragma unroll
        for (int ct = 0; ct < 4; ct++)
          bnext[ct] = *(const short8*)(Wl2 + ((w * 4 + ct) * 8 + kc + 1) * 512);
      }
      __builtin_amdgcn_s_setprio(1);
      #pragma unroll
      for (int rt = 0; rt < 2; rt++)
        #pragma unroll
        for (int ct = 0; ct < 4; ct++)
          acc[rt][ct] = __builtin_amdgcn_mfma_f32_16x16x32_bf16(a[rt], bcur[ct], acc[rt][ct], 0, 0, 0);
      __builtin_amdgcn_s_setprio(0);
      if (kc < 7) {
        #pragma unroll
        for (int ct = 0; ct < 4; ct++) bcur[ct] = bnext[ct];
      }
    }
  }

  // ---- final epilogue: two 16-row LDS passes; H loads issued EARLY ----
  #pragma unroll
  for (int rh = 0; rh < 2; rh++) {
    // issue this pass's H loads before the barriers (latency hidden
    // under barrier drain + Cl writes)
    float4 hv0, hv1, hv2, hv3;
    {
      int i0 = tid, i1 = tid + 256, i2 = tid + 512, i3 = tid + 768;
      hv0 = *(const float4*)(H + ((size_t)(base + rh * 16 + (i0 >> 6))) * 256 + (i0 & 63) * 4);
      hv1 = *(const float4*)(H + ((size_t)(base + rh * 16 + (i1 >> 6))) * 256 + (i1 & 63) * 4);
      hv2 = *(const float4*)(H + ((size_t)(base + rh * 16 + (i2 >> 6))) * 256 + (i2 & 63) * 4);
      hv3 = *(const float4*)(H + ((size_t)(base + rh * 16 + (i3 >> 6))) * 256 + (i3 & 63) * 4);
    }
    __syncthreads();  // GEMM2 Ah reads done (rh=0) / prior pass done (rh=1)
    #pragma unroll
    for (int ct = 0; ct < 4; ct++) {
      int col = w * 64 + ct * 16 + ln15;
      float bb = b2[col];
      #pragma unroll
      for (int r = 0; r < 4; r++)
        Cl[(hi * 4 + r) * CP2 + col] = acc[rh][ct][r] + bb;
    }
    __syncthreads();
    #pragma unroll
    for (int k2 = 0; k2 < 4; k2++) {
      int i = tid + k2 * 256;
      int r = i >> 6, c4 = i & 63;
      size_t gidx = ((size_t)(base + rh * 16 + r)) * 256 + c4 * 4;
      float4 hv = (k2 == 0) ? hv0 : ((k2 == 1) ? hv1 : ((k2 == 2) ? hv2 : hv3));
      float4 cv = *(const float4*)&Cl[r * CP2 + c4 * 4];
      float4 o4 = {hv.x + cv.x, hv.y + cv.y, hv.z + cv.z, hv.w + cv.w};
      *(float4*)(out + gidx) = o4;
    }
  }
}

extern "C" void kernel_launch(void* const* d_in, const int* in_sizes, int n_in,
                              void* d_out, int out_size, void* d_ws, size_t ws_size,
                              hipStream_t stream) {
  (void)in_sizes; (void)n_in; (void)out_size; (void)ws_size;
  const float* H    = (const float*)d_in[0];
  const int*   pids = (const int*)d_in[1];
  const float* ln1g = (const float*)d_in[2];
  const float* ln1b = (const float*)d_in[3];
  const float* Wq   = (const float*)d_in[4];
  const float* bq   = (const float*)d_in[5];
  const float* Wk   = (const float*)d_in[6];
  const float* bk   = (const float*)d_in[7];
  const float* Wv   = (const float*)d_in[8];
  const float* bv   = (const float*)d_in[9];
  const float* Wo   = (const float*)d_in[10];
  const float* bo   = (const float*)d_in[11];
  const float* ln2g = (const float*)d_in[12];
  const float* ln2b = (const float*)d_in[13];
  const float* fW1  = (const float*)d_in[14];
  const float* fb1  = (const float*)d_in[15];
  const float* fW2  = (const float*)d_in[16];
  const float* fb2  = (const float*)d_in[17];
  const float* mW1  = (const float*)d_in[18];
  const float* mb1  = (const float*)d_in[19];
  const float* mW2  = (const float*)d_in[20];
  const float* mb2  = (const float*)d_in[21];
  float* out = (float*)d_out;
  float* ws = (float*)d_ws;

  int*   histc   = (int*)ws;                          // (32768)
  int*   segstart= (int*)(ws + 32768);                // (2048)
  int*   cnti    = (int*)(ws + 34816);                // (2048)
  int*   order   = (int*)(ws + 36864);                // (131072)
  float* counts  = ws + 167936;                       // (2048)
  float* xw      = ws + 169984;                       // (524288)
  float* yw      = ws + 694272;                       // (524288)
  float* qw      = ws + 1218560;                      // (524288)
  float* kw      = ws + 1742848;                      // (524288)
  float* vw      = ws + 2267136;                      // (524288)
  float* kvb     = ws + 2791424;                      // (65536)
  float* ksb     = ws + 2856960;                      // (1024)
  float* aw      = ws + 2857984;                      // (524288)
  float* x2w     = ws + 3382272;                      // (524288)
  float* y2w     = ws + 3906560;                      // (524288)
  unsigned short* hidb  = (unsigned short*)(ws + 4430848);  // 2M shorts
  unsigned short* psub  = (unsigned short*)(ws + 5479424);  // 512K shorts
  unsigned short* Wpack = (unsigned short*)(ws + 5741568);  // 983040 shorts

  hipMemsetAsync(kvb, 0, (65536 + 1024) * sizeof(float), stream);

  wprep2_kernel<<<480, 256, 0, stream>>>(Wq, Wk, Wv, Wo, fW1, fW2, mW1, mW2, Wpack);
  hist_kernel<<<64, 256, 0, stream>>>(pids, histc);
  prefix_kernel<<<4, 256, 0, stream>>>(histc, segstart, cnti, counts);
  scatter_kernel<<<64, 256, 0, stream>>>(pids, histc, order);
  pool_gather<<<1024, 256, 0, stream>>>(H, order, segstart, cnti, ln1g, ln1b, xw, yw);
  qkv_mfma<<<dim3(128, 3), 256, 0, stream>>>(yw, counts, Wpack, bq, bk, bv, qw, kw, vw);
  kv_kernel<<<128, 256, 0, stream>>>(kw, vw, kvb, ksb);
  attn_kernel<<<256, 256, 0, stream>>>(qw, kvb, ksb, aw);
  oproj_mfma<<<128, 256, 0, stream>>>(aw, xw, Wpack, bo, ln2g, ln2b, x2w, y2w);
  ffn1_mfma<<<dim3(128, 4), 256, 0, stream>>>(y2w, Wpack, fb1, hidb);
  ffn2_mfma<<<128, 256, 0, stream>>>(hidb, x2w, Wpack, fb2,
                                     out + (size_t)S * N * D, psub);
  node_mlp_kernel<<<4096, 256, 0, stream>>>(H, pids, psub,
                                            Wpack + 786432, Wpack + 917504,
                                            mb1, mb2, out);
}

// Round 13
// 230.939 us; speedup vs baseline: 2.1009x; 1.0842x over previous
//
#include <hip/hip_runtime.h>
#include <hip/hip_bf16.h>

#define S 4
#define N 32768
#define D 256
#define KSEG 512
#define NH 4
#define HD 64
#define FF 1024

typedef __attribute__((ext_vector_type(8))) short short8;
typedef __attribute__((ext_vector_type(4))) float f32x4;
typedef __attribute__((ext_vector_type(4))) unsigned int u32x4;
typedef __attribute__((ext_vector_type(2))) unsigned int u32x2;

__device__ __forceinline__ unsigned short f2bf(float f) {
  union { __hip_bfloat16 h; unsigned short u; } cv;
  cv.h = __float2bfloat16(f);
  return cv.u;
}

__device__ __forceinline__ float gelu_f(float x) {
  return 0.5f * x * (1.0f + erff(x * 0.70710678118654752440f));
}

__device__ __forceinline__ float wave_reduce_sum(float v) {
  #pragma unroll
  for (int o = 32; o > 0; o >>= 1) v += __shfl_xor(v, o, 64);
  return v;
}

// ---------------- Phase A: counting sort by patch id ----------------
__global__ __launch_bounds__(256) void hist_kernel(
    const int* __restrict__ pids, int* __restrict__ histc)
{
  __shared__ int h[KSEG];
  int b = blockIdx.x, t = threadIdx.x;
  int s = b >> 4, c = b & 15;
  for (int i = t; i < KSEG; i += 256) h[i] = 0;
  __syncthreads();
  const int* p = pids + s * N + c * 2048;
  for (int i = t; i < 2048; i += 256) atomicAdd(&h[p[i]], 1);
  __syncthreads();
  for (int i = t; i < KSEG; i += 256) histc[(s * 16 + c) * KSEG + i] = h[i];
}

__global__ __launch_bounds__(256) void prefix_kernel(
    int* __restrict__ histc, int* __restrict__ segstart,
    int* __restrict__ cnti, float* __restrict__ counts)
{
  __shared__ int h[16 * KSEG];   // 32 KB
  __shared__ int sc[KSEG];
  __shared__ int sa[KSEG], sb[KSEG];
  int s = blockIdx.x, t = threadIdx.x;
  for (int i = t; i < 16 * KSEG; i += 256) h[i] = histc[s * 16 * KSEG + i];
  __syncthreads();
  #pragma unroll
  for (int u = 0; u < 2; u++) {
    int bin = t + u * 256;
    int cc = 0;
    #pragma unroll
    for (int c = 0; c < 16; c++) cc += h[c * KSEG + bin];
    sc[bin] = cc;
    sa[bin] = cc;
  }
  __syncthreads();
  int* src = sa; int* dst = sb;
  for (int off = 1; off < KSEG; off <<= 1) {
    #pragma unroll
    for (int u = 0; u < 2; u++) {
      int bin = t + u * 256;
      int v = src[bin];
      if (bin >= off) v += src[bin - off];
      dst[bin] = v;
    }
    __syncthreads();
    int* tmp = src; src = dst; dst = tmp;
  }
  #pragma unroll
  for (int u = 0; u < 2; u++) {
    int bin = t + u * 256;
    int cc = sc[bin];
    int excl = src[bin] - cc;
    segstart[s * KSEG + bin] = excl;
    cnti[s * KSEG + bin] = cc;
    counts[s * KSEG + bin] = (float)cc;
    int run = excl;
    #pragma unroll
    for (int c = 0; c < 16; c++) {
      int v = h[c * KSEG + bin];
      h[c * KSEG + bin] = run;
      run += v;
    }
  }
  __syncthreads();
  for (int i = t; i < 16 * KSEG; i += 256) histc[s * 16 * KSEG + i] = h[i];
}

__global__ __launch_bounds__(256) void scatter_kernel(
    const int* __restrict__ pids, const int* __restrict__ histc,
    int* __restrict__ order)
{
  __shared__ int offs[KSEG];
  int b = blockIdx.x, t = threadIdx.x;
  int s = b >> 4, c = b & 15;
  for (int i = t; i < KSEG; i += 256) offs[i] = histc[(s * 16 + c) * KSEG + i];
  __syncthreads();
  const int* p = pids + s * N + c * 2048;
  for (int i = t; i < 2048; i += 256) {
    int pid = p[i];
    int pos = atomicAdd(&offs[pid], 1);
    order[s * N + pos] = s * N + c * 2048 + i;
  }
}

// gather-reduce + fused LN1: TWO waves per segment. grid 1024.
__global__ __launch_bounds__(256) void pool_gather(
    const float* __restrict__ H, const int* __restrict__ order,
    const int* __restrict__ segstart, const int* __restrict__ cnti,
    const float* __restrict__ g, const float* __restrict__ bta,
    float* __restrict__ xw, float* __restrict__ yw)
{
  __shared__ float pbuf[4][256];
  int tid = threadIdx.x;
  int w = tid >> 6, lane = tid & 63;
  int seg = blockIdx.x * 2 + (w >> 1);
  int half = w & 1;
  int s = seg >> 9;
  int st = segstart[seg], cn = cnti[seg];
  int en = st + cn;
  const int* ord = order + (size_t)s * N;
  int c4 = lane << 2;
  f32x4 a0 = {0,0,0,0}, a1 = {0,0,0,0}, a2 = {0,0,0,0}, a3 = {0,0,0,0};
  f32x4 a4 = {0,0,0,0}, a5 = {0,0,0,0}, a6 = {0,0,0,0}, a7 = {0,0,0,0};
  int i = st + half;
  for (; i + 14 < en; i += 16) {
    int r0 = ord[i + 0], r1 = ord[i + 2], r2 = ord[i + 4], r3 = ord[i + 6];
    int r4 = ord[i + 8], r5 = ord[i + 10], r6 = ord[i + 12], r7 = ord[i + 14];
    a0 += *(const f32x4*)(H + (size_t)r0 * 256 + c4);
    a1 += *(const f32x4*)(H + (size_t)r1 * 256 + c4);
    a2 += *(const f32x4*)(H + (size_t)r2 * 256 + c4);
    a3 += *(const f32x4*)(H + (size_t)r3 * 256 + c4);
    a4 += *(const f32x4*)(H + (size_t)r4 * 256 + c4);
    a5 += *(const f32x4*)(H + (size_t)r5 * 256 + c4);
    a6 += *(const f32x4*)(H + (size_t)r6 * 256 + c4);
    a7 += *(const f32x4*)(H + (size_t)r7 * 256 + c4);
  }
  for (; i < en; i += 2) {
    int r = ord[i];
    a0 += *(const f32x4*)(H + (size_t)r * 256 + c4);
  }
  f32x4 ssum = ((a0 + a1) + (a2 + a3)) + ((a4 + a5) + (a6 + a7));
  *(f32x4*)&pbuf[w][c4] = ssum;
  __syncthreads();
  if (half == 0) {
    f32x4 tot = *(f32x4*)&pbuf[w][c4];
    tot += *(f32x4*)&pbuf[w + 1][c4];
    float inv = 1.f / fmaxf((float)cn, 1.f);
    tot = tot * inv;
    *(f32x4*)(xw + (size_t)seg * 256 + c4) = tot;
    // fused LN1
    float s1 = tot[0] + tot[1] + tot[2] + tot[3];
    float s2 = tot[0]*tot[0] + tot[1]*tot[1] + tot[2]*tot[2] + tot[3]*tot[3];
    s1 = wave_reduce_sum(s1);
    s2 = wave_reduce_sum(s2);
    float mu = s1 * (1.f / 256.f);
    float var = s2 * (1.f / 256.f) - mu * mu;
    float rs = rsqrtf(var + 1e-5f);
    float4 g4 = *(const float4*)(g + c4);
    float4 b4 = *(const float4*)(bta + c4);
    float4 yv = {(tot[0]-mu)*rs*g4.x + b4.x, (tot[1]-mu)*rs*g4.y + b4.y,
                 (tot[2]-mu)*rs*g4.z + b4.z, (tot[3]-mu)*rs*g4.w + b4.w};
    *(float4*)(yw + (size_t)seg * 256 + c4) = yv;
  }
}

// ---------------- weight pre-pack: all 8 matrices into fragment order ----
__global__ __launch_bounds__(256) void wprep2_kernel(
    const float* __restrict__ Wq, const float* __restrict__ Wk,
    const float* __restrict__ Wv, const float* __restrict__ Wo,
    const float* __restrict__ fW1, const float* __restrict__ fW2,
    const float* __restrict__ mW1, const float* __restrict__ mW2,
    unsigned short* __restrict__ Wpack)
{
  int fi = blockIdx.x * 256 + threadIdx.x;   // 0..122879
  const float* src; int ld, colbase, kcbits; size_t outb; int rfi;
  if (fi < 32768) {
    int m = fi >> 13; rfi = fi & 8191;
    src = (m == 0) ? Wq : ((m == 1) ? Wk : ((m == 2) ? Wv : Wo));
    ld = 256; colbase = 0; kcbits = 3; outb = (size_t)m * 65536;
  } else if (fi < 65536) {
    rfi = fi - 32768; int cc = rfi >> 13; rfi &= 8191;
    src = fW1; ld = 1024; colbase = cc * 256; kcbits = 3;
    outb = 262144 + (size_t)cc * 65536;
  } else if (fi < 98304) {
    rfi = fi - 65536; src = fW2; ld = 256; colbase = 0; kcbits = 5; outb = 524288;
  } else if (fi < 114688) {
    rfi = fi - 98304; src = mW1; ld = 256; colbase = 0; kcbits = 4; outb = 786432;
  } else {
    rfi = fi - 114688; src = mW2; ld = 256; colbase = 0; kcbits = 3; outb = 917504;
  }
  int tile = rfi >> 6, lane = rfi & 63;
  int c = tile >> kcbits, kc = tile & ((1 << kcbits) - 1);
  int k0 = kc * 32 + (lane >> 4) * 8;
  int col = colbase + c * 16 + (lane & 15);
  unsigned int p[4];
  #pragma unroll
  for (int jj = 0; jj < 4; jj++) {
    unsigned int lo = f2bf(src[(size_t)(k0 + 2 * jj) * ld + col]);
    unsigned int hi = f2bf(src[(size_t)(k0 + 2 * jj + 1) * ld + col]);
    p[jj] = lo | (hi << 16);
  }
  u32x4 v = {p[0], p[1], p[2], p[3]};
  *(u32x4*)&Wpack[outb + (size_t)rfi * 8] = v;
}

// ---------------- MFMA patch-GEMM template pieces (16 rows x 256 cols) ----
#define AP3 264  // A row stride (bf16): 256 + 8 pad
#define CP3 260  // C row stride (f32): 256 + 4 pad

// QKV: grid (128, 3). epilogue: phi (m<=1), mask (m>=1).
__global__ __launch_bounds__(256, 4) void qkv_mfma(
    const float* __restrict__ y, const float* __restrict__ counts,
    const unsigned short* __restrict__ Wpack,
    const float* __restrict__ bq, const float* __restrict__ bk,
    const float* __restrict__ bv,
    float* __restrict__ qo, float* __restrict__ ko, float* __restrict__ vo)
{
  __shared__ __align__(16) unsigned char smem[16 * CP3 * 4];  // 16640 B
  unsigned short* Ah = (unsigned short*)smem;
  float* Cl = (float*)smem;
  int m = blockIdx.y;
  const unsigned short* Wf = Wpack + (size_t)m * 65536;
  const float* bias = (m == 0) ? bq : ((m == 1) ? bk : bv);
  float* outp = (m == 0) ? qo : ((m == 1) ? ko : vo);
  int tid = threadIdx.x, lane = tid & 63, w = tid >> 6;
  int ln15 = lane & 15, hi = lane >> 4;
  int base = blockIdx.x * 16;

  for (int i = tid; i < 16 * 64; i += 256) {
    int r = i >> 6, c4 = i & 63;
    float4 f = *(const float4*)(y + ((size_t)(base + r)) * 256 + c4 * 4);
    unsigned int lo = (unsigned int)f2bf(f.x) | ((unsigned int)f2bf(f.y) << 16);
    unsigned int h2 = (unsigned int)f2bf(f.z) | ((unsigned int)f2bf(f.w) << 16);
    u32x2 val = {lo, h2};
    *((u32x2*)&Ah[r * AP3 + c4 * 4]) = val;
  }
  __syncthreads();

  f32x4 acc[4];
  #pragma unroll
  for (int c = 0; c < 4; c++) acc[c] = (f32x4){0.f, 0.f, 0.f, 0.f};
  const unsigned short* Wl = Wf + (size_t)lane * 8;
  short8 bcur[4];
  #pragma unroll
  for (int ct = 0; ct < 4; ct++)
    bcur[ct] = *(const short8*)(Wl + ((w * 4 + ct) * 8 + 0) * 512);
  #pragma unroll
  for (int kc = 0; kc < 8; kc++) {
    short8 a = *(const short8*)(&Ah[ln15 * AP3 + kc * 32 + hi * 8]);
    short8 bnext[4];
    if (kc < 7) {
      #pragma unroll
      for (int ct = 0; ct < 4; ct++)
        bnext[ct] = *(const short8*)(Wl + ((w * 4 + ct) * 8 + kc + 1) * 512);
    }
    #pragma unroll
    for (int ct = 0; ct < 4; ct++)
      acc[ct] = __builtin_amdgcn_mfma_f32_16x16x32_bf16(a, bcur[ct], acc[ct], 0, 0, 0);
    if (kc < 7) {
      #pragma unroll
      for (int ct = 0; ct < 4; ct++) bcur[ct] = bnext[ct];
    }
  }
  __syncthreads();  // A reads done; reuse smem as Cl

  float mk[4];
  #pragma unroll
  for (int r = 0; r < 4; r++)
    mk[r] = (counts[base + hi * 4 + r] > 0.f) ? 1.f : 0.f;
  #pragma unroll
  for (int ct = 0; ct < 4; ct++) {
    int col = w * 64 + ct * 16 + ln15;
    float bb = bias[col];
    #pragma unroll
    for (int r = 0; r < 4; r++) {
      float tv = acc[ct][r] + bb;
      if (m <= 1) tv = (tv > 0.f) ? (tv + 1.f) : expf(tv);
      if (m >= 1) tv *= mk[r];
      Cl[(hi * 4 + r) * CP3 + col] = tv;
    }
  }
  __syncthreads();
  for (int i = tid; i < 16 * 64; i += 256) {
    int r = i >> 6, c4 = i & 63;
    *(float4*)(outp + ((size_t)(base + r)) * 256 + c4 * 4) =
        *(const float4*)&Cl[r * CP3 + c4 * 4];
  }
}

// oproj + fused LN2: x2 = x + a@Wo + bo; y2 = LN(x2). grid 128.
__global__ __launch_bounds__(256, 4) void oproj_mfma(
    const float* __restrict__ aw, const float* __restrict__ xw,
    const unsigned short* __restrict__ Wpack, const float* __restrict__ bo,
    const float* __restrict__ g, const float* __restrict__ bta,
    float* __restrict__ x2, float* __restrict__ y2)
{
  __shared__ __align__(16) unsigned char smem[16 * CP3 * 4];
  unsigned short* Ah = (unsigned short*)smem;
  float* Cl = (float*)smem;
  const unsigned short* Wf = Wpack + 196608;
  int tid = threadIdx.x, lane = tid & 63, w = tid >> 6;
  int ln15 = lane & 15, hi = lane >> 4;
  int base = blockIdx.x * 16;

  for (int i = tid; i < 16 * 64; i += 256) {
    int r = i >> 6, c4 = i & 63;
    float4 f = *(const float4*)(aw + ((size_t)(base + r)) * 256 + c4 * 4);
    unsigned int lo = (unsigned int)f2bf(f.x) | ((unsigned int)f2bf(f.y) << 16);
    unsigned int h2 = (unsigned int)f2bf(f.z) | ((unsigned int)f2bf(f.w) << 16);
    u32x2 val = {lo, h2};
    *((u32x2*)&Ah[r * AP3 + c4 * 4]) = val;
  }
  __syncthreads();

  f32x4 acc[4];
  #pragma unroll
  for (int c = 0; c < 4; c++) acc[c] = (f32x4){0.f, 0.f, 0.f, 0.f};
  const unsigned short* Wl = Wf + (size_t)lane * 8;
  short8 bcur[4];
  #pragma unroll
  for (int ct = 0; ct < 4; ct++)
    bcur[ct] = *(const short8*)(Wl + ((w * 4 + ct) * 8 + 0) * 512);
  #pragma unroll
  for (int kc = 0; kc < 8; kc++) {
    short8 a = *(const short8*)(&Ah[ln15 * AP3 + kc * 32 + hi * 8]);
    short8 bnext[4];
    if (kc < 7) {
      #pragma unroll
      for (int ct = 0; ct < 4; ct++)
        bnext[ct] = *(const short8*)(Wl + ((w * 4 + ct) * 8 + kc + 1) * 512);
    }
    #pragma unroll
    for (int ct = 0; ct < 4; ct++)
      acc[ct] = __builtin_amdgcn_mfma_f32_16x16x32_bf16(a, bcur[ct], acc[ct], 0, 0, 0);
    if (kc < 7) {
      #pragma unroll
      for (int ct = 0; ct < 4; ct++) bcur[ct] = bnext[ct];
    }
  }
  __syncthreads();

  #pragma unroll
  for (int ct = 0; ct < 4; ct++) {
    int col = w * 64 + ct * 16 + ln15;
    float bb = bo[col];
    #pragma unroll
    for (int r = 0; r < 4; r++)
      Cl[(hi * 4 + r) * CP3 + col] = acc[ct][r] + bb;
  }
  __syncthreads();
  // fused residual + LN2: wave w handles rows {4k + w}
  int c4 = lane << 2;
  float4 g4 = *(const float4*)(g + c4);
  float4 b4 = *(const float4*)(bta + c4);
  #pragma unroll
  for (int k = 0; k < 4; k++) {
    int r = k * 4 + w;
    size_t gbase = ((size_t)(base + r)) * 256 + c4;
    float4 xv = *(const float4*)(xw + gbase);
    float4 cv = *(const float4*)&Cl[r * CP3 + c4];
    float4 x2v = {xv.x + cv.x, xv.y + cv.y, xv.z + cv.z, xv.w + cv.w};
    *(float4*)(x2 + gbase) = x2v;
    float s1 = x2v.x + x2v.y + x2v.z + x2v.w;
    float s2 = x2v.x*x2v.x + x2v.y*x2v.y + x2v.z*x2v.z + x2v.w*x2v.w;
    s1 = wave_reduce_sum(s1);
    s2 = wave_reduce_sum(s2);
    float mu = s1 * (1.f / 256.f);
    float var = s2 * (1.f / 256.f) - mu * mu;
    float rs = rsqrtf(var + 1e-5f);
    float4 yv = {(x2v.x-mu)*rs*g4.x + b4.x, (x2v.y-mu)*rs*g4.y + b4.y,
                 (x2v.z-mu)*rs*g4.z + b4.z, (x2v.w-mu)*rs*g4.w + b4.w};
    *(float4*)(y2 + gbase) = yv;
  }
}

// ffn1: hidb = bf16(gelu(y2 @ fW1 + b1)). grid (128, 4 col-chunks).
__global__ __launch_bounds__(256, 4) void ffn1_mfma(
    const float* __restrict__ y2, const unsigned short* __restrict__ Wpack,
    const float* __restrict__ b1, unsigned short* __restrict__ hidb)
{
  __shared__ __align__(16) unsigned char smem[16 * CP3 * 4];
  unsigned short* Ah = (unsigned short*)smem;
  int cc = blockIdx.y;
  const unsigned short* Wf = Wpack + 262144 + (size_t)cc * 65536;
  int tid = threadIdx.x, lane = tid & 63, w = tid >> 6;
  int ln15 = lane & 15, hi = lane >> 4;
  int base = blockIdx.x * 16;

  for (int i = tid; i < 16 * 64; i += 256) {
    int r = i >> 6, c4 = i & 63;
    float4 f = *(const float4*)(y2 + ((size_t)(base + r)) * 256 + c4 * 4);
    unsigned int lo = (unsigned int)f2bf(f.x) | ((unsigned int)f2bf(f.y) << 16);
    unsigned int h2 = (unsigned int)f2bf(f.z) | ((unsigned int)f2bf(f.w) << 16);
    u32x2 val = {lo, h2};
    *((u32x2*)&Ah[r * AP3 + c4 * 4]) = val;
  }
  __syncthreads();

  f32x4 acc[4];
  #pragma unroll
  for (int c = 0; c < 4; c++) acc[c] = (f32x4){0.f, 0.f, 0.f, 0.f};
  const unsigned short* Wl = Wf + (size_t)lane * 8;
  short8 bcur[4];
  #pragma unroll
  for (int ct = 0; ct < 4; ct++)
    bcur[ct] = *(const short8*)(Wl + ((w * 4 + ct) * 8 + 0) * 512);
  #pragma unroll
  for (int kc = 0; kc < 8; kc++) {
    short8 a = *(const short8*)(&Ah[ln15 * AP3 + kc * 32 + hi * 8]);
    short8 bnext[4];
    if (kc < 7) {
      #pragma unroll
      for (int ct = 0; ct < 4; ct++)
        bnext[ct] = *(const short8*)(Wl + ((w * 4 + ct) * 8 + kc + 1) * 512);
    }
    #pragma unroll
    for (int ct = 0; ct < 4; ct++)
      acc[ct] = __builtin_amdgcn_mfma_f32_16x16x32_bf16(a, bcur[ct], acc[ct], 0, 0, 0);
    if (kc < 7) {
      #pragma unroll
      for (int ct = 0; ct < 4; ct++) bcur[ct] = bnext[ct];
    }
  }
  __syncthreads();

  #pragma unroll
  for (int ct = 0; ct < 4; ct++) {
    int col = w * 64 + ct * 16 + ln15;
    float bb = b1[cc * 256 + col];
    #pragma unroll
    for (int r = 0; r < 4; r++)
      Ah[(hi * 4 + r) * 256 + col] = f2bf(gelu_f(acc[ct][r] + bb));
  }
  __syncthreads();
  for (int i = tid; i < 16 * 32; i += 256) {
    int r = i >> 5, c8 = i & 31;
    *(u32x4*)(hidb + ((size_t)(base + r)) * FF + cc * 256 + c8 * 8) =
        *(const u32x4*)&Ah[r * 256 + c8 * 8];
  }
}

// ffn2: psu = x2 + hidb @ fW2 + b2 (fp32 out + bf16 psub). grid 128. K=1024.
__global__ __launch_bounds__(256, 4) void ffn2_mfma(
    const unsigned short* __restrict__ hidb, const float* __restrict__ x2,
    const unsigned short* __restrict__ Wpack, const float* __restrict__ b2,
    float* __restrict__ psu_out, unsigned short* __restrict__ psub)
{
  __shared__ __align__(16) unsigned char smem[16 * CP3 * 4];
  unsigned short* Ah = (unsigned short*)smem;
  float* Cl = (float*)smem;
  const unsigned short* Wf = Wpack + 524288;
  int tid = threadIdx.x, lane = tid & 63, w = tid >> 6;
  int ln15 = lane & 15, hi = lane >> 4;
  int base = blockIdx.x * 16;

  f32x4 acc[4];
  #pragma unroll
  for (int c = 0; c < 4; c++) acc[c] = (f32x4){0.f, 0.f, 0.f, 0.f};
  const unsigned short* Wl = Wf + (size_t)lane * 8;

  for (int ch = 0; ch < 4; ch++) {
    __syncthreads();
    for (int i = tid; i < 16 * 32; i += 256) {
      int r = i >> 5, c8 = i & 31;
      *((u32x4*)&Ah[r * AP3 + c8 * 8]) =
          *(const u32x4*)(hidb + ((size_t)(base + r)) * FF + ch * 256 + c8 * 8);
    }
    __syncthreads();
    short8 bcur[4];
    #pragma unroll
    for (int ct = 0; ct < 4; ct++)
      bcur[ct] = *(const short8*)(Wl + ((w * 4 + ct) * 32 + ch * 8 + 0) * 512);
    #pragma unroll
    for (int kc = 0; kc < 8; kc++) {
      short8 a = *(const short8*)(&Ah[ln15 * AP3 + kc * 32 + hi * 8]);
      short8 bnext[4];
      if (kc < 7) {
        #pragma unroll
        for (int ct = 0; ct < 4; ct++)
          bnext[ct] = *(const short8*)(Wl + ((w * 4 + ct) * 32 + ch * 8 + kc + 1) * 512);
      }
      #pragma unroll
      for (int ct = 0; ct < 4; ct++)
        acc[ct] = __builtin_amdgcn_mfma_f32_16x16x32_bf16(a, bcur[ct], acc[ct], 0, 0, 0);
      if (kc < 7) {
        #pragma unroll
        for (int ct = 0; ct < 4; ct++) bcur[ct] = bnext[ct];
      }
    }
  }
  __syncthreads();

  #pragma unroll
  for (int ct = 0; ct < 4; ct++) {
    int col = w * 64 + ct * 16 + ln15;
    float bb = b2[col];
    #pragma unroll
    for (int r = 0; r < 4; r++)
      Cl[(hi * 4 + r) * CP3 + col] = acc[ct][r] + bb;
  }
  __syncthreads();
  for (int i = tid; i < 16 * 64; i += 256) {
    int r = i >> 6, c4 = i & 63;
    size_t gidx = ((size_t)(base + r)) * 256 + c4 * 4;
    float4 xv = *(const float4*)(x2 + gidx);
    float4 cv = *(const float4*)&Cl[r * CP3 + c4 * 4];
    float4 o = {xv.x + cv.x, xv.y + cv.y, xv.z + cv.z, xv.w + cv.w};
    *(float4*)(psu_out + gidx) = o;
    unsigned int lo = (unsigned int)f2bf(o.x) | ((unsigned int)f2bf(o.y) << 16);
    unsigned int h2 = (unsigned int)f2bf(o.z) | ((unsigned int)f2bf(o.w) << 16);
    u32x2 pb = {lo, h2};
    *(u32x2*)(psub + gidx) = pb;
  }
}

// kv[s,h,d,e] = sum_k k*v ; ksum. grid 128
__global__ __launch_bounds__(256) void kv_kernel(
    const float* __restrict__ kw, const float* __restrict__ vw,
    float* __restrict__ kvb, float* __restrict__ ksb)
{
  int b = blockIdx.x, t = threadIdx.x;
  int s = b / (NH * 8), h = (b / 8) % NH, ck = b & 7;
  __shared__ float kl[64 * 64];
  __shared__ float vl[64 * 64];
  for (int i = t; i < 4096; i += 256) {
    int kk = i >> 6, d = i & 63;
    size_t rowb = ((size_t)(s * KSEG + ck * 64 + kk) * NH + h) * HD + d;
    kl[i] = kw[rowb];
    vl[i] = vw[rowb];
  }
  __syncthreads();
  int d = t & 63, eb = (t >> 6) * 16;
  f32x4 a4[4];
  #pragma unroll
  for (int j = 0; j < 4; j++) a4[j] = (f32x4){0.f, 0.f, 0.f, 0.f};
  float acck = 0.f;
  #pragma unroll 4
  for (int kk = 0; kk < 64; kk++) {
    float kd = kl[kk * 64 + d];
    acck += kd;
    #pragma unroll
    for (int j = 0; j < 4; j++) {
      f32x4 vv = *(const f32x4*)&vl[kk * 64 + eb + j * 4];
      a4[j] += kd * vv;
    }
  }
  #pragma unroll
  for (int j = 0; j < 4; j++)
    #pragma unroll
    for (int e = 0; e < 4; e++)
      atomicAdd(&kvb[(((size_t)(s * NH + h)) * HD + d) * HD + eb + j * 4 + e], a4[j][e]);
  if (t < 64) atomicAdd(&ksb[(s * NH + h) * HD + t], acck);
}

// a = num/den per row. grid 256 blocks
__global__ __launch_bounds__(256) void attn_kernel(
    const float* __restrict__ qw, const float* __restrict__ kvb,
    const float* __restrict__ ksb, float* __restrict__ aw)
{
  __shared__ float kvl[64 * 64];
  __shared__ float ksl[64];
  __shared__ float ql[32 * 64];
  int t = threadIdx.x, b = blockIdx.x;
  int sh = b >> 4, rb = b & 15;
  int s = sh >> 2, h = sh & 3;
  for (int i = t; i < 4096; i += 256) kvl[i] = kvb[sh * 4096 + i];
  if (t < 64) ksl[t] = ksb[sh * 64 + t];
  for (int i = t; i < 2048; i += 256) {
    int r = i >> 6, d = i & 63;
    ql[i] = qw[((size_t)(s * KSEG + rb * 32 + r)) * 256 + h * 64 + d];
  }
  __syncthreads();
  int e = t & 63, rg = t >> 6;
  float num[8], den[8];
  #pragma unroll
  for (int r = 0; r < 8; r++) { num[r] = 0.f; den[r] = 0.f; }
  #pragma unroll 4
  for (int d4 = 0; d4 < 64; d4 += 4) {
    float4 ks4 = *(const float4*)&ksl[d4];
    float kv0 = kvl[(d4 + 0) * 64 + e];
    float kv1 = kvl[(d4 + 1) * 64 + e];
    float kv2 = kvl[(d4 + 2) * 64 + e];
    float kv3 = kvl[(d4 + 3) * 64 + e];
    #pragma unroll
    for (int r = 0; r < 8; r++) {
      float4 q4 = *(const float4*)&ql[(rg * 8 + r) * 64 + d4];
      num[r] += q4.x * kv0 + q4.y * kv1 + q4.z * kv2 + q4.w * kv3;
      den[r] += q4.x * ks4.x + q4.y * ks4.y + q4.z * ks4.z + q4.w * ks4.w;
    }
  }
  #pragma unroll
  for (int r = 0; r < 8; r++) {
    int row = rb * 32 + rg * 8 + r;
    aw[((size_t)(s * KSEG + row)) * 256 + h * 64 + e] = num[r] / (den[r] + 1e-6f);
  }
}

// ---------------- Phase C: fused node MLP (bf16 MFMA), v5 (R10 proven) ----
// 32-row tiles, grid 4096, (256,5), LDS round-trip epilogue with H re-read
// from global (L3-hit), early-issue psu gather. 113-115us reproduced twice.
#define AP2 264
#define CP2 260
__global__ __launch_bounds__(256, 5) void node_mlp_kernel(
    const float* __restrict__ H, const int* __restrict__ pids,
    const unsigned short* __restrict__ psub,
    const unsigned short* __restrict__ W1f, const unsigned short* __restrict__ W2f,
    const float* __restrict__ b1, const float* __restrict__ b2,
    float* __restrict__ out)
{
  __shared__ __align__(16) unsigned char smem[32 * AP2 * 2];  // 16896 B
  __shared__ int pidl[32];
  unsigned short* Ah = (unsigned short*)smem;
  float* Cl = (float*)smem;
  int tid = threadIdx.x;
  int lane = tid & 63, w = tid >> 6;
  int ln15 = lane & 15, hi = lane >> 4;
  int base = blockIdx.x * 32;

  f32x4 acc[2][4];
  #pragma unroll
  for (int a = 0; a < 2; a++)
    #pragma unroll
    for (int c = 0; c < 4; c++) acc[a][c] = (f32x4){0.f, 0.f, 0.f, 0.f};

  // ---- stage 1: H cols 0..255 (fp32 -> bf16) ----
  if (tid < 32) pidl[tid] = pids[base + tid];
  #pragma unroll
  for (int k = 0; k < 8; k++) {
    int i = tid + k * 256;
    int r = i >> 6, c4 = i & 63;
    float4 f = *(const float4*)(H + ((size_t)(base + r)) * 256 + c4 * 4);
    unsigned int lo = (unsigned int)f2bf(f.x) | ((unsigned int)f2bf(f.y) << 16);
    unsigned int hi2 = (unsigned int)f2bf(f.z) | ((unsigned int)f2bf(f.w) << 16);
    u32x2 val = {lo, hi2};
    *((u32x2*)&Ah[r * AP2 + c4 * 4]) = val;
  }
  __syncthreads();  // B1

  const unsigned short* Wl1 = W1f + (size_t)lane * 8;
  // ---- GEMM1a kc 0..7 (K 0..255) ----
  {
    short8 bcur[4];
    #pragma unroll
    for (int ct = 0; ct < 4; ct++)
      bcur[ct] = *(const short8*)(Wl1 + ((w * 4 + ct) * 16 + 0) * 512);
    #pragma unroll
    for (int kc = 0; kc < 8; kc++) {
      short8 a[2], bnext[4];
      #pragma unroll
      for (int rt = 0; rt < 2; rt++)
        a[rt] = *(const short8*)(&Ah[(rt * 16 + ln15) * AP2 + kc * 32 + hi * 8]);
      if (kc < 7) {
        #pragma unroll
        for (int ct = 0; ct < 4; ct++)
          bnext[ct] = *(const short8*)(Wl1 + ((w * 4 + ct) * 16 + kc + 1) * 512);
      }
      __builtin_amdgcn_s_setprio(1);
      #pragma unroll
      for (int rt = 0; rt < 2; rt++)
        #pragma unroll
        for (int ct = 0; ct < 4; ct++)
          acc[rt][ct] = __builtin_amdgcn_mfma_f32_16x16x32_bf16(a[rt], bcur[ct], acc[rt][ct], 0, 0, 0);
      __builtin_amdgcn_s_setprio(0);
      if (kc < 7) {
        #pragma unroll
        for (int ct = 0; ct < 4; ct++) bcur[ct] = bnext[ct];
      }
    }
  }

  // ---- early-issue psu gather (loads in flight across B2) ----
  int ss = base >> 15;
  int r0 = tid >> 5, ch = tid & 31;
  int p0 = pidl[r0], p1 = pidl[8 + r0], p2 = pidl[16 + r0], p3 = pidl[24 + r0];
  const unsigned short* pbase = psub + (size_t)(ss * KSEG) * 256 + (size_t)ch * 8;
  u32x4 g0 = *(const u32x4*)(pbase + (size_t)p0 * 256);
  u32x4 g1 = *(const u32x4*)(pbase + (size_t)p1 * 256);
  u32x4 g2 = *(const u32x4*)(pbase + (size_t)p2 * 256);
  u32x4 g3 = *(const u32x4*)(pbase + (size_t)p3 * 256);
  __syncthreads();  // B2 (GEMM1a A-reads done)
  *(u32x4*)&Ah[r0 * AP2 + ch * 8] = g0;
  *(u32x4*)&Ah[(8 + r0) * AP2 + ch * 8] = g1;
  *(u32x4*)&Ah[(16 + r0) * AP2 + ch * 8] = g2;
  *(u32x4*)&Ah[(24 + r0) * AP2 + ch * 8] = g3;
  __syncthreads();  // B3

  // ---- GEMM1b kc 8..15 (K 256..511) ----
  {
    short8 bcur[4];
    #pragma unroll
    for (int ct = 0; ct < 4; ct++)
      bcur[ct] = *(const short8*)(Wl1 + ((w * 4 + ct) * 16 + 8) * 512);
    #pragma unroll
    for (int kc = 8; kc < 16; kc++) {
      short8 a[2], bnext[4];
      #pragma unroll
      for (int rt = 0; rt < 2; rt++)
        a[rt] = *(const short8*)(&Ah[(rt * 16 + ln15) * AP2 + (kc - 8) * 32 + hi * 8]);
      if (kc < 15) {
        #pragma unroll
        for (int ct = 0; ct < 4; ct++)
          bnext[ct] = *(const short8*)(Wl1 + ((w * 4 + ct) * 16 + kc + 1) * 512);
      }
      __builtin_amdgcn_s_setprio(1);
      #pragma unroll
      for (int rt = 0; rt < 2; rt++)
        #pragma unroll
        for (int ct = 0; ct < 4; ct++)
          acc[rt][ct] = __builtin_amdgcn_mfma_f32_16x16x32_bf16(a[rt], bcur[ct], acc[rt][ct], 0, 0, 0);
      __builtin_amdgcn_s_setprio(0);
      if (kc < 15) {
        #pragma unroll
        for (int ct = 0; ct < 4; ct++) bcur[ct] = bnext[ct];
      }
    }
  }
  __syncthreads();  // B4

  // ---- epi1: bias + gelu -> Hid (aliased over Ah) ----
  #pragma unroll
  for (int rt = 0; rt < 2; rt++) {
    #pragma unroll
    for (int ct = 0; ct < 4; ct++) {
      int col = w * 64 + ct * 16 + ln15;
      float bb = b1[col];
      #pragma unroll
      for (int r = 0; r < 4; r++) {
        int row = rt * 16 + hi * 4 + r;
        Ah[row * AP2 + col] = f2bf(gelu_f(acc[rt][ct][r] + bb));
      }
      acc[rt][ct] = (f32x4){0.f, 0.f, 0.f, 0.f};
    }
  }
  __syncthreads();  // B5

  // ---- GEMM2: [32x256] @ [256x256] ----
  {
    const unsigned short* Wl2 = W2f + (size_t)lane * 8;
    short8 bcur[4];
    #pragma unroll
    for (int ct = 0; ct < 4; ct++)
      bcur[ct] = *(const short8*)(Wl2 + ((w * 4 + ct) * 8 + 0) * 512);
    #pragma unroll
    for (int kc = 0; kc < 8; kc++) {
      short8 a[2], bnext[4];
      #pragma unroll
      for (int rt = 0; rt < 2; rt++)
        a[rt] = *(const short8*)(&Ah[(rt * 16 + ln15) * AP2 + kc * 32 + hi * 8]);
      if (kc < 7) {
        #pragma unroll
        for (int ct = 0; ct < 4; ct++)
          bnext[ct] = *(const short8*)(Wl2 + ((w * 4 + ct) * 8 + kc + 1) * 512);
      }
      __builtin_amdgcn_s_setprio(1);
      #pragma unroll
      for (int rt = 0; rt < 2; rt++)
        #pragma unroll
        for (int ct = 0; ct < 4; ct++)
          acc[rt][ct] = __builtin_amdgcn_mfma_f32_16x16x32_bf16(a[rt], bcur[ct], acc[rt][ct], 0, 0, 0);
      __builtin_amdgcn_s_setprio(0);
      if (kc < 7) {
        #pragma unroll
        for (int ct = 0; ct < 4; ct++) bcur[ct] = bnext[ct];
      }
    }
  }

  // ---- final epilogue: two 16-row LDS passes, H re-read from global ----
  #pragma unroll
  for (int rh = 0; rh < 2; rh++) {
    __syncthreads();  // GEMM2 Ah reads done (rh=0) / prior pass done (rh=1)
    #pragma unroll
    for (int ct = 0; ct < 4; ct++) {
      int col = w * 64 + ct * 16 + ln15;
      float bb = b2[col];
      #pragma unroll
      for (int r = 0; r < 4; r++)
        Cl[(hi * 4 + r) * CP2 + col] = acc[rh][ct][r] + bb;
    }
    __syncthreads();
    #pragma unroll
    for (int k2 = 0; k2 < 4; k2++) {
      int i = tid + k2 * 256;
      int r = i >> 6, c4 = i & 63;
      size_t gidx = ((size_t)(base + rh * 16 + r)) * 256 + c4 * 4;
      float4 hv = *(const float4*)(H + gidx);
      float4 cv = *(const float4*)&Cl[r * CP2 + c4 * 4];
      float4 o4 = {hv.x + cv.x, hv.y + cv.y, hv.z + cv.z, hv.w + cv.w};
      *(float4*)(out + gidx) = o4;
    }
  }
}

extern "C" void kernel_launch(void* const* d_in, const int* in_sizes, int n_in,
                              void* d_out, int out_size, void* d_ws, size_t ws_size,
                              hipStream_t stream) {
  (void)in_sizes; (void)n_in; (void)out_size; (void)ws_size;
  const float* H    = (const float*)d_in[0];
  const int*   pids = (const int*)d_in[1];
  const float* ln1g = (const float*)d_in[2];
  const float* ln1b = (const float*)d_in[3];
  const float* Wq   = (const float*)d_in[4];
  const float* bq   = (const float*)d_in[5];
  const float* Wk   = (const float*)d_in[6];
  const float* bk   = (const float*)d_in[7];
  const float* Wv   = (const float*)d_in[8];
  const float* bv   = (const float*)d_in[9];
  const float* Wo   = (const float*)d_in[10];
  const float* bo   = (const float*)d_in[11];
  const float* ln2g = (const float*)d_in[12];
  const float* ln2b = (const float*)d_in[13];
  const float* fW1  = (const float*)d_in[14];
  const float* fb1  = (const float*)d_in[15];
  const float* fW2  = (const float*)d_in[16];
  const float* fb2  = (const float*)d_in[17];
  const float* mW1  = (const float*)d_in[18];
  const float* mb1  = (const float*)d_in[19];
  const float* mW2  = (const float*)d_in[20];
  const float* mb2  = (const float*)d_in[21];
  float* out = (float*)d_out;
  float* ws = (float*)d_ws;

  int*   histc   = (int*)ws;                          // (32768)
  int*   segstart= (int*)(ws + 32768);                // (2048)
  int*   cnti    = (int*)(ws + 34816);                // (2048)
  int*   order   = (int*)(ws + 36864);                // (131072)
  float* counts  = ws + 167936;                       // (2048)
  float* xw      = ws + 169984;                       // (524288)
  float* yw      = ws + 694272;                       // (524288)
  float* qw      = ws + 1218560;                      // (524288)
  float* kw      = ws + 1742848;                      // (524288)
  float* vw      = ws + 2267136;                      // (524288)
  float* kvb     = ws + 2791424;                      // (65536)
  float* ksb     = ws + 2856960;                      // (1024)
  float* aw      = ws + 2857984;                      // (524288)
  float* x2w     = ws + 3382272;                      // (524288)
  float* y2w     = ws + 3906560;                      // (524288)
  unsigned short* hidb  = (unsigned short*)(ws + 4430848);  // 2M shorts
  unsigned short* psub  = (unsigned short*)(ws + 5479424);  // 512K shorts
  unsigned short* Wpack = (unsigned short*)(ws + 5741568);  // 983040 shorts

  hipMemsetAsync(kvb, 0, (65536 + 1024) * sizeof(float), stream);

  wprep2_kernel<<<480, 256, 0, stream>>>(Wq, Wk, Wv, Wo, fW1, fW2, mW1, mW2, Wpack);
  hist_kernel<<<64, 256, 0, stream>>>(pids, histc);
  prefix_kernel<<<4, 256, 0, stream>>>(histc, segstart, cnti, counts);
  scatter_kernel<<<64, 256, 0, stream>>>(pids, histc, order);
  pool_gather<<<1024, 256, 0, stream>>>(H, order, segstart, cnti, ln1g, ln1b, xw, yw);
  qkv_mfma<<<dim3(128, 3), 256, 0, stream>>>(yw, counts, Wpack, bq, bk, bv, qw, kw, vw);
  kv_kernel<<<128, 256, 0, stream>>>(kw, vw, kvb, ksb);
  attn_kernel<<<256, 256, 0, stream>>>(qw, kvb, ksb, aw);
  oproj_mfma<<<128, 256, 0, stream>>>(aw, xw, Wpack, bo, ln2g, ln2b, x2w, y2w);
  ffn1_mfma<<<dim3(128, 4), 256, 0, stream>>>(y2w, Wpack, fb1, hidb);
  ffn2_mfma<<<128, 256, 0, stream>>>(hidb, x2w, Wpack, fb2,
                                     out + (size_t)S * N * D, psub);
  node_mlp_kernel<<<4096, 256, 0, stream>>>(H, pids, psub,
                                            Wpack + 786432, Wpack + 917504,
                                            mb1, mb2, out);
}

// Round 14
// 227.601 us; speedup vs baseline: 2.1317x; 1.0147x over previous
//
#include <hip/hip_runtime.h>
#include <hip/hip_bf16.h>

#define S 4
#define N 32768
#define D 256
#define KSEG 512
#define NH 4
#define HD 64
#define FF 1024

typedef __attribute__((ext_vector_type(8))) short short8;
typedef __attribute__((ext_vector_type(4))) float f32x4;
typedef __attribute__((ext_vector_type(4))) unsigned int u32x4;
typedef __attribute__((ext_vector_type(2))) unsigned int u32x2;

__device__ __forceinline__ unsigned short f2bf(float f) {
  union { __hip_bfloat16 h; unsigned short u; } cv;
  cv.h = __float2bfloat16(f);
  return cv.u;
}

// tanh-form gelu (|err| vs exact erf-gelu < ~3e-3 abs; threshold 0.11).
// Correct saturation at +/-inf via __expf.
__device__ __forceinline__ float gelu_f(float x) {
  float u = 0.7978845608028654f * (x + 0.044715f * x * x * x);
  float e = __expf(2.f * u);
  float t = 1.f - 2.f / (e + 1.f);
  return 0.5f * x * (1.f + t);
}

__device__ __forceinline__ float wave_reduce_sum(float v) {
  #pragma unroll
  for (int o = 32; o > 0; o >>= 1) v += __shfl_xor(v, o, 64);
  return v;
}

// ---------------- Phase A: counting sort by patch id ----------------
__global__ __launch_bounds__(256) void hist_kernel(
    const int* __restrict__ pids, int* __restrict__ histc)
{
  __shared__ int h[KSEG];
  int b = blockIdx.x, t = threadIdx.x;
  int s = b >> 4, c = b & 15;
  for (int i = t; i < KSEG; i += 256) h[i] = 0;
  __syncthreads();
  const int* p = pids + s * N + c * 2048;
  for (int i = t; i < 2048; i += 256) atomicAdd(&h[p[i]], 1);
  __syncthreads();
  for (int i = t; i < KSEG; i += 256) histc[(s * 16 + c) * KSEG + i] = h[i];
}

__global__ __launch_bounds__(256) void prefix_kernel(
    int* __restrict__ histc, int* __restrict__ segstart,
    int* __restrict__ cnti, float* __restrict__ counts)
{
  __shared__ int h[16 * KSEG];   // 32 KB
  __shared__ int sc[KSEG];
  __shared__ int sa[KSEG], sb[KSEG];
  int s = blockIdx.x, t = threadIdx.x;
  for (int i = t; i < 16 * KSEG; i += 256) h[i] = histc[s * 16 * KSEG + i];
  __syncthreads();
  #pragma unroll
  for (int u = 0; u < 2; u++) {
    int bin = t + u * 256;
    int cc = 0;
    #pragma unroll
    for (int c = 0; c < 16; c++) cc += h[c * KSEG + bin];
    sc[bin] = cc;
    sa[bin] = cc;
  }
  __syncthreads();
  int* src = sa; int* dst = sb;
  for (int off = 1; off < KSEG; off <<= 1) {
    #pragma unroll
    for (int u = 0; u < 2; u++) {
      int bin = t + u * 256;
      int v = src[bin];
      if (bin >= off) v += src[bin - off];
      dst[bin] = v;
    }
    __syncthreads();
    int* tmp = src; src = dst; dst = tmp;
  }
  #pragma unroll
  for (int u = 0; u < 2; u++) {
    int bin = t + u * 256;
    int cc = sc[bin];
    int excl = src[bin] - cc;
    segstart[s * KSEG + bin] = excl;
    cnti[s * KSEG + bin] = cc;
    counts[s * KSEG + bin] = (float)cc;
    int run = excl;
    #pragma unroll
    for (int c = 0; c < 16; c++) {
      int v = h[c * KSEG + bin];
      h[c * KSEG + bin] = run;
      run += v;
    }
  }
  __syncthreads();
  for (int i = t; i < 16 * KSEG; i += 256) histc[s * 16 * KSEG + i] = h[i];
}

__global__ __launch_bounds__(256) void scatter_kernel(
    const int* __restrict__ pids, const int* __restrict__ histc,
    int* __restrict__ order)
{
  __shared__ int offs[KSEG];
  int b = blockIdx.x, t = threadIdx.x;
  int s = b >> 4, c = b & 15;
  for (int i = t; i < KSEG; i += 256) offs[i] = histc[(s * 16 + c) * KSEG + i];
  __syncthreads();
  const int* p = pids + s * N + c * 2048;
  for (int i = t; i < 2048; i += 256) {
    int pid = p[i];
    int pos = atomicAdd(&offs[pid], 1);
    order[s * N + pos] = s * N + c * 2048 + i;
  }
}

// gather-reduce + fused LN1: FOUR waves per segment. grid 2048 (1 seg/block).
__global__ __launch_bounds__(256) void pool_gather(
    const float* __restrict__ H, const int* __restrict__ order,
    const int* __restrict__ segstart, const int* __restrict__ cnti,
    const float* __restrict__ g, const float* __restrict__ bta,
    float* __restrict__ xw, float* __restrict__ yw)
{
  __shared__ float pbuf[4][256];
  int tid = threadIdx.x;
  int w = tid >> 6, lane = tid & 63;
  int seg = blockIdx.x;
  int s = seg >> 9;
  int st = segstart[seg], cn = cnti[seg];
  int en = st + cn;
  const int* ord = order + (size_t)s * N;
  int c4 = lane << 2;
  f32x4 a0 = {0,0,0,0}, a1 = {0,0,0,0}, a2 = {0,0,0,0}, a3 = {0,0,0,0};
  f32x4 a4 = {0,0,0,0}, a5 = {0,0,0,0}, a6 = {0,0,0,0}, a7 = {0,0,0,0};
  int i = st + w;
  for (; i + 28 < en; i += 32) {
    int r0 = ord[i + 0], r1 = ord[i + 4], r2 = ord[i + 8], r3 = ord[i + 12];
    int r4 = ord[i + 16], r5 = ord[i + 20], r6 = ord[i + 24], r7 = ord[i + 28];
    a0 += *(const f32x4*)(H + (size_t)r0 * 256 + c4);
    a1 += *(const f32x4*)(H + (size_t)r1 * 256 + c4);
    a2 += *(const f32x4*)(H + (size_t)r2 * 256 + c4);
    a3 += *(const f32x4*)(H + (size_t)r3 * 256 + c4);
    a4 += *(const f32x4*)(H + (size_t)r4 * 256 + c4);
    a5 += *(const f32x4*)(H + (size_t)r5 * 256 + c4);
    a6 += *(const f32x4*)(H + (size_t)r6 * 256 + c4);
    a7 += *(const f32x4*)(H + (size_t)r7 * 256 + c4);
  }
  for (; i < en; i += 4) {
    int r = ord[i];
    a0 += *(const f32x4*)(H + (size_t)r * 256 + c4);
  }
  f32x4 ssum = ((a0 + a1) + (a2 + a3)) + ((a4 + a5) + (a6 + a7));
  *(f32x4*)&pbuf[w][c4] = ssum;
  __syncthreads();
  if (w == 0) {
    f32x4 tot = *(f32x4*)&pbuf[0][c4];
    tot += *(f32x4*)&pbuf[1][c4];
    tot += *(f32x4*)&pbuf[2][c4];
    tot += *(f32x4*)&pbuf[3][c4];
    float inv = 1.f / fmaxf((float)cn, 1.f);
    tot = tot * inv;
    *(f32x4*)(xw + (size_t)seg * 256 + c4) = tot;
    // fused LN1
    float s1 = tot[0] + tot[1] + tot[2] + tot[3];
    float s2 = tot[0]*tot[0] + tot[1]*tot[1] + tot[2]*tot[2] + tot[3]*tot[3];
    s1 = wave_reduce_sum(s1);
    s2 = wave_reduce_sum(s2);
    float mu = s1 * (1.f / 256.f);
    float var = s2 * (1.f / 256.f) - mu * mu;
    float rs = rsqrtf(var + 1e-5f);
    float4 g4 = *(const float4*)(g + c4);
    float4 b4 = *(const float4*)(bta + c4);
    float4 yv = {(tot[0]-mu)*rs*g4.x + b4.x, (tot[1]-mu)*rs*g4.y + b4.y,
                 (tot[2]-mu)*rs*g4.z + b4.z, (tot[3]-mu)*rs*g4.w + b4.w};
    *(float4*)(yw + (size_t)seg * 256 + c4) = yv;
  }
}

// ---------------- weight pre-pack: all 8 matrices into fragment order ----
__global__ __launch_bounds__(256) void wprep2_kernel(
    const float* __restrict__ Wq, const float* __restrict__ Wk,
    const float* __restrict__ Wv, const float* __restrict__ Wo,
    const float* __restrict__ fW1, const float* __restrict__ fW2,
    const float* __restrict__ mW1, const float* __restrict__ mW2,
    unsigned short* __restrict__ Wpack)
{
  int fi = blockIdx.x * 256 + threadIdx.x;   // 0..122879
  const float* src; int ld, colbase, kcbits; size_t outb; int rfi;
  if (fi < 32768) {
    int m = fi >> 13; rfi = fi & 8191;
    src = (m == 0) ? Wq : ((m == 1) ? Wk : ((m == 2) ? Wv : Wo));
    ld = 256; colbase = 0; kcbits = 3; outb = (size_t)m * 65536;
  } else if (fi < 65536) {
    rfi = fi - 32768; int cc = rfi >> 13; rfi &= 8191;
    src = fW1; ld = 1024; colbase = cc * 256; kcbits = 3;
    outb = 262144 + (size_t)cc * 65536;
  } else if (fi < 98304) {
    rfi = fi - 65536; src = fW2; ld = 256; colbase = 0; kcbits = 5; outb = 524288;
  } else if (fi < 114688) {
    rfi = fi - 98304; src = mW1; ld = 256; colbase = 0; kcbits = 4; outb = 786432;
  } else {
    rfi = fi - 114688; src = mW2; ld = 256; colbase = 0; kcbits = 3; outb = 917504;
  }
  int tile = rfi >> 6, lane = rfi & 63;
  int c = tile >> kcbits, kc = tile & ((1 << kcbits) - 1);
  int k0 = kc * 32 + (lane >> 4) * 8;
  int col = colbase + c * 16 + (lane & 15);
  unsigned int p[4];
  #pragma unroll
  for (int jj = 0; jj < 4; jj++) {
    unsigned int lo = f2bf(src[(size_t)(k0 + 2 * jj) * ld + col]);
    unsigned int hi = f2bf(src[(size_t)(k0 + 2 * jj + 1) * ld + col]);
    p[jj] = lo | (hi << 16);
  }
  u32x4 v = {p[0], p[1], p[2], p[3]};
  *(u32x4*)&Wpack[outb + (size_t)rfi * 8] = v;
}

// ---------------- MFMA patch-GEMM template pieces (16 rows x 256 cols) ----
#define AP3 264  // A row stride (bf16): 256 + 8 pad
#define CP3 260  // C row stride (f32): 256 + 4 pad

// QKV: grid (128, 3). epilogue: phi (m<=1), mask (m>=1).
__global__ __launch_bounds__(256, 4) void qkv_mfma(
    const float* __restrict__ y, const float* __restrict__ counts,
    const unsigned short* __restrict__ Wpack,
    const float* __restrict__ bq, const float* __restrict__ bk,
    const float* __restrict__ bv,
    float* __restrict__ qo, float* __restrict__ ko, float* __restrict__ vo)
{
  __shared__ __align__(16) unsigned char smem[16 * CP3 * 4];  // 16640 B
  unsigned short* Ah = (unsigned short*)smem;
  float* Cl = (float*)smem;
  int m = blockIdx.y;
  const unsigned short* Wf = Wpack + (size_t)m * 65536;
  const float* bias = (m == 0) ? bq : ((m == 1) ? bk : bv);
  float* outp = (m == 0) ? qo : ((m == 1) ? ko : vo);
  int tid = threadIdx.x, lane = tid & 63, w = tid >> 6;
  int ln15 = lane & 15, hi = lane >> 4;
  int base = blockIdx.x * 16;

  for (int i = tid; i < 16 * 64; i += 256) {
    int r = i >> 6, c4 = i & 63;
    float4 f = *(const float4*)(y + ((size_t)(base + r)) * 256 + c4 * 4);
    unsigned int lo = (unsigned int)f2bf(f.x) | ((unsigned int)f2bf(f.y) << 16);
    unsigned int h2 = (unsigned int)f2bf(f.z) | ((unsigned int)f2bf(f.w) << 16);
    u32x2 val = {lo, h2};
    *((u32x2*)&Ah[r * AP3 + c4 * 4]) = val;
  }
  __syncthreads();

  f32x4 acc[4];
  #pragma unroll
  for (int c = 0; c < 4; c++) acc[c] = (f32x4){0.f, 0.f, 0.f, 0.f};
  const unsigned short* Wl = Wf + (size_t)lane * 8;
  short8 bcur[4];
  #pragma unroll
  for (int ct = 0; ct < 4; ct++)
    bcur[ct] = *(const short8*)(Wl + ((w * 4 + ct) * 8 + 0) * 512);
  #pragma unroll
  for (int kc = 0; kc < 8; kc++) {
    short8 a = *(const short8*)(&Ah[ln15 * AP3 + kc * 32 + hi * 8]);
    short8 bnext[4];
    if (kc < 7) {
      #pragma unroll
      for (int ct = 0; ct < 4; ct++)
        bnext[ct] = *(const short8*)(Wl + ((w * 4 + ct) * 8 + kc + 1) * 512);
    }
    #pragma unroll
    for (int ct = 0; ct < 4; ct++)
      acc[ct] = __builtin_amdgcn_mfma_f32_16x16x32_bf16(a, bcur[ct], acc[ct], 0, 0, 0);
    if (kc < 7) {
      #pragma unroll
      for (int ct = 0; ct < 4; ct++) bcur[ct] = bnext[ct];
    }
  }
  __syncthreads();  // A reads done; reuse smem as Cl

  float mk[4];
  #pragma unroll
  for (int r = 0; r < 4; r++)
    mk[r] = (counts[base + hi * 4 + r] > 0.f) ? 1.f : 0.f;
  #pragma unroll
  for (int ct = 0; ct < 4; ct++) {
    int col = w * 64 + ct * 16 + ln15;
    float bb = bias[col];
    #pragma unroll
    for (int r = 0; r < 4; r++) {
      float tv = acc[ct][r] + bb;
      if (m <= 1) tv = (tv > 0.f) ? (tv + 1.f) : __expf(tv);
      if (m >= 1) tv *= mk[r];
      Cl[(hi * 4 + r) * CP3 + col] = tv;
    }
  }
  __syncthreads();
  for (int i = tid; i < 16 * 64; i += 256) {
    int r = i >> 6, c4 = i & 63;
    *(float4*)(outp + ((size_t)(base + r)) * 256 + c4 * 4) =
        *(const float4*)&Cl[r * CP3 + c4 * 4];
  }
}

// oproj + fused LN2: x2 = x + a@Wo + bo; y2 = LN(x2). grid 128.
__global__ __launch_bounds__(256, 4) void oproj_mfma(
    const float* __restrict__ aw, const float* __restrict__ xw,
    const unsigned short* __restrict__ Wpack, const float* __restrict__ bo,
    const float* __restrict__ g, const float* __restrict__ bta,
    float* __restrict__ x2, float* __restrict__ y2)
{
  __shared__ __align__(16) unsigned char smem[16 * CP3 * 4];
  unsigned short* Ah = (unsigned short*)smem;
  float* Cl = (float*)smem;
  const unsigned short* Wf = Wpack + 196608;
  int tid = threadIdx.x, lane = tid & 63, w = tid >> 6;
  int ln15 = lane & 15, hi = lane >> 4;
  int base = blockIdx.x * 16;

  for (int i = tid; i < 16 * 64; i += 256) {
    int r = i >> 6, c4 = i & 63;
    float4 f = *(const float4*)(aw + ((size_t)(base + r)) * 256 + c4 * 4);
    unsigned int lo = (unsigned int)f2bf(f.x) | ((unsigned int)f2bf(f.y) << 16);
    unsigned int h2 = (unsigned int)f2bf(f.z) | ((unsigned int)f2bf(f.w) << 16);
    u32x2 val = {lo, h2};
    *((u32x2*)&Ah[r * AP3 + c4 * 4]) = val;
  }
  __syncthreads();

  f32x4 acc[4];
  #pragma unroll
  for (int c = 0; c < 4; c++) acc[c] = (f32x4){0.f, 0.f, 0.f, 0.f};
  const unsigned short* Wl = Wf + (size_t)lane * 8;
  short8 bcur[4];
  #pragma unroll
  for (int ct = 0; ct < 4; ct++)
    bcur[ct] = *(const short8*)(Wl + ((w * 4 + ct) * 8 + 0) * 512);
  #pragma unroll
  for (int kc = 0; kc < 8; kc++) {
    short8 a = *(const short8*)(&Ah[ln15 * AP3 + kc * 32 + hi * 8]);
    short8 bnext[4];
    if (kc < 7) {
      #pragma unroll
      for (int ct = 0; ct < 4; ct++)
        bnext[ct] = *(const short8*)(Wl + ((w * 4 + ct) * 8 + kc + 1) * 512);
    }
    #pragma unroll
    for (int ct = 0; ct < 4; ct++)
      acc[ct] = __builtin_amdgcn_mfma_f32_16x16x32_bf16(a, bcur[ct], acc[ct], 0, 0, 0);
    if (kc < 7) {
      #pragma unroll
      for (int ct = 0; ct < 4; ct++) bcur[ct] = bnext[ct];
    }
  }
  __syncthreads();

  #pragma unroll
  for (int ct = 0; ct < 4; ct++) {
    int col = w * 64 + ct * 16 + ln15;
    float bb = bo[col];
    #pragma unroll
    for (int r = 0; r < 4; r++)
      Cl[(hi * 4 + r) * CP3 + col] = acc[ct][r] + bb;
  }
  __syncthreads();
  // fused residual + LN2: wave w handles rows {4k + w}
  int c4 = lane << 2;
  float4 g4 = *(const float4*)(g + c4);
  float4 b4 = *(const float4*)(bta + c4);
  #pragma unroll
  for (int k = 0; k < 4; k++) {
    int r = k * 4 + w;
    size_t gbase = ((size_t)(base + r)) * 256 + c4;
    float4 xv = *(const float4*)(xw + gbase);
    float4 cv = *(const float4*)&Cl[r * CP3 + c4];
    float4 x2v = {xv.x + cv.x, xv.y + cv.y, xv.z + cv.z, xv.w + cv.w};
    *(float4*)(x2 + gbase) = x2v;
    float s1 = x2v.x + x2v.y + x2v.z + x2v.w;
    float s2 = x2v.x*x2v.x + x2v.y*x2v.y + x2v.z*x2v.z + x2v.w*x2v.w;
    s1 = wave_reduce_sum(s1);
    s2 = wave_reduce_sum(s2);
    float mu = s1 * (1.f / 256.f);
    float var = s2 * (1.f / 256.f) - mu * mu;
    float rs = rsqrtf(var + 1e-5f);
    float4 yv = {(x2v.x-mu)*rs*g4.x + b4.x, (x2v.y-mu)*rs*g4.y + b4.y,
                 (x2v.z-mu)*rs*g4.z + b4.z, (x2v.w-mu)*rs*g4.w + b4.w};
    *(float4*)(y2 + gbase) = yv;
  }
}

// ffn1: hidb = bf16(gelu(y2 @ fW1 + b1)). grid (128, 4 col-chunks).
__global__ __launch_bounds__(256, 4) void ffn1_mfma(
    const float* __restrict__ y2, const unsigned short* __restrict__ Wpack,
    const float* __restrict__ b1, unsigned short* __restrict__ hidb)
{
  __shared__ __align__(16) unsigned char smem[16 * CP3 * 4];
  unsigned short* Ah = (unsigned short*)smem;
  int cc = blockIdx.y;
  const unsigned short* Wf = Wpack + 262144 + (size_t)cc * 65536;
  int tid = threadIdx.x, lane = tid & 63, w = tid >> 6;
  int ln15 = lane & 15, hi = lane >> 4;
  int base = blockIdx.x * 16;

  for (int i = tid; i < 16 * 64; i += 256) {
    int r = i >> 6, c4 = i & 63;
    float4 f = *(const float4*)(y2 + ((size_t)(base + r)) * 256 + c4 * 4);
    unsigned int lo = (unsigned int)f2bf(f.x) | ((unsigned int)f2bf(f.y) << 16);
    unsigned int h2 = (unsigned int)f2bf(f.z) | ((unsigned int)f2bf(f.w) << 16);
    u32x2 val = {lo, h2};
    *((u32x2*)&Ah[r * AP3 + c4 * 4]) = val;
  }
  __syncthreads();

  f32x4 acc[4];
  #pragma unroll
  for (int c = 0; c < 4; c++) acc[c] = (f32x4){0.f, 0.f, 0.f, 0.f};
  const unsigned short* Wl = Wf + (size_t)lane * 8;
  short8 bcur[4];
  #pragma unroll
  for (int ct = 0; ct < 4; ct++)
    bcur[ct] = *(const short8*)(Wl + ((w * 4 + ct) * 8 + 0) * 512);
  #pragma unroll
  for (int kc = 0; kc < 8; kc++) {
    short8 a = *(const short8*)(&Ah[ln15 * AP3 + kc * 32 + hi * 8]);
    short8 bnext[4];
    if (kc < 7) {
      #pragma unroll
      for (int ct = 0; ct < 4; ct++)
        bnext[ct] = *(const short8*)(Wl + ((w * 4 + ct) * 8 + kc + 1) * 512);
    }
    #pragma unroll
    for (int ct = 0; ct < 4; ct++)
      acc[ct] = __builtin_amdgcn_mfma_f32_16x16x32_bf16(a, bcur[ct], acc[ct], 0, 0, 0);
    if (kc < 7) {
      #pragma unroll
      for (int ct = 0; ct < 4; ct++) bcur[ct] = bnext[ct];
    }
  }
  __syncthreads();

  #pragma unroll
  for (int ct = 0; ct < 4; ct++) {
    int col = w * 64 + ct * 16 + ln15;
    float bb = b1[cc * 256 + col];
    #pragma unroll
    for (int r = 0; r < 4; r++)
      Ah[(hi * 4 + r) * 256 + col] = f2bf(gelu_f(acc[ct][r] + bb));
  }
  __syncthreads();
  for (int i = tid; i < 16 * 32; i += 256) {
    int r = i >> 5, c8 = i & 31;
    *(u32x4*)(hidb + ((size_t)(base + r)) * FF + cc * 256 + c8 * 8) =
        *(const u32x4*)&Ah[r * 256 + c8 * 8];
  }
}

// ffn2: psu = x2 + hidb @ fW2 + b2 (fp32 out + bf16 psub). grid 128. K=1024.
__global__ __launch_bounds__(256, 4) void ffn2_mfma(
    const unsigned short* __restrict__ hidb, const float* __restrict__ x2,
    const unsigned short* __restrict__ Wpack, const float* __restrict__ b2,
    float* __restrict__ psu_out, unsigned short* __restrict__ psub)
{
  __shared__ __align__(16) unsigned char smem[16 * CP3 * 4];
  unsigned short* Ah = (unsigned short*)smem;
  float* Cl = (float*)smem;
  const unsigned short* Wf = Wpack + 524288;
  int tid = threadIdx.x, lane = tid & 63, w = tid >> 6;
  int ln15 = lane & 15, hi = lane >> 4;
  int base = blockIdx.x * 16;

  f32x4 acc[4];
  #pragma unroll
  for (int c = 0; c < 4; c++) acc[c] = (f32x4){0.f, 0.f, 0.f, 0.f};
  const unsigned short* Wl = Wf + (size_t)lane * 8;

  for (int ch = 0; ch < 4; ch++) {
    __syncthreads();
    for (int i = tid; i < 16 * 32; i += 256) {
      int r = i >> 5, c8 = i & 31;
      *((u32x4*)&Ah[r * AP3 + c8 * 8]) =
          *(const u32x4*)(hidb + ((size_t)(base + r)) * FF + ch * 256 + c8 * 8);
    }
    __syncthreads();
    short8 bcur[4];
    #pragma unroll
    for (int ct = 0; ct < 4; ct++)
      bcur[ct] = *(const short8*)(Wl + ((w * 4 + ct) * 32 + ch * 8 + 0) * 512);
    #pragma unroll
    for (int kc = 0; kc < 8; kc++) {
      short8 a = *(const short8*)(&Ah[ln15 * AP3 + kc * 32 + hi * 8]);
      short8 bnext[4];
      if (kc < 7) {
        #pragma unroll
        for (int ct = 0; ct < 4; ct++)
          bnext[ct] = *(const short8*)(Wl + ((w * 4 + ct) * 32 + ch * 8 + kc + 1) * 512);
      }
      #pragma unroll
      for (int ct = 0; ct < 4; ct++)
        acc[ct] = __builtin_amdgcn_mfma_f32_16x16x32_bf16(a, bcur[ct], acc[ct], 0, 0, 0);
      if (kc < 7) {
        #pragma unroll
        for (int ct = 0; ct < 4; ct++) bcur[ct] = bnext[ct];
      }
    }
  }
  __syncthreads();

  #pragma unroll
  for (int ct = 0; ct < 4; ct++) {
    int col = w * 64 + ct * 16 + ln15;
    float bb = b2[col];
    #pragma unroll
    for (int r = 0; r < 4; r++)
      Cl[(hi * 4 + r) * CP3 + col] = acc[ct][r] + bb;
  }
  __syncthreads();
  for (int i = tid; i < 16 * 64; i += 256) {
    int r = i >> 6, c4 = i & 63;
    size_t gidx = ((size_t)(base + r)) * 256 + c4 * 4;
    float4 xv = *(const float4*)(x2 + gidx);
    float4 cv = *(const float4*)&Cl[r * CP3 + c4 * 4];
    float4 o = {xv.x + cv.x, xv.y + cv.y, xv.z + cv.z, xv.w + cv.w};
    *(float4*)(psu_out + gidx) = o;
    unsigned int lo = (unsigned int)f2bf(o.x) | ((unsigned int)f2bf(o.y) << 16);
    unsigned int h2 = (unsigned int)f2bf(o.z) | ((unsigned int)f2bf(o.w) << 16);
    u32x2 pb = {lo, h2};
    *(u32x2*)(psub + gidx) = pb;
  }
}

// kv[s,h,d,e] = sum_k k*v ; ksum. grid 128
__global__ __launch_bounds__(256) void kv_kernel(
    const float* __restrict__ kw, const float* __restrict__ vw,
    float* __restrict__ kvb, float* __restrict__ ksb)
{
  int b = blockIdx.x, t = threadIdx.x;
  int s = b / (NH * 8), h = (b / 8) % NH, ck = b & 7;
  __shared__ float kl[64 * 64];
  __shared__ float vl[64 * 64];
  for (int i = t; i < 4096; i += 256) {
    int kk = i >> 6, d = i & 63;
    size_t rowb = ((size_t)(s * KSEG + ck * 64 + kk) * NH + h) * HD + d;
    kl[i] = kw[rowb];
    vl[i] = vw[rowb];
  }
  __syncthreads();
  int d = t & 63, eb = (t >> 6) * 16;
  f32x4 a4[4];
  #pragma unroll
  for (int j = 0; j < 4; j++) a4[j] = (f32x4){0.f, 0.f, 0.f, 0.f};
  float acck = 0.f;
  #pragma unroll 4
  for (int kk = 0; kk < 64; kk++) {
    float kd = kl[kk * 64 + d];
    acck += kd;
    #pragma unroll
    for (int j = 0; j < 4; j++) {
      f32x4 vv = *(const f32x4*)&vl[kk * 64 + eb + j * 4];
      a4[j] += kd * vv;
    }
  }
  #pragma unroll
  for (int j = 0; j < 4; j++)
    #pragma unroll
    for (int e = 0; e < 4; e++)
      atomicAdd(&kvb[(((size_t)(s * NH + h)) * HD + d) * HD + eb + j * 4 + e], a4[j][e]);
  if (t < 64) atomicAdd(&ksb[(s * NH + h) * HD + t], acck);
}

// a = num/den per row. grid 256 blocks
__global__ __launch_bounds__(256) void attn_kernel(
    const float* __restrict__ qw, const float* __restrict__ kvb,
    const float* __restrict__ ksb, float* __restrict__ aw)
{
  __shared__ float kvl[64 * 64];
  __shared__ float ksl[64];
  __shared__ float ql[32 * 64];
  int t = threadIdx.x, b = blockIdx.x;
  int sh = b >> 4, rb = b & 15;
  int s = sh >> 2, h = sh & 3;
  for (int i = t; i < 4096; i += 256) kvl[i] = kvb[sh * 4096 + i];
  if (t < 64) ksl[t] = ksb[sh * 64 + t];
  for (int i = t; i < 2048; i += 256) {
    int r = i >> 6, d = i & 63;
    ql[i] = qw[((size_t)(s * KSEG + rb * 32 + r)) * 256 + h * 64 + d];
  }
  __syncthreads();
  int e = t & 63, rg = t >> 6;
  float num[8], den[8];
  #pragma unroll
  for (int r = 0; r < 8; r++) { num[r] = 0.f; den[r] = 0.f; }
  #pragma unroll 4
  for (int d4 = 0; d4 < 64; d4 += 4) {
    float4 ks4 = *(const float4*)&ksl[d4];
    float kv0 = kvl[(d4 + 0) * 64 + e];
    float kv1 = kvl[(d4 + 1) * 64 + e];
    float kv2 = kvl[(d4 + 2) * 64 + e];
    float kv3 = kvl[(d4 + 3) * 64 + e];
    #pragma unroll
    for (int r = 0; r < 8; r++) {
      float4 q4 = *(const float4*)&ql[(rg * 8 + r) * 64 + d4];
      num[r] += q4.x * kv0 + q4.y * kv1 + q4.z * kv2 + q4.w * kv3;
      den[r] += q4.x * ks4.x + q4.y * ks4.y + q4.z * ks4.z + q4.w * ks4.w;
    }
  }
  #pragma unroll
  for (int r = 0; r < 8; r++) {
    int row = rb * 32 + rg * 8 + r;
    aw[((size_t)(s * KSEG + row)) * 256 + h * 64 + e] = num[r] / (den[r] + 1e-6f);
  }
}

// ---------------- Phase C: fused node MLP (bf16 MFMA), v5 (R10 proven) ----
// 32-row tiles, grid 4096, (256,5), LDS round-trip epilogue with H re-read
// from global (L3-hit), early-issue psu gather. Only delta vs R13: fast gelu.
#define AP2 264
#define CP2 260
__global__ __launch_bounds__(256, 5) void node_mlp_kernel(
    const float* __restrict__ H, const int* __restrict__ pids,
    const unsigned short* __restrict__ psub,
    const unsigned short* __restrict__ W1f, const unsigned short* __restrict__ W2f,
    const float* __restrict__ b1, const float* __restrict__ b2,
    float* __restrict__ out)
{
  __shared__ __align__(16) unsigned char smem[32 * AP2 * 2];  // 16896 B
  __shared__ int pidl[32];
  unsigned short* Ah = (unsigned short*)smem;
  float* Cl = (float*)smem;
  int tid = threadIdx.x;
  int lane = tid & 63, w = tid >> 6;
  int ln15 = lane & 15, hi = lane >> 4;
  int base = blockIdx.x * 32;

  f32x4 acc[2][4];
  #pragma unroll
  for (int a = 0; a < 2; a++)
    #pragma unroll
    for (int c = 0; c < 4; c++) acc[a][c] = (f32x4){0.f, 0.f, 0.f, 0.f};

  // ---- stage 1: H cols 0..255 (fp32 -> bf16) ----
  if (tid < 32) pidl[tid] = pids[base + tid];
  #pragma unroll
  for (int k = 0; k < 8; k++) {
    int i = tid + k * 256;
    int r = i >> 6, c4 = i & 63;
    float4 f = *(const float4*)(H + ((size_t)(base + r)) * 256 + c4 * 4);
    unsigned int lo = (unsigned int)f2bf(f.x) | ((unsigned int)f2bf(f.y) << 16);
    unsigned int hi2 = (unsigned int)f2bf(f.z) | ((unsigned int)f2bf(f.w) << 16);
    u32x2 val = {lo, hi2};
    *((u32x2*)&Ah[r * AP2 + c4 * 4]) = val;
  }
  __syncthreads();  // B1

  const unsigned short* Wl1 = W1f + (size_t)lane * 8;
  // ---- GEMM1a kc 0..7 (K 0..255) ----
  {
    short8 bcur[4];
    #pragma unroll
    for (int ct = 0; ct < 4; ct++)
      bcur[ct] = *(const short8*)(Wl1 + ((w * 4 + ct) * 16 + 0) * 512);
    #pragma unroll
    for (int kc = 0; kc < 8; kc++) {
      short8 a[2], bnext[4];
      #pragma unroll
      for (int rt = 0; rt < 2; rt++)
        a[rt] = *(const short8*)(&Ah[(rt * 16 + ln15) * AP2 + kc * 32 + hi * 8]);
      if (kc < 7) {
        #pragma unroll
        for (int ct = 0; ct < 4; ct++)
          bnext[ct] = *(const short8*)(Wl1 + ((w * 4 + ct) * 16 + kc + 1) * 512);
      }
      __builtin_amdgcn_s_setprio(1);
      #pragma unroll
      for (int rt = 0; rt < 2; rt++)
        #pragma unroll
        for (int ct = 0; ct < 4; ct++)
          acc[rt][ct] = __builtin_amdgcn_mfma_f32_16x16x32_bf16(a[rt], bcur[ct], acc[rt][ct], 0, 0, 0);
      __builtin_amdgcn_s_setprio(0);
      if (kc < 7) {
        #pragma unroll
        for (int ct = 0; ct < 4; ct++) bcur[ct] = bnext[ct];
      }
    }
  }

  // ---- early-issue psu gather (loads in flight across B2) ----
  int ss = base >> 15;
  int r0 = tid >> 5, ch = tid & 31;
  int p0 = pidl[r0], p1 = pidl[8 + r0], p2 = pidl[16 + r0], p3 = pidl[24 + r0];
  const unsigned short* pbase = psub + (size_t)(ss * KSEG) * 256 + (size_t)ch * 8;
  u32x4 g0 = *(const u32x4*)(pbase + (size_t)p0 * 256);
  u32x4 g1 = *(const u32x4*)(pbase + (size_t)p1 * 256);
  u32x4 g2 = *(const u32x4*)(pbase + (size_t)p2 * 256);
  u32x4 g3 = *(const u32x4*)(pbase + (size_t)p3 * 256);
  __syncthreads();  // B2 (GEMM1a A-reads done)
  *(u32x4*)&Ah[r0 * AP2 + ch * 8] = g0;
  *(u32x4*)&Ah[(8 + r0) * AP2 + ch * 8] = g1;
  *(u32x4*)&Ah[(16 + r0) * AP2 + ch * 8] = g2;
  *(u32x4*)&Ah[(24 + r0) * AP2 + ch * 8] = g3;
  __syncthreads();  // B3

  // ---- GEMM1b kc 8..15 (K 256..511) ----
  {
    short8 bcur[4];
    #pragma unroll
    for (int ct = 0; ct < 4; ct++)
      bcur[ct] = *(const short8*)(Wl1 + ((w * 4 + ct) * 16 + 8) * 512);
    #pragma unroll
    for (int kc = 8; kc < 16; kc++) {
      short8 a[2], bnext[4];
      #pragma unroll
      for (int rt = 0; rt < 2; rt++)
        a[rt] = *(const short8*)(&Ah[(rt * 16 + ln15) * AP2 + (kc - 8) * 32 + hi * 8]);
      if (kc < 15) {
        #pragma unroll
        for (int ct = 0; ct < 4; ct++)
          bnext[ct] = *(const short8*)(Wl1 + ((w * 4 + ct) * 16 + kc + 1) * 512);
      }
      __builtin_amdgcn_s_setprio(1);
      #pragma unroll
      for (int rt = 0; rt < 2; rt++)
        #pragma unroll
        for (int ct = 0; ct < 4; ct++)
          acc[rt][ct] = __builtin_amdgcn_mfma_f32_16x16x32_bf16(a[rt], bcur[ct], acc[rt][ct], 0, 0, 0);
      __builtin_amdgcn_s_setprio(0);
      if (kc < 15) {
        #pragma unroll
        for (int ct = 0; ct < 4; ct++) bcur[ct] = bnext[ct];
      }
    }
  }
  __syncthreads();  // B4

  // ---- epi1: bias + gelu -> Hid (aliased over Ah) ----
  #pragma unroll
  for (int rt = 0; rt < 2; rt++) {
    #pragma unroll
    for (int ct = 0; ct < 4; ct++) {
      int col = w * 64 + ct * 16 + ln15;
      float bb = b1[col];
      #pragma unroll
      for (int r = 0; r < 4; r++) {
        int row = rt * 16 + hi * 4 + r;
        Ah[row * AP2 + col] = f2bf(gelu_f(acc[rt][ct][r] + bb));
      }
      acc[rt][ct] = (f32x4){0.f, 0.f, 0.f, 0.f};
    }
  }
  __syncthreads();  // B5

  // ---- GEMM2: [32x256] @ [256x256] ----
  {
    const unsigned short* Wl2 = W2f + (size_t)lane * 8;
    short8 bcur[4];
    #pragma unroll
    for (int ct = 0; ct < 4; ct++)
      bcur[ct] = *(const short8*)(Wl2 + ((w * 4 + ct) * 8 + 0) * 512);
    #pragma unroll
    for (int kc = 0; kc < 8; kc++) {
      short8 a[2], bnext[4];
      #pragma unroll
      for (int rt = 0; rt < 2; rt++)
        a[rt] = *(const short8*)(&Ah[(rt * 16 + ln15) * AP2 + kc * 32 + hi * 8]);
      if (kc < 7) {
        #pragma unroll
        for (int ct = 0; ct < 4; ct++)
          bnext[ct] = *(const short8*)(Wl2 + ((w * 4 + ct) * 8 + kc + 1) * 512);
      }
      __builtin_amdgcn_s_setprio(1);
      #pragma unroll
      for (int rt = 0; rt < 2; rt++)
        #pragma unroll
        for (int ct = 0; ct < 4; ct++)
          acc[rt][ct] = __builtin_amdgcn_mfma_f32_16x16x32_bf16(a[rt], bcur[ct], acc[rt][ct], 0, 0, 0);
      __builtin_amdgcn_s_setprio(0);
      if (kc < 7) {
        #pragma unroll
        for (int ct = 0; ct < 4; ct++) bcur[ct] = bnext[ct];
      }
    }
  }

  // ---- final epilogue: two 16-row LDS passes, H re-read from global ----
  #pragma unroll
  for (int rh = 0; rh < 2; rh++) {
    __syncthreads();  // GEMM2 Ah reads done (rh=0) / prior pass done (rh=1)
    #pragma unroll
    for (int ct = 0; ct < 4; ct++) {
      int col = w * 64 + ct * 16 + ln15;
      float bb = b2[col];
      #pragma unroll
      for (int r = 0; r < 4; r++)
        Cl[(hi * 4 + r) * CP2 + col] = acc[rh][ct][r] + bb;
    }
    __syncthreads();
    #pragma unroll
    for (int k2 = 0; k2 < 4; k2++) {
      int i = tid + k2 * 256;
      int r = i >> 6, c4 = i & 63;
      size_t gidx = ((size_t)(base + rh * 16 + r)) * 256 + c4 * 4;
      float4 hv = *(const float4*)(H + gidx);
      float4 cv = *(const float4*)&Cl[r * CP2 + c4 * 4];
      float4 o4 = {hv.x + cv.x, hv.y + cv.y, hv.z + cv.z, hv.w + cv.w};
      *(float4*)(out + gidx) = o4;
    }
  }
}

extern "C" void kernel_launch(void* const* d_in, const int* in_sizes, int n_in,
                              void* d_out, int out_size, void* d_ws, size_t ws_size,
                              hipStream_t stream) {
  (void)in_sizes; (void)n_in; (void)out_size; (void)ws_size;
  const float* H    = (const float*)d_in[0];
  const int*   pids = (const int*)d_in[1];
  const float* ln1g = (const float*)d_in[2];
  const float* ln1b = (const float*)d_in[3];
  const float* Wq   = (const float*)d_in[4];
  const float* bq   = (const float*)d_in[5];
  const float* Wk   = (const float*)d_in[6];
  const float* bk   = (const float*)d_in[7];
  const float* Wv   = (const float*)d_in[8];
  const float* bv   = (const float*)d_in[9];
  const float* Wo   = (const float*)d_in[10];
  const float* bo   = (const float*)d_in[11];
  const float* ln2g = (const float*)d_in[12];
  const float* ln2b = (const float*)d_in[13];
  const float* fW1  = (const float*)d_in[14];
  const float* fb1  = (const float*)d_in[15];
  const float* fW2  = (const float*)d_in[16];
  const float* fb2  = (const float*)d_in[17];
  const float* mW1  = (const float*)d_in[18];
  const float* mb1  = (const float*)d_in[19];
  const float* mW2  = (const float*)d_in[20];
  const float* mb2  = (const float*)d_in[21];
  float* out = (float*)d_out;
  float* ws = (float*)d_ws;

  int*   histc   = (int*)ws;                          // (32768)
  int*   segstart= (int*)(ws + 32768);                // (2048)
  int*   cnti    = (int*)(ws + 34816);                // (2048)
  int*   order   = (int*)(ws + 36864);                // (131072)
  float* counts  = ws + 167936;                       // (2048)
  float* xw      = ws + 169984;                       // (524288)
  float* yw      = ws + 694272;                       // (524288)
  float* qw      = ws + 1218560;                      // (524288)
  float* kw      = ws + 1742848;                      // (524288)
  float* vw      = ws + 2267136;                      // (524288)
  float* kvb     = ws + 2791424;                      // (65536)
  float* ksb     = ws + 2856960;                      // (1024)
  float* aw      = ws + 2857984;                      // (524288)
  float* x2w     = ws + 3382272;                      // (524288)
  float* y2w     = ws + 3906560;                      // (524288)
  unsigned short* hidb  = (unsigned short*)(ws + 4430848);  // 2M shorts
  unsigned short* psub  = (unsigned short*)(ws + 5479424);  // 512K shorts
  unsigned short* Wpack = (unsigned short*)(ws + 5741568);  // 983040 shorts

  hipMemsetAsync(kvb, 0, (65536 + 1024) * sizeof(float), stream);

  wprep2_kernel<<<480, 256, 0, stream>>>(Wq, Wk, Wv, Wo, fW1, fW2, mW1, mW2, Wpack);
  hist_kernel<<<64, 256, 0, stream>>>(pids, histc);
  prefix_kernel<<<4, 256, 0, stream>>>(histc, segstart, cnti, counts);
  scatter_kernel<<<64, 256, 0, stream>>>(pids, histc, order);
  pool_gather<<<2048, 256, 0, stream>>>(H, order, segstart, cnti, ln1g, ln1b, xw, yw);
  qkv_mfma<<<dim3(128, 3), 256, 0, stream>>>(yw, counts, Wpack, bq, bk, bv, qw, kw, vw);
  kv_kernel<<<128, 256, 0, stream>>>(kw, vw, kvb, ksb);
  attn_kernel<<<256, 256, 0, stream>>>(qw, kvb, ksb, aw);
  oproj_mfma<<<128, 256, 0, stream>>>(aw, xw, Wpack, bo, ln2g, ln2b, x2w, y2w);
  ffn1_mfma<<<dim3(128, 4), 256, 0, stream>>>(y2w, Wpack, fb1, hidb);
  ffn2_mfma<<<128, 256, 0, stream>>>(hidb, x2w, Wpack, fb2,
                                     out + (size_t)S * N * D, psub);
  node_mlp_kernel<<<4096, 256, 0, stream>>>(H, pids, psub,
                                            Wpack + 786432, Wpack + 917504,
                                            mb1, mb2, out);
}

// Round 15
// 206.584 us; speedup vs baseline: 2.3485x; 1.1017x over previous
//
#include <hip/hip_runtime.h>
#include <hip/hip_bf16.h>

#define S 4
#define N 32768
#define D 256
#define KSEG 512
#define NH 4
#define HD 64
#define FF 1024

typedef __attribute__((ext_vector_type(8))) short short8;
typedef __attribute__((ext_vector_type(4))) float f32x4;
typedef __attribute__((ext_vector_type(4))) unsigned int u32x4;
typedef __attribute__((ext_vector_type(2))) unsigned int u32x2;

__device__ __forceinline__ unsigned short f2bf(float f) {
  union { __hip_bfloat16 h; unsigned short u; } cv;
  cv.h = __float2bfloat16(f);
  return cv.u;
}

// tanh-form gelu (|err| vs exact erf-gelu < ~3e-3 abs; threshold 0.11).
__device__ __forceinline__ float gelu_f(float x) {
  float u = 0.7978845608028654f * (x + 0.044715f * x * x * x);
  float e = __expf(2.f * u);
  float t = 1.f - 2.f / (e + 1.f);
  return 0.5f * x * (1.f + t);
}

__device__ __forceinline__ float wave_reduce_sum(float v) {
  #pragma unroll
  for (int o = 32; o > 0; o >>= 1) v += __shfl_xor(v, o, 64);
  return v;
}

// ---------------- Phase A: counting sort by patch id ----------------
__global__ __launch_bounds__(256) void hist_kernel(
    const int* __restrict__ pids, int* __restrict__ histc)
{
  __shared__ int h[KSEG];
  int b = blockIdx.x, t = threadIdx.x;
  int s = b >> 4, c = b & 15;
  for (int i = t; i < KSEG; i += 256) h[i] = 0;
  __syncthreads();
  const int* p = pids + s * N + c * 2048;
  for (int i = t; i < 2048; i += 256) atomicAdd(&h[p[i]], 1);
  __syncthreads();
  for (int i = t; i < KSEG; i += 256) histc[(s * 16 + c) * KSEG + i] = h[i];
}

__global__ __launch_bounds__(256) void prefix_kernel(
    int* __restrict__ histc, int* __restrict__ segstart,
    int* __restrict__ cnti, float* __restrict__ counts)
{
  __shared__ int h[16 * KSEG];   // 32 KB
  __shared__ int sc[KSEG];
  __shared__ int sa[KSEG], sb[KSEG];
  int s = blockIdx.x, t = threadIdx.x;
  for (int i = t; i < 16 * KSEG; i += 256) h[i] = histc[s * 16 * KSEG + i];
  __syncthreads();
  #pragma unroll
  for (int u = 0; u < 2; u++) {
    int bin = t + u * 256;
    int cc = 0;
    #pragma unroll
    for (int c = 0; c < 16; c++) cc += h[c * KSEG + bin];
    sc[bin] = cc;
    sa[bin] = cc;
  }
  __syncthreads();
  int* src = sa; int* dst = sb;
  for (int off = 1; off < KSEG; off <<= 1) {
    #pragma unroll
    for (int u = 0; u < 2; u++) {
      int bin = t + u * 256;
      int v = src[bin];
      if (bin >= off) v += src[bin - off];
      dst[bin] = v;
    }
    __syncthreads();
    int* tmp = src; src = dst; dst = tmp;
  }
  #pragma unroll
  for (int u = 0; u < 2; u++) {
    int bin = t + u * 256;
    int cc = sc[bin];
    int excl = src[bin] - cc;
    segstart[s * KSEG + bin] = excl;
    cnti[s * KSEG + bin] = cc;
    counts[s * KSEG + bin] = (float)cc;
    int run = excl;
    #pragma unroll
    for (int c = 0; c < 16; c++) {
      int v = h[c * KSEG + bin];
      h[c * KSEG + bin] = run;
      run += v;
    }
  }
  __syncthreads();
  for (int i = t; i < 16 * KSEG; i += 256) histc[s * 16 * KSEG + i] = h[i];
}

__global__ __launch_bounds__(256) void scatter_kernel(
    const int* __restrict__ pids, const int* __restrict__ histc,
    int* __restrict__ order)
{
  __shared__ int offs[KSEG];
  int b = blockIdx.x, t = threadIdx.x;
  int s = b >> 4, c = b & 15;
  for (int i = t; i < KSEG; i += 256) offs[i] = histc[(s * 16 + c) * KSEG + i];
  __syncthreads();
  const int* p = pids + s * N + c * 2048;
  for (int i = t; i < 2048; i += 256) {
    int pid = p[i];
    int pos = atomicAdd(&offs[pid], 1);
    order[s * N + pos] = s * N + c * 2048 + i;
  }
}

// gather-reduce + fused LN1: FOUR waves per segment. grid 2048 (1 seg/block).
__global__ __launch_bounds__(256) void pool_gather(
    const float* __restrict__ H, const int* __restrict__ order,
    const int* __restrict__ segstart, const int* __restrict__ cnti,
    const float* __restrict__ g, const float* __restrict__ bta,
    float* __restrict__ xw, float* __restrict__ yw)
{
  __shared__ float pbuf[4][256];
  int tid = threadIdx.x;
  int w = tid >> 6, lane = tid & 63;
  int seg = blockIdx.x;
  int s = seg >> 9;
  int st = segstart[seg], cn = cnti[seg];
  int en = st + cn;
  const int* ord = order + (size_t)s * N;
  int c4 = lane << 2;
  f32x4 a0 = {0,0,0,0}, a1 = {0,0,0,0}, a2 = {0,0,0,0}, a3 = {0,0,0,0};
  f32x4 a4 = {0,0,0,0}, a5 = {0,0,0,0}, a6 = {0,0,0,0}, a7 = {0,0,0,0};
  int i = st + w;
  for (; i + 28 < en; i += 32) {
    int r0 = ord[i + 0], r1 = ord[i + 4], r2 = ord[i + 8], r3 = ord[i + 12];
    int r4 = ord[i + 16], r5 = ord[i + 20], r6 = ord[i + 24], r7 = ord[i + 28];
    a0 += *(const f32x4*)(H + (size_t)r0 * 256 + c4);
    a1 += *(const f32x4*)(H + (size_t)r1 * 256 + c4);
    a2 += *(const f32x4*)(H + (size_t)r2 * 256 + c4);
    a3 += *(const f32x4*)(H + (size_t)r3 * 256 + c4);
    a4 += *(const f32x4*)(H + (size_t)r4 * 256 + c4);
    a5 += *(const f32x4*)(H + (size_t)r5 * 256 + c4);
    a6 += *(const f32x4*)(H + (size_t)r6 * 256 + c4);
    a7 += *(const f32x4*)(H + (size_t)r7 * 256 + c4);
  }
  for (; i < en; i += 4) {
    int r = ord[i];
    a0 += *(const f32x4*)(H + (size_t)r * 256 + c4);
  }
  f32x4 ssum = ((a0 + a1) + (a2 + a3)) + ((a4 + a5) + (a6 + a7));
  *(f32x4*)&pbuf[w][c4] = ssum;
  __syncthreads();
  if (w == 0) {
    f32x4 tot = *(f32x4*)&pbuf[0][c4];
    tot += *(f32x4*)&pbuf[1][c4];
    tot += *(f32x4*)&pbuf[2][c4];
    tot += *(f32x4*)&pbuf[3][c4];
    float inv = 1.f / fmaxf((float)cn, 1.f);
    tot = tot * inv;
    *(f32x4*)(xw + (size_t)seg * 256 + c4) = tot;
    // fused LN1
    float s1 = tot[0] + tot[1] + tot[2] + tot[3];
    float s2 = tot[0]*tot[0] + tot[1]*tot[1] + tot[2]*tot[2] + tot[3]*tot[3];
    s1 = wave_reduce_sum(s1);
    s2 = wave_reduce_sum(s2);
    float mu = s1 * (1.f / 256.f);
    float var = s2 * (1.f / 256.f) - mu * mu;
    float rs = rsqrtf(var + 1e-5f);
    float4 g4 = *(const float4*)(g + c4);
    float4 b4 = *(const float4*)(bta + c4);
    float4 yv = {(tot[0]-mu)*rs*g4.x + b4.x, (tot[1]-mu)*rs*g4.y + b4.y,
                 (tot[2]-mu)*rs*g4.z + b4.z, (tot[3]-mu)*rs*g4.w + b4.w};
    *(float4*)(yw + (size_t)seg * 256 + c4) = yv;
  }
}

// ---------------- weight pre-pack: all 8 matrices into fragment order ----
__global__ __launch_bounds__(256) void wprep2_kernel(
    const float* __restrict__ Wq, const float* __restrict__ Wk,
    const float* __restrict__ Wv, const float* __restrict__ Wo,
    const float* __restrict__ fW1, const float* __restrict__ fW2,
    const float* __restrict__ mW1, const float* __restrict__ mW2,
    unsigned short* __restrict__ Wpack)
{
  int fi = blockIdx.x * 256 + threadIdx.x;   // 0..122879
  const float* src; int ld, colbase, kcbits; size_t outb; int rfi;
  if (fi < 32768) {
    int m = fi >> 13; rfi = fi & 8191;
    src = (m == 0) ? Wq : ((m == 1) ? Wk : ((m == 2) ? Wv : Wo));
    ld = 256; colbase = 0; kcbits = 3; outb = (size_t)m * 65536;
  } else if (fi < 65536) {
    rfi = fi - 32768; int cc = rfi >> 13; rfi &= 8191;
    src = fW1; ld = 1024; colbase = cc * 256; kcbits = 3;
    outb = 262144 + (size_t)cc * 65536;
  } else if (fi < 98304) {
    rfi = fi - 65536; src = fW2; ld = 256; colbase = 0; kcbits = 5; outb = 524288;
  } else if (fi < 114688) {
    rfi = fi - 98304; src = mW1; ld = 256; colbase = 0; kcbits = 4; outb = 786432;
  } else {
    rfi = fi - 114688; src = mW2; ld = 256; colbase = 0; kcbits = 3; outb = 917504;
  }
  int tile = rfi >> 6, lane = rfi & 63;
  int c = tile >> kcbits, kc = tile & ((1 << kcbits) - 1);
  int k0 = kc * 32 + (lane >> 4) * 8;
  int col = colbase + c * 16 + (lane & 15);
  unsigned int p[4];
  #pragma unroll
  for (int jj = 0; jj < 4; jj++) {
    unsigned int lo = f2bf(src[(size_t)(k0 + 2 * jj) * ld + col]);
    unsigned int hi = f2bf(src[(size_t)(k0 + 2 * jj + 1) * ld + col]);
    p[jj] = lo | (hi << 16);
  }
  u32x4 v = {p[0], p[1], p[2], p[3]};
  *(u32x4*)&Wpack[outb + (size_t)rfi * 8] = v;
}

// ---------------- MFMA patch-GEMM template pieces (16 rows x 256 cols) ----
#define AP3 264  // A row stride (bf16): 256 + 8 pad
#define CP3 260  // C row stride (f32): 256 + 4 pad

// QKV: grid (128, 3). epilogue: phi (m<=1), mask (m>=1).
__global__ __launch_bounds__(256, 4) void qkv_mfma(
    const float* __restrict__ y, const float* __restrict__ counts,
    const unsigned short* __restrict__ Wpack,
    const float* __restrict__ bq, const float* __restrict__ bk,
    const float* __restrict__ bv,
    float* __restrict__ qo, float* __restrict__ ko, float* __restrict__ vo)
{
  __shared__ __align__(16) unsigned char smem[16 * CP3 * 4];  // 16640 B
  unsigned short* Ah = (unsigned short*)smem;
  float* Cl = (float*)smem;
  int m = blockIdx.y;
  const unsigned short* Wf = Wpack + (size_t)m * 65536;
  const float* bias = (m == 0) ? bq : ((m == 1) ? bk : bv);
  float* outp = (m == 0) ? qo : ((m == 1) ? ko : vo);
  int tid = threadIdx.x, lane = tid & 63, w = tid >> 6;
  int ln15 = lane & 15, hi = lane >> 4;
  int base = blockIdx.x * 16;

  for (int i = tid; i < 16 * 64; i += 256) {
    int r = i >> 6, c4 = i & 63;
    float4 f = *(const float4*)(y + ((size_t)(base + r)) * 256 + c4 * 4);
    unsigned int lo = (unsigned int)f2bf(f.x) | ((unsigned int)f2bf(f.y) << 16);
    unsigned int h2 = (unsigned int)f2bf(f.z) | ((unsigned int)f2bf(f.w) << 16);
    u32x2 val = {lo, h2};
    *((u32x2*)&Ah[r * AP3 + c4 * 4]) = val;
  }
  __syncthreads();

  f32x4 acc[4];
  #pragma unroll
  for (int c = 0; c < 4; c++) acc[c] = (f32x4){0.f, 0.f, 0.f, 0.f};
  const unsigned short* Wl = Wf + (size_t)lane * 8;
  short8 bcur[4];
  #pragma unroll
  for (int ct = 0; ct < 4; ct++)
    bcur[ct] = *(const short8*)(Wl + ((w * 4 + ct) * 8 + 0) * 512);
  #pragma unroll
  for (int kc = 0; kc < 8; kc++) {
    short8 a = *(const short8*)(&Ah[ln15 * AP3 + kc * 32 + hi * 8]);
    short8 bnext[4];
    if (kc < 7) {
      #pragma unroll
      for (int ct = 0; ct < 4; ct++)
        bnext[ct] = *(const short8*)(Wl + ((w * 4 + ct) * 8 + kc + 1) * 512);
    }
    #pragma unroll
    for (int ct = 0; ct < 4; ct++)
      acc[ct] = __builtin_amdgcn_mfma_f32_16x16x32_bf16(a, bcur[ct], acc[ct], 0, 0, 0);
    if (kc < 7) {
      #pragma unroll
      for (int ct = 0; ct < 4; ct++) bcur[ct] = bnext[ct];
    }
  }
  __syncthreads();  // A reads done; reuse smem as Cl

  float mk[4];
  #pragma unroll
  for (int r = 0; r < 4; r++)
    mk[r] = (counts[base + hi * 4 + r] > 0.f) ? 1.f : 0.f;
  #pragma unroll
  for (int ct = 0; ct < 4; ct++) {
    int col = w * 64 + ct * 16 + ln15;
    float bb = bias[col];
    #pragma unroll
    for (int r = 0; r < 4; r++) {
      float tv = acc[ct][r] + bb;
      if (m <= 1) tv = (tv > 0.f) ? (tv + 1.f) : __expf(tv);
      if (m >= 1) tv *= mk[r];
      Cl[(hi * 4 + r) * CP3 + col] = tv;
    }
  }
  __syncthreads();
  for (int i = tid; i < 16 * 64; i += 256) {
    int r = i >> 6, c4 = i & 63;
    *(float4*)(outp + ((size_t)(base + r)) * 256 + c4 * 4) =
        *(const float4*)&Cl[r * CP3 + c4 * 4];
  }
}

// oproj + fused LN2: x2 = x + a@Wo + bo; y2 = LN(x2). grid 128.
__global__ __launch_bounds__(256, 4) void oproj_mfma(
    const float* __restrict__ aw, const float* __restrict__ xw,
    const unsigned short* __restrict__ Wpack, const float* __restrict__ bo,
    const float* __restrict__ g, const float* __restrict__ bta,
    float* __restrict__ x2, float* __restrict__ y2)
{
  __shared__ __align__(16) unsigned char smem[16 * CP3 * 4];
  unsigned short* Ah = (unsigned short*)smem;
  float* Cl = (float*)smem;
  const unsigned short* Wf = Wpack + 196608;
  int tid = threadIdx.x, lane = tid & 63, w = tid >> 6;
  int ln15 = lane & 15, hi = lane >> 4;
  int base = blockIdx.x * 16;

  for (int i = tid; i < 16 * 64; i += 256) {
    int r = i >> 6, c4 = i & 63;
    float4 f = *(const float4*)(aw + ((size_t)(base + r)) * 256 + c4 * 4);
    unsigned int lo = (unsigned int)f2bf(f.x) | ((unsigned int)f2bf(f.y) << 16);
    unsigned int h2 = (unsigned int)f2bf(f.z) | ((unsigned int)f2bf(f.w) << 16);
    u32x2 val = {lo, h2};
    *((u32x2*)&Ah[r * AP3 + c4 * 4]) = val;
  }
  __syncthreads();

  f32x4 acc[4];
  #pragma unroll
  for (int c = 0; c < 4; c++) acc[c] = (f32x4){0.f, 0.f, 0.f, 0.f};
  const unsigned short* Wl = Wf + (size_t)lane * 8;
  short8 bcur[4];
  #pragma unroll
  for (int ct = 0; ct < 4; ct++)
    bcur[ct] = *(const short8*)(Wl + ((w * 4 + ct) * 8 + 0) * 512);
  #pragma unroll
  for (int kc = 0; kc < 8; kc++) {
    short8 a = *(const short8*)(&Ah[ln15 * AP3 + kc * 32 + hi * 8]);
    short8 bnext[4];
    if (kc < 7) {
      #pragma unroll
      for (int ct = 0; ct < 4; ct++)
        bnext[ct] = *(const short8*)(Wl + ((w * 4 + ct) * 8 + kc + 1) * 512);
    }
    #pragma unroll
    for (int ct = 0; ct < 4; ct++)
      acc[ct] = __builtin_amdgcn_mfma_f32_16x16x32_bf16(a, bcur[ct], acc[ct], 0, 0, 0);
    if (kc < 7) {
      #pragma unroll
      for (int ct = 0; ct < 4; ct++) bcur[ct] = bnext[ct];
    }
  }
  __syncthreads();

  #pragma unroll
  for (int ct = 0; ct < 4; ct++) {
    int col = w * 64 + ct * 16 + ln15;
    float bb = bo[col];
    #pragma unroll
    for (int r = 0; r < 4; r++)
      Cl[(hi * 4 + r) * CP3 + col] = acc[ct][r] + bb;
  }
  __syncthreads();
  // fused residual + LN2: wave w handles rows {4k + w}
  int c4 = lane << 2;
  float4 g4 = *(const float4*)(g + c4);
  float4 b4 = *(const float4*)(bta + c4);
  #pragma unroll
  for (int k = 0; k < 4; k++) {
    int r = k * 4 + w;
    size_t gbase = ((size_t)(base + r)) * 256 + c4;
    float4 xv = *(const float4*)(xw + gbase);
    float4 cv = *(const float4*)&Cl[r * CP3 + c4];
    float4 x2v = {xv.x + cv.x, xv.y + cv.y, xv.z + cv.z, xv.w + cv.w};
    *(float4*)(x2 + gbase) = x2v;
    float s1 = x2v.x + x2v.y + x2v.z + x2v.w;
    float s2 = x2v.x*x2v.x + x2v.y*x2v.y + x2v.z*x2v.z + x2v.w*x2v.w;
    s1 = wave_reduce_sum(s1);
    s2 = wave_reduce_sum(s2);
    float mu = s1 * (1.f / 256.f);
    float var = s2 * (1.f / 256.f) - mu * mu;
    float rs = rsqrtf(var + 1e-5f);
    float4 yv = {(x2v.x-mu)*rs*g4.x + b4.x, (x2v.y-mu)*rs*g4.y + b4.y,
                 (x2v.z-mu)*rs*g4.z + b4.z, (x2v.w-mu)*rs*g4.w + b4.w};
    *(float4*)(y2 + gbase) = yv;
  }
}

// ffn1: hidb = bf16(gelu(y2 @ fW1 + b1)). grid (128, 4 col-chunks).
__global__ __launch_bounds__(256, 4) void ffn1_mfma(
    const float* __restrict__ y2, const unsigned short* __restrict__ Wpack,
    const float* __restrict__ b1, unsigned short* __restrict__ hidb)
{
  __shared__ __align__(16) unsigned char smem[16 * CP3 * 4];
  unsigned short* Ah = (unsigned short*)smem;
  int cc = blockIdx.y;
  const unsigned short* Wf = Wpack + 262144 + (size_t)cc * 65536;
  int tid = threadIdx.x, lane = tid & 63, w = tid >> 6;
  int ln15 = lane & 15, hi = lane >> 4;
  int base = blockIdx.x * 16;

  for (int i = tid; i < 16 * 64; i += 256) {
    int r = i >> 6, c4 = i & 63;
    float4 f = *(const float4*)(y2 + ((size_t)(base + r)) * 256 + c4 * 4);
    unsigned int lo = (unsigned int)f2bf(f.x) | ((unsigned int)f2bf(f.y) << 16);
    unsigned int h2 = (unsigned int)f2bf(f.z) | ((unsigned int)f2bf(f.w) << 16);
    u32x2 val = {lo, h2};
    *((u32x2*)&Ah[r * AP3 + c4 * 4]) = val;
  }
  __syncthreads();

  f32x4 acc[4];
  #pragma unroll
  for (int c = 0; c < 4; c++) acc[c] = (f32x4){0.f, 0.f, 0.f, 0.f};
  const unsigned short* Wl = Wf + (size_t)lane * 8;
  short8 bcur[4];
  #pragma unroll
  for (int ct = 0; ct < 4; ct++)
    bcur[ct] = *(const short8*)(Wl + ((w * 4 + ct) * 8 + 0) * 512);
  #pragma unroll
  for (int kc = 0; kc < 8; kc++) {
    short8 a = *(const short8*)(&Ah[ln15 * AP3 + kc * 32 + hi * 8]);
    short8 bnext[4];
    if (kc < 7) {
      #pragma unroll
      for (int ct = 0; ct < 4; ct++)
        bnext[ct] = *(const short8*)(Wl + ((w * 4 + ct) * 8 + kc + 1) * 512);
    }
    #pragma unroll
    for (int ct = 0; ct < 4; ct++)
      acc[ct] = __builtin_amdgcn_mfma_f32_16x16x32_bf16(a, bcur[ct], acc[ct], 0, 0, 0);
    if (kc < 7) {
      #pragma unroll
      for (int ct = 0; ct < 4; ct++) bcur[ct] = bnext[ct];
    }
  }
  __syncthreads();

  #pragma unroll
  for (int ct = 0; ct < 4; ct++) {
    int col = w * 64 + ct * 16 + ln15;
    float bb = b1[cc * 256 + col];
    #pragma unroll
    for (int r = 0; r < 4; r++)
      Ah[(hi * 4 + r) * 256 + col] = f2bf(gelu_f(acc[ct][r] + bb));
  }
  __syncthreads();
  for (int i = tid; i < 16 * 32; i += 256) {
    int r = i >> 5, c8 = i & 31;
    *(u32x4*)(hidb + ((size_t)(base + r)) * FF + cc * 256 + c8 * 8) =
        *(const u32x4*)&Ah[r * 256 + c8 * 8];
  }
}

// ffn2: psu = x2 + hidb @ fW2 + b2 (fp32 out + bf16 psub). grid 128. K=1024.
__global__ __launch_bounds__(256, 4) void ffn2_mfma(
    const unsigned short* __restrict__ hidb, const float* __restrict__ x2,
    const unsigned short* __restrict__ Wpack, const float* __restrict__ b2,
    float* __restrict__ psu_out, unsigned short* __restrict__ psub)
{
  __shared__ __align__(16) unsigned char smem[16 * CP3 * 4];
  unsigned short* Ah = (unsigned short*)smem;
  float* Cl = (float*)smem;
  const unsigned short* Wf = Wpack + 524288;
  int tid = threadIdx.x, lane = tid & 63, w = tid >> 6;
  int ln15 = lane & 15, hi = lane >> 4;
  int base = blockIdx.x * 16;

  f32x4 acc[4];
  #pragma unroll
  for (int c = 0; c < 4; c++) acc[c] = (f32x4){0.f, 0.f, 0.f, 0.f};
  const unsigned short* Wl = Wf + (size_t)lane * 8;

  for (int ch = 0; ch < 4; ch++) {
    __syncthreads();
    for (int i = tid; i < 16 * 32; i += 256) {
      int r = i >> 5, c8 = i & 31;
      *((u32x4*)&Ah[r * AP3 + c8 * 8]) =
          *(const u32x4*)(hidb + ((size_t)(base + r)) * FF + ch * 256 + c8 * 8);
    }
    __syncthreads();
    short8 bcur[4];
    #pragma unroll
    for (int ct = 0; ct < 4; ct++)
      bcur[ct] = *(const short8*)(Wl + ((w * 4 + ct) * 32 + ch * 8 + 0) * 512);
    #pragma unroll
    for (int kc = 0; kc < 8; kc++) {
      short8 a = *(const short8*)(&Ah[ln15 * AP3 + kc * 32 + hi * 8]);
      short8 bnext[4];
      if (kc < 7) {
        #pragma unroll
        for (int ct = 0; ct < 4; ct++)
          bnext[ct] = *(const short8*)(Wl + ((w * 4 + ct) * 32 + ch * 8 + kc + 1) * 512);
      }
      #pragma unroll
      for (int ct = 0; ct < 4; ct++)
        acc[ct] = __builtin_amdgcn_mfma_f32_16x16x32_bf16(a, bcur[ct], acc[ct], 0, 0, 0);
      if (kc < 7) {
        #pragma unroll
        for (int ct = 0; ct < 4; ct++) bcur[ct] = bnext[ct];
      }
    }
  }
  __syncthreads();

  #pragma unroll
  for (int ct = 0; ct < 4; ct++) {
    int col = w * 64 + ct * 16 + ln15;
    float bb = b2[col];
    #pragma unroll
    for (int r = 0; r < 4; r++)
      Cl[(hi * 4 + r) * CP3 + col] = acc[ct][r] + bb;
  }
  __syncthreads();
  for (int i = tid; i < 16 * 64; i += 256) {
    int r = i >> 6, c4 = i & 63;
    size_t gidx = ((size_t)(base + r)) * 256 + c4 * 4;
    float4 xv = *(const float4*)(x2 + gidx);
    float4 cv = *(const float4*)&Cl[r * CP3 + c4 * 4];
    float4 o = {xv.x + cv.x, xv.y + cv.y, xv.z + cv.z, xv.w + cv.w};
    *(float4*)(psu_out + gidx) = o;
    unsigned int lo = (unsigned int)f2bf(o.x) | ((unsigned int)f2bf(o.y) << 16);
    unsigned int h2 = (unsigned int)f2bf(o.z) | ((unsigned int)f2bf(o.w) << 16);
    u32x2 pb = {lo, h2};
    *(u32x2*)(psub + gidx) = pb;
  }
}

// kv partials: kvp[ck][s,h,d,e] = sum over chunk ck; NO atomics. grid 128
__global__ __launch_bounds__(256) void kv_kernel(
    const float* __restrict__ kw, const float* __restrict__ vw,
    float* __restrict__ kvp, float* __restrict__ ksp)
{
  int b = blockIdx.x, t = threadIdx.x;
  int s = b / (NH * 8), h = (b / 8) % NH, ck = b & 7;
  __shared__ float kl[64 * 64];
  __shared__ float vl[64 * 64];
  for (int i = t; i < 4096; i += 256) {
    int kk = i >> 6, d = i & 63;
    size_t rowb = ((size_t)(s * KSEG + ck * 64 + kk) * NH + h) * HD + d;
    kl[i] = kw[rowb];
    vl[i] = vw[rowb];
  }
  __syncthreads();
  int d = t & 63, eb = (t >> 6) * 16;
  f32x4 a4[4];
  #pragma unroll
  for (int j = 0; j < 4; j++) a4[j] = (f32x4){0.f, 0.f, 0.f, 0.f};
  float acck = 0.f;
  #pragma unroll 4
  for (int kk = 0; kk < 64; kk++) {
    float kd = kl[kk * 64 + d];
    acck += kd;
    #pragma unroll
    for (int j = 0; j < 4; j++) {
      f32x4 vv = *(const f32x4*)&vl[kk * 64 + eb + j * 4];
      a4[j] += kd * vv;
    }
  }
  float* kvo = kvp + (size_t)ck * 65536 + (((size_t)(s * NH + h)) * HD + d) * HD + eb;
  #pragma unroll
  for (int j = 0; j < 4; j++)
    *(f32x4*)(kvo + j * 4) = a4[j];
  if (t < 64) ksp[ck * 1024 + (s * NH + h) * HD + t] = acck;
}

// a = num/den per row; sums 8 kv partials during staging. grid 256 blocks
__global__ __launch_bounds__(256) void attn_kernel(
    const float* __restrict__ qw, const float* __restrict__ kvp,
    const float* __restrict__ ksp, float* __restrict__ aw)
{
  __shared__ float kvl[64 * 64];
  __shared__ float ksl[64];
  __shared__ float ql[32 * 64];
  int t = threadIdx.x, b = blockIdx.x;
  int sh = b >> 4, rb = b & 15;
  int s = sh >> 2, h = sh & 3;
  for (int i = t; i < 4096; i += 256) {
    float v = 0.f;
    #pragma unroll
    for (int ck = 0; ck < 8; ck++)
      v += kvp[(size_t)ck * 65536 + sh * 4096 + i];
    kvl[i] = v;
  }
  if (t < 64) {
    float v = 0.f;
    #pragma unroll
    for (int ck = 0; ck < 8; ck++)
      v += ksp[ck * 1024 + sh * 64 + t];
    ksl[t] = v;
  }
  for (int i = t; i < 2048; i += 256) {
    int r = i >> 6, d = i & 63;
    ql[i] = qw[((size_t)(s * KSEG + rb * 32 + r)) * 256 + h * 64 + d];
  }
  __syncthreads();
  int e = t & 63, rg = t >> 6;
  float num[8], den[8];
  #pragma unroll
  for (int r = 0; r < 8; r++) { num[r] = 0.f; den[r] = 0.f; }
  #pragma unroll 4
  for (int d4 = 0; d4 < 64; d4 += 4) {
    float4 ks4 = *(const float4*)&ksl[d4];
    float kv0 = kvl[(d4 + 0) * 64 + e];
    float kv1 = kvl[(d4 + 1) * 64 + e];
    float kv2 = kvl[(d4 + 2) * 64 + e];
    float kv3 = kvl[(d4 + 3) * 64 + e];
    #pragma unroll
    for (int r = 0; r < 8; r++) {
      float4 q4 = *(const float4*)&ql[(rg * 8 + r) * 64 + d4];
      num[r] += q4.x * kv0 + q4.y * kv1 + q4.z * kv2 + q4.w * kv3;
      den[r] += q4.x * ks4.x + q4.y * ks4.y + q4.z * ks4.z + q4.w * ks4.w;
    }
  }
  #pragma unroll
  for (int r = 0; r < 8; r++) {
    int row = rb * 32 + rg * 8 + r;
    aw[((size_t)(s * KSEG + row)) * 256 + h * 64 + e] = num[r] / (den[r] + 1e-6f);
  }
}

// ---------------- Phase C: fused node MLP (bf16 MFMA), v5 (R10 proven) ----
#define AP2 264
#define CP2 260
__global__ __launch_bounds__(256, 5) void node_mlp_kernel(
    const float* __restrict__ H, const int* __restrict__ pids,
    const unsigned short* __restrict__ psub,
    const unsigned short* __restrict__ W1f, const unsigned short* __restrict__ W2f,
    const float* __restrict__ b1, const float* __restrict__ b2,
    float* __restrict__ out)
{
  __shared__ __align__(16) unsigned char smem[32 * AP2 * 2];  // 16896 B
  __shared__ int pidl[32];
  unsigned short* Ah = (unsigned short*)smem;
  float* Cl = (float*)smem;
  int tid = threadIdx.x;
  int lane = tid & 63, w = tid >> 6;
  int ln15 = lane & 15, hi = lane >> 4;
  int base = blockIdx.x * 32;

  f32x4 acc[2][4];
  #pragma unroll
  for (int a = 0; a < 2; a++)
    #pragma unroll
    for (int c = 0; c < 4; c++) acc[a][c] = (f32x4){0.f, 0.f, 0.f, 0.f};

  // ---- stage 1: H cols 0..255 (fp32 -> bf16) ----
  if (tid < 32) pidl[tid] = pids[base + tid];
  #pragma unroll
  for (int k = 0; k < 8; k++) {
    int i = tid + k * 256;
    int r = i >> 6, c4 = i & 63;
    float4 f = *(const float4*)(H + ((size_t)(base + r)) * 256 + c4 * 4);
    unsigned int lo = (unsigned int)f2bf(f.x) | ((unsigned int)f2bf(f.y) << 16);
    unsigned int hi2 = (unsigned int)f2bf(f.z) | ((unsigned int)f2bf(f.w) << 16);
    u32x2 val = {lo, hi2};
    *((u32x2*)&Ah[r * AP2 + c4 * 4]) = val;
  }
  __syncthreads();  // B1

  const unsigned short* Wl1 = W1f + (size_t)lane * 8;
  // ---- GEMM1a kc 0..7 (K 0..255) ----
  {
    short8 bcur[4];
    #pragma unroll
    for (int ct = 0; ct < 4; ct++)
      bcur[ct] = *(const short8*)(Wl1 + ((w * 4 + ct) * 16 + 0) * 512);
    #pragma unroll
    for (int kc = 0; kc < 8; kc++) {
      short8 a[2], bnext[4];
      #pragma unroll
      for (int rt = 0; rt < 2; rt++)
        a[rt] = *(const short8*)(&Ah[(rt * 16 + ln15) * AP2 + kc * 32 + hi * 8]);
      if (kc < 7) {
        #pragma unroll
        for (int ct = 0; ct < 4; ct++)
          bnext[ct] = *(const short8*)(Wl1 + ((w * 4 + ct) * 16 + kc + 1) * 512);
      }
      __builtin_amdgcn_s_setprio(1);
      #pragma unroll
      for (int rt = 0; rt < 2; rt++)
        #pragma unroll
        for (int ct = 0; ct < 4; ct++)
          acc[rt][ct] = __builtin_amdgcn_mfma_f32_16x16x32_bf16(a[rt], bcur[ct], acc[rt][ct], 0, 0, 0);
      __builtin_amdgcn_s_setprio(0);
      if (kc < 7) {
        #pragma unroll
        for (int ct = 0; ct < 4; ct++) bcur[ct] = bnext[ct];
      }
    }
  }

  // ---- early-issue psu gather (loads in flight across B2) ----
  int ss = base >> 15;
  int r0 = tid >> 5, ch = tid & 31;
  int p0 = pidl[r0], p1 = pidl[8 + r0], p2 = pidl[16 + r0], p3 = pidl[24 + r0];
  const unsigned short* pbase = psub + (size_t)(ss * KSEG) * 256 + (size_t)ch * 8;
  u32x4 g0 = *(const u32x4*)(pbase + (size_t)p0 * 256);
  u32x4 g1 = *(const u32x4*)(pbase + (size_t)p1 * 256);
  u32x4 g2 = *(const u32x4*)(pbase + (size_t)p2 * 256);
  u32x4 g3 = *(const u32x4*)(pbase + (size_t)p3 * 256);
  __syncthreads();  // B2 (GEMM1a A-reads done)
  *(u32x4*)&Ah[r0 * AP2 + ch * 8] = g0;
  *(u32x4*)&Ah[(8 + r0) * AP2 + ch * 8] = g1;
  *(u32x4*)&Ah[(16 + r0) * AP2 + ch * 8] = g2;
  *(u32x4*)&Ah[(24 + r0) * AP2 + ch * 8] = g3;
  __syncthreads();  // B3

  // ---- GEMM1b kc 8..15 (K 256..511) ----
  {
    short8 bcur[4];
    #pragma unroll
    for (int ct = 0; ct < 4; ct++)
      bcur[ct] = *(const short8*)(Wl1 + ((w * 4 + ct) * 16 + 8) * 512);
    #pragma unroll
    for (int kc = 8; kc < 16; kc++) {
      short8 a[2], bnext[4];
      #pragma unroll
      for (int rt = 0; rt < 2; rt++)
        a[rt] = *(const short8*)(&Ah[(rt * 16 + ln15) * AP2 + (kc - 8) * 32 + hi * 8]);
      if (kc < 15) {
        #pragma unroll
        for (int ct = 0; ct < 4; ct++)
          bnext[ct] = *(const short8*)(Wl1 + ((w * 4 + ct) * 16 + kc + 1) * 512);
      }
      __builtin_amdgcn_s_setprio(1);
      #pragma unroll
      for (int rt = 0; rt < 2; rt++)
        #pragma unroll
        for (int ct = 0; ct < 4; ct++)
          acc[rt][ct] = __builtin_amdgcn_mfma_f32_16x16x32_bf16(a[rt], bcur[ct], acc[rt][ct], 0, 0, 0);
      __builtin_amdgcn_s_setprio(0);
      if (kc < 15) {
        #pragma unroll
        for (int ct = 0; ct < 4; ct++) bcur[ct] = bnext[ct];
      }
    }
  }
  __syncthreads();  // B4

  // ---- epi1: bias + gelu -> Hid (aliased over Ah) ----
  #pragma unroll
  for (int rt = 0; rt < 2; rt++) {
    #pragma unroll
    for (int ct = 0; ct < 4; ct++) {
      int col = w * 64 + ct * 16 + ln15;
      float bb = b1[col];
      #pragma unroll
      for (int r = 0; r < 4; r++) {
        int row = rt * 16 + hi * 4 + r;
        Ah[row * AP2 + col] = f2bf(gelu_f(acc[rt][ct][r] + bb));
      }
      acc[rt][ct] = (f32x4){0.f, 0.f, 0.f, 0.f};
    }
  }
  __syncthreads();  // B5

  // ---- GEMM2: [32x256] @ [256x256] ----
  {
    const unsigned short* Wl2 = W2f + (size_t)lane * 8;
    short8 bcur[4];
    #pragma unroll
    for (int ct = 0; ct < 4; ct++)
      bcur[ct] = *(const short8*)(Wl2 + ((w * 4 + ct) * 8 + 0) * 512);
    #pragma unroll
    for (int kc = 0; kc < 8; kc++) {
      short8 a[2], bnext[4];
      #pragma unroll
      for (int rt = 0; rt < 2; rt++)
        a[rt] = *(const short8*)(&Ah[(rt * 16 + ln15) * AP2 + kc * 32 + hi * 8]);
      if (kc < 7) {
        #pragma unroll
        for (int ct = 0; ct < 4; ct++)
          bnext[ct] = *(const short8*)(Wl2 + ((w * 4 + ct) * 8 + kc + 1) * 512);
      }
      __builtin_amdgcn_s_setprio(1);
      #pragma unroll
      for (int rt = 0; rt < 2; rt++)
        #pragma unroll
        for (int ct = 0; ct < 4; ct++)
          acc[rt][ct] = __builtin_amdgcn_mfma_f32_16x16x32_bf16(a[rt], bcur[ct], acc[rt][ct], 0, 0, 0);
      __builtin_amdgcn_s_setprio(0);
      if (kc < 7) {
        #pragma unroll
        for (int ct = 0; ct < 4; ct++) bcur[ct] = bnext[ct];
      }
    }
  }

  // ---- final epilogue: two 16-row LDS passes, H re-read from global ----
  #pragma unroll
  for (int rh = 0; rh < 2; rh++) {
    __syncthreads();  // GEMM2 Ah reads done (rh=0) / prior pass done (rh=1)
    #pragma unroll
    for (int ct = 0; ct < 4; ct++) {
      int col = w * 64 + ct * 16 + ln15;
      float bb = b2[col];
      #pragma unroll
      for (int r = 0; r < 4; r++)
        Cl[(hi * 4 + r) * CP2 + col] = acc[rh][ct][r] + bb;
    }
    __syncthreads();
    #pragma unroll
    for (int k2 = 0; k2 < 4; k2++) {
      int i = tid + k2 * 256;
      int r = i >> 6, c4 = i & 63;
      size_t gidx = ((size_t)(base + rh * 16 + r)) * 256 + c4 * 4;
      float4 hv = *(const float4*)(H + gidx);
      float4 cv = *(const float4*)&Cl[r * CP2 + c4 * 4];
      float4 o4 = {hv.x + cv.x, hv.y + cv.y, hv.z + cv.z, hv.w + cv.w};
      *(float4*)(out + gidx) = o4;
    }
  }
}

extern "C" void kernel_launch(void* const* d_in, const int* in_sizes, int n_in,
                              void* d_out, int out_size, void* d_ws, size_t ws_size,
                              hipStream_t stream) {
  (void)in_sizes; (void)n_in; (void)out_size; (void)ws_size;
  const float* H    = (const float*)d_in[0];
  const int*   pids = (const int*)d_in[1];
  const float* ln1g = (const float*)d_in[2];
  const float* ln1b = (const float*)d_in[3];
  const float* Wq   = (const float*)d_in[4];
  const float* bq   = (const float*)d_in[5];
  const float* Wk   = (const float*)d_in[6];
  const float* bk   = (const float*)d_in[7];
  const float* Wv   = (const float*)d_in[8];
  const float* bv   = (const float*)d_in[9];
  const float* Wo   = (const float*)d_in[10];
  const float* bo   = (const float*)d_in[11];
  const float* ln2g = (const float*)d_in[12];
  const float* ln2b = (const float*)d_in[13];
  const float* fW1  = (const float*)d_in[14];
  const float* fb1  = (const float*)d_in[15];
  const float* fW2  = (const float*)d_in[16];
  const float* fb2  = (const float*)d_in[17];
  const float* mW1  = (const float*)d_in[18];
  const float* mb1  = (const float*)d_in[19];
  const float* mW2  = (const float*)d_in[20];
  const float* mb2  = (const float*)d_in[21];
  float* out = (float*)d_out;
  float* ws = (float*)d_ws;

  int*   histc   = (int*)ws;                          // (32768)
  int*   segstart= (int*)(ws + 32768);                // (2048)
  int*   cnti    = (int*)(ws + 34816);                // (2048)
  int*   order   = (int*)(ws + 36864);                // (131072)
  float* counts  = ws + 167936;                       // (2048)
  float* xw      = ws + 169984;                       // (524288)
  float* yw      = ws + 694272;                       // (524288)
  float* qw      = ws + 1218560;                      // (524288)
  float* kw      = ws + 1742848;                      // (524288)
  float* vw      = ws + 2267136;                      // (524288)
  float* aw      = ws + 2857984;                      // (524288)
  float* x2w     = ws + 3382272;                      // (524288)
  float* y2w     = ws + 3906560;                      // (524288)
  unsigned short* hidb  = (unsigned short*)(ws + 4430848);  // 2M shorts
  unsigned short* psub  = (unsigned short*)(ws + 5479424);  // 512K shorts
  unsigned short* Wpack = (unsigned short*)(ws + 5741568);  // 983040 shorts
  float* kvp     = ws + 6233088;                      // 8 x 65536 = 524288
  float* ksp     = ws + 6757376;                      // 8 x 1024  = 8192

  wprep2_kernel<<<480, 256, 0, stream>>>(Wq, Wk, Wv, Wo, fW1, fW2, mW1, mW2, Wpack);
  hist_kernel<<<64, 256, 0, stream>>>(pids, histc);
  prefix_kernel<<<4, 256, 0, stream>>>(histc, segstart, cnti, counts);
  scatter_kernel<<<64, 256, 0, stream>>>(pids, histc, order);
  pool_gather<<<2048, 256, 0, stream>>>(H, order, segstart, cnti, ln1g, ln1b, xw, yw);
  qkv_mfma<<<dim3(128, 3), 256, 0, stream>>>(yw, counts, Wpack, bq, bk, bv, qw, kw, vw);
  kv_kernel<<<128, 256, 0, stream>>>(kw, vw, kvp, ksp);
  attn_kernel<<<256, 256, 0, stream>>>(qw, kvp, ksp, aw);
  oproj_mfma<<<128, 256, 0, stream>>>(aw, xw, Wpack, bo, ln2g, ln2b, x2w, y2w);
  ffn1_mfma<<<dim3(128, 4), 256, 0, stream>>>(y2w, Wpack, fb1, hidb);
  ffn2_mfma<<<128, 256, 0, stream>>>(hidb, x2w, Wpack, fb2,
                                     out + (size_t)S * N * D, psub);
  node_mlp_kernel<<<4096, 256, 0, stream>>>(H, pids, psub,
                                            Wpack + 786432, Wpack + 917504,
                                            mb1, mb2, out);
}

// Round 16
// 205.834 us; speedup vs baseline: 2.3571x; 1.0036x over previous
//
#include <hip/hip_runtime.h>
#include <hip/hip_bf16.h>

#define S 4
#define N 32768
#define D 256
#define KSEG 512
#define NH 4
#define HD 64
#define FF 1024

typedef __attribute__((ext_vector_type(8))) short short8;
typedef __attribute__((ext_vector_type(4))) float f32x4;
typedef __attribute__((ext_vector_type(4))) unsigned int u32x4;
typedef __attribute__((ext_vector_type(2))) unsigned int u32x2;

__device__ __forceinline__ unsigned short f2bf(float f) {
  union { __hip_bfloat16 h; unsigned short u; } cv;
  cv.h = __float2bfloat16(f);
  return cv.u;
}

// tanh-form gelu (|err| vs exact erf-gelu < ~3e-3 abs; threshold 0.11).
__device__ __forceinline__ float gelu_f(float x) {
  float u = 0.7978845608028654f * (x + 0.044715f * x * x * x);
  float e = __expf(2.f * u);
  float t = 1.f - 2.f / (e + 1.f);
  return 0.5f * x * (1.f + t);
}

__device__ __forceinline__ float wave_reduce_sum(float v) {
  #pragma unroll
  for (int o = 32; o > 0; o >>= 1) v += __shfl_xor(v, o, 64);
  return v;
}

// ---------------- Phase A: counting sort by patch id ----------------
__global__ __launch_bounds__(256) void hist_kernel(
    const int* __restrict__ pids, int* __restrict__ histc)
{
  __shared__ int h[KSEG];
  int b = blockIdx.x, t = threadIdx.x;
  int s = b >> 4, c = b & 15;
  for (int i = t; i < KSEG; i += 256) h[i] = 0;
  __syncthreads();
  const int* p = pids + s * N + c * 2048;
  for (int i = t; i < 2048; i += 256) atomicAdd(&h[p[i]], 1);
  __syncthreads();
  for (int i = t; i < KSEG; i += 256) histc[(s * 16 + c) * KSEG + i] = h[i];
}

__global__ __launch_bounds__(256) void prefix_kernel(
    int* __restrict__ histc, int* __restrict__ segstart,
    int* __restrict__ cnti, float* __restrict__ counts)
{
  __shared__ int h[16 * KSEG];   // 32 KB
  __shared__ int sc[KSEG];
  __shared__ int sa[KSEG], sb[KSEG];
  int s = blockIdx.x, t = threadIdx.x;
  for (int i = t; i < 16 * KSEG; i += 256) h[i] = histc[s * 16 * KSEG + i];
  __syncthreads();
  #pragma unroll
  for (int u = 0; u < 2; u++) {
    int bin = t + u * 256;
    int cc = 0;
    #pragma unroll
    for (int c = 0; c < 16; c++) cc += h[c * KSEG + bin];
    sc[bin] = cc;
    sa[bin] = cc;
  }
  __syncthreads();
  int* src = sa; int* dst = sb;
  for (int off = 1; off < KSEG; off <<= 1) {
    #pragma unroll
    for (int u = 0; u < 2; u++) {
      int bin = t + u * 256;
      int v = src[bin];
      if (bin >= off) v += src[bin - off];
      dst[bin] = v;
    }
    __syncthreads();
    int* tmp = src; src = dst; dst = tmp;
  }
  #pragma unroll
  for (int u = 0; u < 2; u++) {
    int bin = t + u * 256;
    int cc = sc[bin];
    int excl = src[bin] - cc;
    segstart[s * KSEG + bin] = excl;
    cnti[s * KSEG + bin] = cc;
    counts[s * KSEG + bin] = (float)cc;
    int run = excl;
    #pragma unroll
    for (int c = 0; c < 16; c++) {
      int v = h[c * KSEG + bin];
      h[c * KSEG + bin] = run;
      run += v;
    }
  }
  __syncthreads();
  for (int i = t; i < 16 * KSEG; i += 256) histc[s * 16 * KSEG + i] = h[i];
}

__global__ __launch_bounds__(256) void scatter_kernel(
    const int* __restrict__ pids, const int* __restrict__ histc,
    int* __restrict__ order)
{
  __shared__ int offs[KSEG];
  int b = blockIdx.x, t = threadIdx.x;
  int s = b >> 4, c = b & 15;
  for (int i = t; i < KSEG; i += 256) offs[i] = histc[(s * 16 + c) * KSEG + i];
  __syncthreads();
  const int* p = pids + s * N + c * 2048;
  for (int i = t; i < 2048; i += 256) {
    int pid = p[i];
    int pos = atomicAdd(&offs[pid], 1);
    order[s * N + pos] = s * N + c * 2048 + i;
  }
}

// gather-reduce + fused LN1: FOUR waves per segment. grid 2048 (1 seg/block).
__global__ __launch_bounds__(256) void pool_gather(
    const float* __restrict__ H, const int* __restrict__ order,
    const int* __restrict__ segstart, const int* __restrict__ cnti,
    const float* __restrict__ g, const float* __restrict__ bta,
    float* __restrict__ xw, float* __restrict__ yw)
{
  __shared__ float pbuf[4][256];
  int tid = threadIdx.x;
  int w = tid >> 6, lane = tid & 63;
  int seg = blockIdx.x;
  int s = seg >> 9;
  int st = segstart[seg], cn = cnti[seg];
  int en = st + cn;
  const int* ord = order + (size_t)s * N;
  int c4 = lane << 2;
  f32x4 a0 = {0,0,0,0}, a1 = {0,0,0,0}, a2 = {0,0,0,0}, a3 = {0,0,0,0};
  f32x4 a4 = {0,0,0,0}, a5 = {0,0,0,0}, a6 = {0,0,0,0}, a7 = {0,0,0,0};
  int i = st + w;
  for (; i + 28 < en; i += 32) {
    int r0 = ord[i + 0], r1 = ord[i + 4], r2 = ord[i + 8], r3 = ord[i + 12];
    int r4 = ord[i + 16], r5 = ord[i + 20], r6 = ord[i + 24], r7 = ord[i + 28];
    a0 += *(const f32x4*)(H + (size_t)r0 * 256 + c4);
    a1 += *(const f32x4*)(H + (size_t)r1 * 256 + c4);
    a2 += *(const f32x4*)(H + (size_t)r2 * 256 + c4);
    a3 += *(const f32x4*)(H + (size_t)r3 * 256 + c4);
    a4 += *(const f32x4*)(H + (size_t)r4 * 256 + c4);
    a5 += *(const f32x4*)(H + (size_t)r5 * 256 + c4);
    a6 += *(const f32x4*)(H + (size_t)r6 * 256 + c4);
    a7 += *(const f32x4*)(H + (size_t)r7 * 256 + c4);
  }
  for (; i < en; i += 4) {
    int r = ord[i];
    a0 += *(const f32x4*)(H + (size_t)r * 256 + c4);
  }
  f32x4 ssum = ((a0 + a1) + (a2 + a3)) + ((a4 + a5) + (a6 + a7));
  *(f32x4*)&pbuf[w][c4] = ssum;
  __syncthreads();
  if (w == 0) {
    f32x4 tot = *(f32x4*)&pbuf[0][c4];
    tot += *(f32x4*)&pbuf[1][c4];
    tot += *(f32x4*)&pbuf[2][c4];
    tot += *(f32x4*)&pbuf[3][c4];
    float inv = 1.f / fmaxf((float)cn, 1.f);
    tot = tot * inv;
    *(f32x4*)(xw + (size_t)seg * 256 + c4) = tot;
    // fused LN1
    float s1 = tot[0] + tot[1] + tot[2] + tot[3];
    float s2 = tot[0]*tot[0] + tot[1]*tot[1] + tot[2]*tot[2] + tot[3]*tot[3];
    s1 = wave_reduce_sum(s1);
    s2 = wave_reduce_sum(s2);
    float mu = s1 * (1.f / 256.f);
    float var = s2 * (1.f / 256.f) - mu * mu;
    float rs = rsqrtf(var + 1e-5f);
    float4 g4 = *(const float4*)(g + c4);
    float4 b4 = *(const float4*)(bta + c4);
    float4 yv = {(tot[0]-mu)*rs*g4.x + b4.x, (tot[1]-mu)*rs*g4.y + b4.y,
                 (tot[2]-mu)*rs*g4.z + b4.z, (tot[3]-mu)*rs*g4.w + b4.w};
    *(float4*)(yw + (size_t)seg * 256 + c4) = yv;
  }
}

// ---------------- weight pre-pack: all 8 matrices into fragment order ----
__global__ __launch_bounds__(256) void wprep2_kernel(
    const float* __restrict__ Wq, const float* __restrict__ Wk,
    const float* __restrict__ Wv, const float* __restrict__ Wo,
    const float* __restrict__ fW1, const float* __restrict__ fW2,
    const float* __restrict__ mW1, const float* __restrict__ mW2,
    unsigned short* __restrict__ Wpack)
{
  int fi = blockIdx.x * 256 + threadIdx.x;   // 0..122879
  const float* src; int ld, colbase, kcbits; size_t outb; int rfi;
  if (fi < 32768) {
    int m = fi >> 13; rfi = fi & 8191;
    src = (m == 0) ? Wq : ((m == 1) ? Wk : ((m == 2) ? Wv : Wo));
    ld = 256; colbase = 0; kcbits = 3; outb = (size_t)m * 65536;
  } else if (fi < 65536) {
    rfi = fi - 32768; int cc = rfi >> 13; rfi &= 8191;
    src = fW1; ld = 1024; colbase = cc * 256; kcbits = 3;
    outb = 262144 + (size_t)cc * 65536;
  } else if (fi < 98304) {
    rfi = fi - 65536; src = fW2; ld = 256; colbase = 0; kcbits = 5; outb = 524288;
  } else if (fi < 114688) {
    rfi = fi - 98304; src = mW1; ld = 256; colbase = 0; kcbits = 4; outb = 786432;
  } else {
    rfi = fi - 114688; src = mW2; ld = 256; colbase = 0; kcbits = 3; outb = 917504;
  }
  int tile = rfi >> 6, lane = rfi & 63;
  int c = tile >> kcbits, kc = tile & ((1 << kcbits) - 1);
  int k0 = kc * 32 + (lane >> 4) * 8;
  int col = colbase + c * 16 + (lane & 15);
  unsigned int p[4];
  #pragma unroll
  for (int jj = 0; jj < 4; jj++) {
    unsigned int lo = f2bf(src[(size_t)(k0 + 2 * jj) * ld + col]);
    unsigned int hi = f2bf(src[(size_t)(k0 + 2 * jj + 1) * ld + col]);
    p[jj] = lo | (hi << 16);
  }
  u32x4 v = {p[0], p[1], p[2], p[3]};
  *(u32x4*)&Wpack[outb + (size_t)rfi * 8] = v;
}

// ---------------- MFMA patch-GEMM template pieces (16 rows x 256 cols) ----
#define AP3 264  // A row stride (bf16): 256 + 8 pad
#define CP3 260  // C row stride (f32): 256 + 4 pad

// QKV: grid (128, 3). epilogue: phi (m<=1), mask (m>=1).
__global__ __launch_bounds__(256, 4) void qkv_mfma(
    const float* __restrict__ y, const float* __restrict__ counts,
    const unsigned short* __restrict__ Wpack,
    const float* __restrict__ bq, const float* __restrict__ bk,
    const float* __restrict__ bv,
    float* __restrict__ qo, float* __restrict__ ko, float* __restrict__ vo)
{
  __shared__ __align__(16) unsigned char smem[16 * CP3 * 4];  // 16640 B
  unsigned short* Ah = (unsigned short*)smem;
  float* Cl = (float*)smem;
  int m = blockIdx.y;
  const unsigned short* Wf = Wpack + (size_t)m * 65536;
  const float* bias = (m == 0) ? bq : ((m == 1) ? bk : bv);
  float* outp = (m == 0) ? qo : ((m == 1) ? ko : vo);
  int tid = threadIdx.x, lane = tid & 63, w = tid >> 6;
  int ln15 = lane & 15, hi = lane >> 4;
  int base = blockIdx.x * 16;

  for (int i = tid; i < 16 * 64; i += 256) {
    int r = i >> 6, c4 = i & 63;
    float4 f = *(const float4*)(y + ((size_t)(base + r)) * 256 + c4 * 4);
    unsigned int lo = (unsigned int)f2bf(f.x) | ((unsigned int)f2bf(f.y) << 16);
    unsigned int h2 = (unsigned int)f2bf(f.z) | ((unsigned int)f2bf(f.w) << 16);
    u32x2 val = {lo, h2};
    *((u32x2*)&Ah[r * AP3 + c4 * 4]) = val;
  }
  __syncthreads();

  f32x4 acc[4];
  #pragma unroll
  for (int c = 0; c < 4; c++) acc[c] = (f32x4){0.f, 0.f, 0.f, 0.f};
  const unsigned short* Wl = Wf + (size_t)lane * 8;
  short8 bcur[4];
  #pragma unroll
  for (int ct = 0; ct < 4; ct++)
    bcur[ct] = *(const short8*)(Wl + ((w * 4 + ct) * 8 + 0) * 512);
  #pragma unroll
  for (int kc = 0; kc < 8; kc++) {
    short8 a = *(const short8*)(&Ah[ln15 * AP3 + kc * 32 + hi * 8]);
    short8 bnext[4];
    if (kc < 7) {
      #pragma unroll
      for (int ct = 0; ct < 4; ct++)
        bnext[ct] = *(const short8*)(Wl + ((w * 4 + ct) * 8 + kc + 1) * 512);
    }
    #pragma unroll
    for (int ct = 0; ct < 4; ct++)
      acc[ct] = __builtin_amdgcn_mfma_f32_16x16x32_bf16(a, bcur[ct], acc[ct], 0, 0, 0);
    if (kc < 7) {
      #pragma unroll
      for (int ct = 0; ct < 4; ct++) bcur[ct] = bnext[ct];
    }
  }
  __syncthreads();  // A reads done; reuse smem as Cl

  float mk[4];
  #pragma unroll
  for (int r = 0; r < 4; r++)
    mk[r] = (counts[base + hi * 4 + r] > 0.f) ? 1.f : 0.f;
  #pragma unroll
  for (int ct = 0; ct < 4; ct++) {
    int col = w * 64 + ct * 16 + ln15;
    float bb = bias[col];
    #pragma unroll
    for (int r = 0; r < 4; r++) {
      float tv = acc[ct][r] + bb;
      if (m <= 1) tv = (tv > 0.f) ? (tv + 1.f) : __expf(tv);
      if (m >= 1) tv *= mk[r];
      Cl[(hi * 4 + r) * CP3 + col] = tv;
    }
  }
  __syncthreads();
  for (int i = tid; i < 16 * 64; i += 256) {
    int r = i >> 6, c4 = i & 63;
    *(float4*)(outp + ((size_t)(base + r)) * 256 + c4 * 4) =
        *(const float4*)&Cl[r * CP3 + c4 * 4];
  }
}

// oproj + fused LN2: x2 = x + a@Wo + bo; y2 = LN(x2). grid 128.
__global__ __launch_bounds__(256, 4) void oproj_mfma(
    const float* __restrict__ aw, const float* __restrict__ xw,
    const unsigned short* __restrict__ Wpack, const float* __restrict__ bo,
    const float* __restrict__ g, const float* __restrict__ bta,
    float* __restrict__ x2, float* __restrict__ y2)
{
  __shared__ __align__(16) unsigned char smem[16 * CP3 * 4];
  unsigned short* Ah = (unsigned short*)smem;
  float* Cl = (float*)smem;
  const unsigned short* Wf = Wpack + 196608;
  int tid = threadIdx.x, lane = tid & 63, w = tid >> 6;
  int ln15 = lane & 15, hi = lane >> 4;
  int base = blockIdx.x * 16;

  for (int i = tid; i < 16 * 64; i += 256) {
    int r = i >> 6, c4 = i & 63;
    float4 f = *(const float4*)(aw + ((size_t)(base + r)) * 256 + c4 * 4);
    unsigned int lo = (unsigned int)f2bf(f.x) | ((unsigned int)f2bf(f.y) << 16);
    unsigned int h2 = (unsigned int)f2bf(f.z) | ((unsigned int)f2bf(f.w) << 16);
    u32x2 val = {lo, h2};
    *((u32x2*)&Ah[r * AP3 + c4 * 4]) = val;
  }
  __syncthreads();

  f32x4 acc[4];
  #pragma unroll
  for (int c = 0; c < 4; c++) acc[c] = (f32x4){0.f, 0.f, 0.f, 0.f};
  const unsigned short* Wl = Wf + (size_t)lane * 8;
  short8 bcur[4];
  #pragma unroll
  for (int ct = 0; ct < 4; ct++)
    bcur[ct] = *(const short8*)(Wl + ((w * 4 + ct) * 8 + 0) * 512);
  #pragma unroll
  for (int kc = 0; kc < 8; kc++) {
    short8 a = *(const short8*)(&Ah[ln15 * AP3 + kc * 32 + hi * 8]);
    short8 bnext[4];
    if (kc < 7) {
      #pragma unroll
      for (int ct = 0; ct < 4; ct++)
        bnext[ct] = *(const short8*)(Wl + ((w * 4 + ct) * 8 + kc + 1) * 512);
    }
    #pragma unroll
    for (int ct = 0; ct < 4; ct++)
      acc[ct] = __builtin_amdgcn_mfma_f32_16x16x32_bf16(a, bcur[ct], acc[ct], 0, 0, 0);
    if (kc < 7) {
      #pragma unroll
      for (int ct = 0; ct < 4; ct++) bcur[ct] = bnext[ct];
    }
  }
  __syncthreads();

  #pragma unroll
  for (int ct = 0; ct < 4; ct++) {
    int col = w * 64 + ct * 16 + ln15;
    float bb = bo[col];
    #pragma unroll
    for (int r = 0; r < 4; r++)
      Cl[(hi * 4 + r) * CP3 + col] = acc[ct][r] + bb;
  }
  __syncthreads();
  // fused residual + LN2: wave w handles rows {4k + w}
  int c4 = lane << 2;
  float4 g4 = *(const float4*)(g + c4);
  float4 b4 = *(const float4*)(bta + c4);
  #pragma unroll
  for (int k = 0; k < 4; k++) {
    int r = k * 4 + w;
    size_t gbase = ((size_t)(base + r)) * 256 + c4;
    float4 xv = *(const float4*)(xw + gbase);
    float4 cv = *(const float4*)&Cl[r * CP3 + c4];
    float4 x2v = {xv.x + cv.x, xv.y + cv.y, xv.z + cv.z, xv.w + cv.w};
    *(float4*)(x2 + gbase) = x2v;
    float s1 = x2v.x + x2v.y + x2v.z + x2v.w;
    float s2 = x2v.x*x2v.x + x2v.y*x2v.y + x2v.z*x2v.z + x2v.w*x2v.w;
    s1 = wave_reduce_sum(s1);
    s2 = wave_reduce_sum(s2);
    float mu = s1 * (1.f / 256.f);
    float var = s2 * (1.f / 256.f) - mu * mu;
    float rs = rsqrtf(var + 1e-5f);
    float4 yv = {(x2v.x-mu)*rs*g4.x + b4.x, (x2v.y-mu)*rs*g4.y + b4.y,
                 (x2v.z-mu)*rs*g4.z + b4.z, (x2v.w-mu)*rs*g4.w + b4.w};
    *(float4*)(y2 + gbase) = yv;
  }
}

// ffn1: hidb = bf16(gelu(y2 @ fW1 + b1)). grid (128, 4 col-chunks).
__global__ __launch_bounds__(256, 4) void ffn1_mfma(
    const float* __restrict__ y2, const unsigned short* __restrict__ Wpack,
    const float* __restrict__ b1, unsigned short* __restrict__ hidb)
{
  __shared__ __align__(16) unsigned char smem[16 * CP3 * 4];
  unsigned short* Ah = (unsigned short*)smem;
  int cc = blockIdx.y;
  const unsigned short* Wf = Wpack + 262144 + (size_t)cc * 65536;
  int tid = threadIdx.x, lane = tid & 63, w = tid >> 6;
  int ln15 = lane & 15, hi = lane >> 4;
  int base = blockIdx.x * 16;

  for (int i = tid; i < 16 * 64; i += 256) {
    int r = i >> 6, c4 = i & 63;
    float4 f = *(const float4*)(y2 + ((size_t)(base + r)) * 256 + c4 * 4);
    unsigned int lo = (unsigned int)f2bf(f.x) | ((unsigned int)f2bf(f.y) << 16);
    unsigned int h2 = (unsigned int)f2bf(f.z) | ((unsigned int)f2bf(f.w) << 16);
    u32x2 val = {lo, h2};
    *((u32x2*)&Ah[r * AP3 + c4 * 4]) = val;
  }
  __syncthreads();

  f32x4 acc[4];
  #pragma unroll
  for (int c = 0; c < 4; c++) acc[c] = (f32x4){0.f, 0.f, 0.f, 0.f};
  const unsigned short* Wl = Wf + (size_t)lane * 8;
  short8 bcur[4];
  #pragma unroll
  for (int ct = 0; ct < 4; ct++)
    bcur[ct] = *(const short8*)(Wl + ((w * 4 + ct) * 8 + 0) * 512);
  #pragma unroll
  for (int kc = 0; kc < 8; kc++) {
    short8 a = *(const short8*)(&Ah[ln15 * AP3 + kc * 32 + hi * 8]);
    short8 bnext[4];
    if (kc < 7) {
      #pragma unroll
      for (int ct = 0; ct < 4; ct++)
        bnext[ct] = *(const short8*)(Wl + ((w * 4 + ct) * 8 + kc + 1) * 512);
    }
    #pragma unroll
    for (int ct = 0; ct < 4; ct++)
      acc[ct] = __builtin_amdgcn_mfma_f32_16x16x32_bf16(a, bcur[ct], acc[ct], 0, 0, 0);
    if (kc < 7) {
      #pragma unroll
      for (int ct = 0; ct < 4; ct++) bcur[ct] = bnext[ct];
    }
  }
  __syncthreads();

  #pragma unroll
  for (int ct = 0; ct < 4; ct++) {
    int col = w * 64 + ct * 16 + ln15;
    float bb = b1[cc * 256 + col];
    #pragma unroll
    for (int r = 0; r < 4; r++)
      Ah[(hi * 4 + r) * 256 + col] = f2bf(gelu_f(acc[ct][r] + bb));
  }
  __syncthreads();
  for (int i = tid; i < 16 * 32; i += 256) {
    int r = i >> 5, c8 = i & 31;
    *(u32x4*)(hidb + ((size_t)(base + r)) * FF + cc * 256 + c8 * 8) =
        *(const u32x4*)&Ah[r * 256 + c8 * 8];
  }
}

// ffn2: psu = x2 + hidb @ fW2 + b2 (fp32 out + bf16 psub). grid 128. K=1024.
__global__ __launch_bounds__(256, 4) void ffn2_mfma(
    const unsigned short* __restrict__ hidb, const float* __restrict__ x2,
    const unsigned short* __restrict__ Wpack, const float* __restrict__ b2,
    float* __restrict__ psu_out, unsigned short* __restrict__ psub)
{
  __shared__ __align__(16) unsigned char smem[16 * CP3 * 4];
  unsigned short* Ah = (unsigned short*)smem;
  float* Cl = (float*)smem;
  const unsigned short* Wf = Wpack + 524288;
  int tid = threadIdx.x, lane = tid & 63, w = tid >> 6;
  int ln15 = lane & 15, hi = lane >> 4;
  int base = blockIdx.x * 16;

  f32x4 acc[4];
  #pragma unroll
  for (int c = 0; c < 4; c++) acc[c] = (f32x4){0.f, 0.f, 0.f, 0.f};
  const unsigned short* Wl = Wf + (size_t)lane * 8;

  for (int ch = 0; ch < 4; ch++) {
    __syncthreads();
    for (int i = tid; i < 16 * 32; i += 256) {
      int r = i >> 5, c8 = i & 31;
      *((u32x4*)&Ah[r * AP3 + c8 * 8]) =
          *(const u32x4*)(hidb + ((size_t)(base + r)) * FF + ch * 256 + c8 * 8);
    }
    __syncthreads();
    short8 bcur[4];
    #pragma unroll
    for (int ct = 0; ct < 4; ct++)
      bcur[ct] = *(const short8*)(Wl + ((w * 4 + ct) * 32 + ch * 8 + 0) * 512);
    #pragma unroll
    for (int kc = 0; kc < 8; kc++) {
      short8 a = *(const short8*)(&Ah[ln15 * AP3 + kc * 32 + hi * 8]);
      short8 bnext[4];
      if (kc < 7) {
        #pragma unroll
        for (int ct = 0; ct < 4; ct++)
          bnext[ct] = *(const short8*)(Wl + ((w * 4 + ct) * 32 + ch * 8 + kc + 1) * 512);
      }
      #pragma unroll
      for (int ct = 0; ct < 4; ct++)
        acc[ct] = __builtin_amdgcn_mfma_f32_16x16x32_bf16(a, bcur[ct], acc[ct], 0, 0, 0);
      if (kc < 7) {
        #pragma unroll
        for (int ct = 0; ct < 4; ct++) bcur[ct] = bnext[ct];
      }
    }
  }
  __syncthreads();

  #pragma unroll
  for (int ct = 0; ct < 4; ct++) {
    int col = w * 64 + ct * 16 + ln15;
    float bb = b2[col];
    #pragma unroll
    for (int r = 0; r < 4; r++)
      Cl[(hi * 4 + r) * CP3 + col] = acc[ct][r] + bb;
  }
  __syncthreads();
  for (int i = tid; i < 16 * 64; i += 256) {
    int r = i >> 6, c4 = i & 63;
    size_t gidx = ((size_t)(base + r)) * 256 + c4 * 4;
    float4 xv = *(const float4*)(x2 + gidx);
    float4 cv = *(const float4*)&Cl[r * CP3 + c4 * 4];
    float4 o = {xv.x + cv.x, xv.y + cv.y, xv.z + cv.z, xv.w + cv.w};
    *(float4*)(psu_out + gidx) = o;
    unsigned int lo = (unsigned int)f2bf(o.x) | ((unsigned int)f2bf(o.y) << 16);
    unsigned int h2 = (unsigned int)f2bf(o.z) | ((unsigned int)f2bf(o.w) << 16);
    u32x2 pb = {lo, h2};
    *(u32x2*)(psub + gidx) = pb;
  }
}

// kv partials: kvp[ck][s,h,d,e] = sum over chunk ck; NO atomics. grid 128
__global__ __launch_bounds__(256) void kv_kernel(
    const float* __restrict__ kw, const float* __restrict__ vw,
    float* __restrict__ kvp, float* __restrict__ ksp)
{
  int b = blockIdx.x, t = threadIdx.x;
  int s = b / (NH * 8), h = (b / 8) % NH, ck = b & 7;
  __shared__ float kl[64 * 64];
  __shared__ float vl[64 * 64];
  for (int i = t; i < 4096; i += 256) {
    int kk = i >> 6, d = i & 63;
    size_t rowb = ((size_t)(s * KSEG + ck * 64 + kk) * NH + h) * HD + d;
    kl[i] = kw[rowb];
    vl[i] = vw[rowb];
  }
  __syncthreads();
  int d = t & 63, eb = (t >> 6) * 16;
  f32x4 a4[4];
  #pragma unroll
  for (int j = 0; j < 4; j++) a4[j] = (f32x4){0.f, 0.f, 0.f, 0.f};
  float acck = 0.f;
  #pragma unroll 4
  for (int kk = 0; kk < 64; kk++) {
    float kd = kl[kk * 64 + d];
    acck += kd;
    #pragma unroll
    for (int j = 0; j < 4; j++) {
      f32x4 vv = *(const f32x4*)&vl[kk * 64 + eb + j * 4];
      a4[j] += kd * vv;
    }
  }
  float* kvo = kvp + (size_t)ck * 65536 + (((size_t)(s * NH + h)) * HD + d) * HD + eb;
  #pragma unroll
  for (int j = 0; j < 4; j++)
    *(f32x4*)(kvo + j * 4) = a4[j];
  if (t < 64) ksp[ck * 1024 + (s * NH + h) * HD + t] = acck;
}

// a = num/den per row; sums 8 kv partials during staging. grid 256 blocks
__global__ __launch_bounds__(256) void attn_kernel(
    const float* __restrict__ qw, const float* __restrict__ kvp,
    const float* __restrict__ ksp, float* __restrict__ aw)
{
  __shared__ float kvl[64 * 64];
  __shared__ float ksl[64];
  __shared__ float ql[32 * 64];
  int t = threadIdx.x, b = blockIdx.x;
  int sh = b >> 4, rb = b & 15;
  int s = sh >> 2, h = sh & 3;
  for (int i = t; i < 4096; i += 256) {
    float v = 0.f;
    #pragma unroll
    for (int ck = 0; ck < 8; ck++)
      v += kvp[(size_t)ck * 65536 + sh * 4096 + i];
    kvl[i] = v;
  }
  if (t < 64) {
    float v = 0.f;
    #pragma unroll
    for (int ck = 0; ck < 8; ck++)
      v += ksp[ck * 1024 + sh * 64 + t];
    ksl[t] = v;
  }
  for (int i = t; i < 2048; i += 256) {
    int r = i >> 6, d = i & 63;
    ql[i] = qw[((size_t)(s * KSEG + rb * 32 + r)) * 256 + h * 64 + d];
  }
  __syncthreads();
  int e = t & 63, rg = t >> 6;
  float num[8], den[8];
  #pragma unroll
  for (int r = 0; r < 8; r++) { num[r] = 0.f; den[r] = 0.f; }
  #pragma unroll 4
  for (int d4 = 0; d4 < 64; d4 += 4) {
    float4 ks4 = *(const float4*)&ksl[d4];
    float kv0 = kvl[(d4 + 0) * 64 + e];
    float kv1 = kvl[(d4 + 1) * 64 + e];
    float kv2 = kvl[(d4 + 2) * 64 + e];
    float kv3 = kvl[(d4 + 3) * 64 + e];
    #pragma unroll
    for (int r = 0; r < 8; r++) {
      float4 q4 = *(const float4*)&ql[(rg * 8 + r) * 64 + d4];
      num[r] += q4.x * kv0 + q4.y * kv1 + q4.z * kv2 + q4.w * kv3;
      den[r] += q4.x * ks4.x + q4.y * ks4.y + q4.z * ks4.z + q4.w * ks4.w;
    }
  }
  #pragma unroll
  for (int r = 0; r < 8; r++) {
    int row = rb * 32 + rg * 8 + r;
    aw[((size_t)(s * KSEG + row)) * 256 + h * 64 + e] = num[r] / (den[r] + 1e-6f);
  }
}

// ---------------- Phase C: fused node MLP (bf16 MFMA), v5 + XCD swizzle ----
// R10/R14-proven structure; only delta: bijective XCD-aware blockIdx remap
// (grid 4096 % 8 == 0 -> contiguous 512-block chunk per XCD). Register-neutral.
#define AP2 264
#define CP2 260
__global__ __launch_bounds__(256, 5) void node_mlp_kernel(
    const float* __restrict__ H, const int* __restrict__ pids,
    const unsigned short* __restrict__ psub,
    const unsigned short* __restrict__ W1f, const unsigned short* __restrict__ W2f,
    const float* __restrict__ b1, const float* __restrict__ b2,
    float* __restrict__ out)
{
  __shared__ __align__(16) unsigned char smem[32 * AP2 * 2];  // 16896 B
  __shared__ int pidl[32];
  unsigned short* Ah = (unsigned short*)smem;
  float* Cl = (float*)smem;
  int tid = threadIdx.x;
  int lane = tid & 63, w = tid >> 6;
  int ln15 = lane & 15, hi = lane >> 4;
  // XCD-aware swizzle: round-robin (hw) -> contiguous chunk per XCD
  int bid = blockIdx.x;
  int swz = (bid & 7) * 512 + (bid >> 3);
  int base = swz * 32;

  f32x4 acc[2][4];
  #pragma unroll
  for (int a = 0; a < 2; a++)
    #pragma unroll
    for (int c = 0; c < 4; c++) acc[a][c] = (f32x4){0.f, 0.f, 0.f, 0.f};

  // ---- stage 1: H cols 0..255 (fp32 -> bf16) ----
  if (tid < 32) pidl[tid] = pids[base + tid];
  #pragma unroll
  for (int k = 0; k < 8; k++) {
    int i = tid + k * 256;
    int r = i >> 6, c4 = i & 63;
    float4 f = *(const float4*)(H + ((size_t)(base + r)) * 256 + c4 * 4);
    unsigned int lo = (unsigned int)f2bf(f.x) | ((unsigned int)f2bf(f.y) << 16);
    unsigned int hi2 = (unsigned int)f2bf(f.z) | ((unsigned int)f2bf(f.w) << 16);
    u32x2 val = {lo, hi2};
    *((u32x2*)&Ah[r * AP2 + c4 * 4]) = val;
  }
  __syncthreads();  // B1

  const unsigned short* Wl1 = W1f + (size_t)lane * 8;
  // ---- GEMM1a kc 0..7 (K 0..255) ----
  {
    short8 bcur[4];
    #pragma unroll
    for (int ct = 0; ct < 4; ct++)
      bcur[ct] = *(const short8*)(Wl1 + ((w * 4 + ct) * 16 + 0) * 512);
    #pragma unroll
    for (int kc = 0; kc < 8; kc++) {
      short8 a[2], bnext[4];
      #pragma unroll
      for (int rt = 0; rt < 2; rt++)
        a[rt] = *(const short8*)(&Ah[(rt * 16 + ln15) * AP2 + kc * 32 + hi * 8]);
      if (kc < 7) {
        #pragma unroll
        for (int ct = 0; ct < 4; ct++)
          bnext[ct] = *(const short8*)(Wl1 + ((w * 4 + ct) * 16 + kc + 1) * 512);
      }
      __builtin_amdgcn_s_setprio(1);
      #pragma unroll
      for (int rt = 0; rt < 2; rt++)
        #pragma unroll
        for (int ct = 0; ct < 4; ct++)
          acc[rt][ct] = __builtin_amdgcn_mfma_f32_16x16x32_bf16(a[rt], bcur[ct], acc[rt][ct], 0, 0, 0);
      __builtin_amdgcn_s_setprio(0);
      if (kc < 7) {
        #pragma unroll
        for (int ct = 0; ct < 4; ct++) bcur[ct] = bnext[ct];
      }
    }
  }

  // ---- early-issue psu gather (loads in flight across B2) ----
  int ss = base >> 15;
  int r0 = tid >> 5, ch = tid & 31;
  int p0 = pidl[r0], p1 = pidl[8 + r0], p2 = pidl[16 + r0], p3 = pidl[24 + r0];
  const unsigned short* pbase = psub + (size_t)(ss * KSEG) * 256 + (size_t)ch * 8;
  u32x4 g0 = *(const u32x4*)(pbase + (size_t)p0 * 256);
  u32x4 g1 = *(const u32x4*)(pbase + (size_t)p1 * 256);
  u32x4 g2 = *(const u32x4*)(pbase + (size_t)p2 * 256);
  u32x4 g3 = *(const u32x4*)(pbase + (size_t)p3 * 256);
  __syncthreads();  // B2 (GEMM1a A-reads done)
  *(u32x4*)&Ah[r0 * AP2 + ch * 8] = g0;
  *(u32x4*)&Ah[(8 + r0) * AP2 + ch * 8] = g1;
  *(u32x4*)&Ah[(16 + r0) * AP2 + ch * 8] = g2;
  *(u32x4*)&Ah[(24 + r0) * AP2 + ch * 8] = g3;
  __syncthreads();  // B3

  // ---- GEMM1b kc 8..15 (K 256..511) ----
  {
    short8 bcur[4];
    #pragma unroll
    for (int ct = 0; ct < 4; ct++)
      bcur[ct] = *(const short8*)(Wl1 + ((w * 4 + ct) * 16 + 8) * 512);
    #pragma unroll
    for (int kc = 8; kc < 16; kc++) {
      short8 a[2], bnext[4];
      #pragma unroll
      for (int rt = 0; rt < 2; rt++)
        a[rt] = *(const short8*)(&Ah[(rt * 16 + ln15) * AP2 + (kc - 8) * 32 + hi * 8]);
      if (kc < 15) {
        #pragma unroll
        for (int ct = 0; ct < 4; ct++)
          bnext[ct] = *(const short8*)(Wl1 + ((w * 4 + ct) * 16 + kc + 1) * 512);
      }
      __builtin_amdgcn_s_setprio(1);
      #pragma unroll
      for (int rt = 0; rt < 2; rt++)
        #pragma unroll
        for (int ct = 0; ct < 4; ct++)
          acc[rt][ct] = __builtin_amdgcn_mfma_f32_16x16x32_bf16(a[rt], bcur[ct], acc[rt][ct], 0, 0, 0);
      __builtin_amdgcn_s_setprio(0);
      if (kc < 15) {
        #pragma unroll
        for (int ct = 0; ct < 4; ct++) bcur[ct] = bnext[ct];
      }
    }
  }
  __syncthreads();  // B4

  // ---- epi1: bias + gelu -> Hid (aliased over Ah) ----
  #pragma unroll
  for (int rt = 0; rt < 2; rt++) {
    #pragma unroll
    for (int ct = 0; ct < 4; ct++) {
      int col = w * 64 + ct * 16 + ln15;
      float bb = b1[col];
      #pragma unroll
      for (int r = 0; r < 4; r++) {
        int row = rt * 16 + hi * 4 + r;
        Ah[row * AP2 + col] = f2bf(gelu_f(acc[rt][ct][r] + bb));
      }
      acc[rt][ct] = (f32x4){0.f, 0.f, 0.f, 0.f};
    }
  }
  __syncthreads();  // B5

  // ---- GEMM2: [32x256] @ [256x256] ----
  {
    const unsigned short* Wl2 = W2f + (size_t)lane * 8;
    short8 bcur[4];
    #pragma unroll
    for (int ct = 0; ct < 4; ct++)
      bcur[ct] = *(const short8*)(Wl2 + ((w * 4 + ct) * 8 + 0) * 512);
    #pragma unroll
    for (int kc = 0; kc < 8; kc++) {
      short8 a[2], bnext[4];
      #pragma unroll
      for (int rt = 0; rt < 2; rt++)
        a[rt] = *(const short8*)(&Ah[(rt * 16 + ln15) * AP2 + kc * 32 + hi * 8]);
      if (kc < 7) {
        #pragma unroll
        for (int ct = 0; ct < 4; ct++)
          bnext[ct] = *(const short8*)(Wl2 + ((w * 4 + ct) * 8 + kc + 1) * 512);
      }
      __builtin_amdgcn_s_setprio(1);
      #pragma unroll
      for (int rt = 0; rt < 2; rt++)
        #pragma unroll
        for (int ct = 0; ct < 4; ct++)
          acc[rt][ct] = __builtin_amdgcn_mfma_f32_16x16x32_bf16(a[rt], bcur[ct], acc[rt][ct], 0, 0, 0);
      __builtin_amdgcn_s_setprio(0);
      if (kc < 7) {
        #pragma unroll
        for (int ct = 0; ct < 4; ct++) bcur[ct] = bnext[ct];
      }
    }
  }

  // ---- final epilogue: two 16-row LDS passes, H re-read from global ----
  #pragma unroll
  for (int rh = 0; rh < 2; rh++) {
    __syncthreads();  // GEMM2 Ah reads done (rh=0) / prior pass done (rh=1)
    #pragma unroll
    for (int ct = 0; ct < 4; ct++) {
      int col = w * 64 + ct * 16 + ln15;
      float bb = b2[col];
      #pragma unroll
      for (int r = 0; r < 4; r++)
        Cl[(hi * 4 + r) * CP2 + col] = acc[rh][ct][r] + bb;
    }
    __syncthreads();
    #pragma unroll
    for (int k2 = 0; k2 < 4; k2++) {
      int i = tid + k2 * 256;
      int r = i >> 6, c4 = i & 63;
      size_t gidx = ((size_t)(base + rh * 16 + r)) * 256 + c4 * 4;
      float4 hv = *(const float4*)(H + gidx);
      float4 cv = *(const float4*)&Cl[r * CP2 + c4 * 4];
      float4 o4 = {hv.x + cv.x, hv.y + cv.y, hv.z + cv.z, hv.w + cv.w};
      *(float4*)(out + gidx) = o4;
    }
  }
}

extern "C" void kernel_launch(void* const* d_in, const int* in_sizes, int n_in,
                              void* d_out, int out_size, void* d_ws, size_t ws_size,
                              hipStream_t stream) {
  (void)in_sizes; (void)n_in; (void)out_size; (void)ws_size;
  const float* H    = (const float*)d_in[0];
  const int*   pids = (const int*)d_in[1];
  const float* ln1g = (const float*)d_in[2];
  const float* ln1b = (const float*)d_in[3];
  const float* Wq   = (const float*)d_in[4];
  const float* bq   = (const float*)d_in[5];
  const float* Wk   = (const float*)d_in[6];
  const float* bk   = (const float*)d_in[7];
  const float* Wv   = (const float*)d_in[8];
  const float* bv   = (const float*)d_in[9];
  const float* Wo   = (const float*)d_in[10];
  const float* bo   = (const float*)d_in[11];
  const float* ln2g = (const float*)d_in[12];
  const float* ln2b = (const float*)d_in[13];
  const float* fW1  = (const float*)d_in[14];
  const float* fb1  = (const float*)d_in[15];
  const float* fW2  = (const float*)d_in[16];
  const float* fb2  = (const float*)d_in[17];
  const float* mW1  = (const float*)d_in[18];
  const float* mb1  = (const float*)d_in[19];
  const float* mW2  = (const float*)d_in[20];
  const float* mb2  = (const float*)d_in[21];
  float* out = (float*)d_out;
  float* ws = (float*)d_ws;

  int*   histc   = (int*)ws;                          // (32768)
  int*   segstart= (int*)(ws + 32768);                // (2048)
  int*   cnti    = (int*)(ws + 34816);                // (2048)
  int*   order   = (int*)(ws + 36864);                // (131072)
  float* counts  = ws + 167936;                       // (2048)
  float* xw      = ws + 169984;                       // (524288)
  float* yw      = ws + 694272;                       // (524288)
  float* qw      = ws + 1218560;                      // (524288)
  float* kw      = ws + 1742848;                      // (524288)
  float* vw      = ws + 2267136;                      // (524288)
  float* aw      = ws + 2857984;                      // (524288)
  float* x2w     = ws + 3382272;                      // (524288)
  float* y2w     = ws + 3906560;                      // (524288)
  unsigned short* hidb  = (unsigned short*)(ws + 4430848);  // 2M shorts
  unsigned short* psub  = (unsigned short*)(ws + 5479424);  // 512K shorts
  unsigned short* Wpack = (unsigned short*)(ws + 5741568);  // 983040 shorts
  float* kvp     = ws + 6233088;                      // 8 x 65536 = 524288
  float* ksp     = ws + 6757376;                      // 8 x 1024  = 8192

  wprep2_kernel<<<480, 256, 0, stream>>>(Wq, Wk, Wv, Wo, fW1, fW2, mW1, mW2, Wpack);
  hist_kernel<<<64, 256, 0, stream>>>(pids, histc);
  prefix_kernel<<<4, 256, 0, stream>>>(histc, segstart, cnti, counts);
  scatter_kernel<<<64, 256, 0, stream>>>(pids, histc, order);
  pool_gather<<<2048, 256, 0, stream>>>(H, order, segstart, cnti, ln1g, ln1b, xw, yw);
  qkv_mfma<<<dim3(128, 3), 256, 0, stream>>>(yw, counts, Wpack, bq, bk, bv, qw, kw, vw);
  kv_kernel<<<128, 256, 0, stream>>>(kw, vw, kvp, ksp);
  attn_kernel<<<256, 256, 0, stream>>>(qw, kvp, ksp, aw);
  oproj_mfma<<<128, 256, 0, stream>>>(aw, xw, Wpack, bo, ln2g, ln2b, x2w, y2w);
  ffn1_mfma<<<dim3(128, 4), 256, 0, stream>>>(y2w, Wpack, fb1, hidb);
  ffn2_mfma<<<128, 256, 0, stream>>>(hidb, x2w, Wpack, fb2,
                                     out + (size_t)S * N * D, psub);
  node_mlp_kernel<<<4096, 256, 0, stream>>>(H, pids, psub,
                                            Wpack + 786432, Wpack + 917504,
                                            mb1, mb2, out);
}